// Round 5
// baseline (441.865 us; speedup 1.0000x reference)
//
#include <hip/hip_runtime.h>
#include <hip/hip_bf16.h>
#include <math.h>

// ---------------------------------------------------------------------------
// DistributedMoE forward, MI355X — R5: shared conv template with float2/b128
// LDS reads (4oc x 8rows x 2cols per thread), ic-split to 256 threads,
// bank-stagger pads, padded global activation planes (zero halos).
// R4 lesson: scalar b32 input reads + ~7 waves/CU = latency-bound 137us trunk.
// One expert per sample (softmax over one dispatched element == 1).
//
// out (fp32): final[256,10] @0, balanced[256,8] @2560, D[256,8] @4608
// ---------------------------------------------------------------------------

#define BN_RS (1.0f / sqrtf(1.00001f))

// ws byte offsets
#define WS_TFP    0           // f32[256][8][32] trunk partial sums
#define WS_TK     262144      // i32[512]
#define WS_CHOSEN 264192      // i32[256]
#define WS_TW2T   265216      // f32[32ic][9][32oc]
#define WS_EW2T   302080      // f32[8][32ic][9][64oc]
#define WS_EW3T   891904      // f32[8][64ic][9][128oc]
#define WS_FEATG  3251200     // f32[256*128]
#define WS_A1G    3382272     // f32[256][32][34][36] padded conv1 (trunk) - dead after trunkB
#define WS_P1G    3382272     // f32[256][32][18][20] padded (overlays dead a1g)
#define WS_P2G    15178752    // f32[256][64][10][12] padded

// =================== prep: weight transposes to [ic][k][oc] ================
__global__ __launch_bounds__(256) void prep_kernel(
    const float* __restrict__ tw2, const float* __restrict__ ew2,
    const float* __restrict__ ew3, float* __restrict__ tw2t,
    float* __restrict__ ew2t, float* __restrict__ ew3t)
{
  const int j = blockIdx.x * 256 + threadIdx.x;
  if (j < 9216) {
    int ic = j / 288, rem = j % 288, k = rem / 32, oc = rem % 32;
    tw2t[j] = tw2[oc*288 + ic*9 + k];
  } else if (j < 156672) {
    int jj = j - 9216;
    int e = jj / 18432, r2 = jj % 18432, ic = r2 / 576, r3 = r2 % 576;
    int k = r3 / 64, oc = r3 % 64;
    ew2t[jj] = ew2[e*18432 + oc*288 + ic*9 + k];
  } else if (j < 746496) {
    int jj = j - 156672;
    int e = jj / 73728, r2 = jj % 73728, ic = r2 / 1152, r3 = r2 % 1152;
    int k = r3 / 128, oc = r3 % 128;
    ew3t[jj] = ew3[e*73728 + oc*576 + ic*9 + k];
  }
}

// ============ trunkA: conv1 3->32 (32x32) full-res -> padded a1g ===========
// grid 1024 = b*4 + rowslab(8r); 256 thr = g8(4oc) x c32
__global__ __launch_bounds__(256) void trunkA_kernel(
    const float* __restrict__ x, const float* __restrict__ tw1,
    const float* __restrict__ tg1, const float* __restrict__ tb1,
    float* __restrict__ a1g)
{
  __shared__ __align__(16) float sxa[1020];   // [3][10][34]
  __shared__ __align__(16) float sw1t[864];   // [3ic][9][32oc]
  __shared__ float bs[32], bb[32];
  const int t = threadIdx.x;
  const int b = blockIdx.x >> 2, rs = blockIdx.x & 3;
  const int r0 = rs * 8;

  // zero this block's share of a1g borders (rows 0,33; cols 0,33)
  for (int j = t; j < 1088; j += 256) {
    int idx = rs*1088 + j;
    int ic = idx / 136, r2 = idx % 136, row, col;
    if (r2 < 36)       { row = 0;  col = r2; }
    else if (r2 < 72)  { row = 33; col = r2 - 36; }
    else if (r2 < 104) { row = 1 + (r2 - 72);  col = 0; }
    else               { row = 1 + (r2 - 104); col = 33; }
    a1g[b*39168 + ic*1224 + row*36 + col] = 0.f;
  }
  for (int j = t; j < 1020; j += 256) {
    int ic = j / 340, r = (j % 340) / 34, cxx = j % 34;
    int gy = r0 - 1 + r, gx = cxx - 1;
    float v = 0.f;
    if (gy >= 0 && gy < 32 && gx >= 0 && gx < 32) v = x[b*3072 + ic*1024 + gy*32 + gx];
    sxa[j] = v;
  }
  for (int j = t; j < 864; j += 256) {
    int oc = j / 27, r = j % 27, ic = r / 9, k = r % 9;
    sw1t[ic*288 + k*32 + oc] = tw1[j];
  }
  if (t < 32) { bs[t] = tg1[t]*BN_RS; bb[t] = tb1[t]; }
  __syncthreads();

  const int g = t >> 5, c = t & 31;
  float acc[4][8];
  #pragma unroll
  for (int o = 0; o < 4; ++o)
    #pragma unroll
    for (int r = 0; r < 8; ++r) acc[o][r] = 0.f;

  for (int ic = 0; ic < 3; ++ic) {
    float w[4][9];
    #pragma unroll
    for (int k = 0; k < 9; ++k) {
      float4 wv = *(const float4*)&sw1t[ic*288 + k*32 + 4*g];
      w[0][k] = wv.x; w[1][k] = wv.y; w[2][k] = wv.z; w[3][k] = wv.w;
    }
    const float* src = &sxa[ic*340 + c];
    #pragma unroll
    for (int rr = 0; rr < 10; ++rr) {
      const float i0 = src[rr*34], i1 = src[rr*34 + 1], i2 = src[rr*34 + 2];
      #pragma unroll
      for (int dr = 0; dr < 3; ++dr) {
        const int r = rr - dr;
        if (r < 0 || r > 7) continue;
        #pragma unroll
        for (int o = 0; o < 4; ++o) {
          acc[o][r] = fmaf(w[o][dr*3+0], i0, acc[o][r]);
          acc[o][r] = fmaf(w[o][dr*3+1], i1, acc[o][r]);
          acc[o][r] = fmaf(w[o][dr*3+2], i2, acc[o][r]);
        }
      }
    }
  }
  #pragma unroll
  for (int o = 0; o < 4; ++o) {
    const int oc = 4*g + o;
    const float s = bs[oc], bo = bb[oc];
    #pragma unroll
    for (int r = 0; r < 8; ++r) {
      float v = fmaxf(fmaf(acc[o][r], s, bo), 0.f);
      a1g[b*39168 + oc*1224 + (1 + r0 + r)*36 + 1 + c] = v;
    }
  }
}

// ====== trunkB: conv2 32->32 + pool + quadrant partial sums -> tfp =========
// grid 2048 = b*8 + (rs(4)*2 + ch(2)); 256 thr = g8(4oc) x q4(ic quarter) x cp8
#define TB_SLAB 0      // [32ic] stride 202 ([10r][20c] data)
#define TB_WD   6464   // dbuf 2 x [4q stride 296][9][32oc]
#define TB_BN   8832   // 64
__global__ __launch_bounds__(256, 4) void trunkB_kernel(
    const float* __restrict__ a1g, const float* __restrict__ tw2t,
    const float* __restrict__ tg2, const float* __restrict__ tb2,
    float* __restrict__ tfp)
{
  __shared__ __align__(16) float sm[8896];
  const int t = threadIdx.x;
  const int b = blockIdx.x >> 3, blk = blockIdx.x & 7;
  const int rs = blk >> 1, ch = blk & 1;
  const int r0 = rs*8, c0 = ch*16;

  for (int j = t; j < 1600; j += 256) {
    int ic = j / 50, rem = j % 50, rr = rem / 5, c4 = rem % 5;
    float4 v = *(const float4*)&a1g[b*39168 + ic*1224 + (r0+rr)*36 + c0 + 4*c4];
    float* d = &sm[TB_SLAB + ic*202 + rr*20 + 4*c4];
    d[0] = v.x; d[1] = v.y; d[2] = v.z; d[3] = v.w;
  }
  for (int j = t; j < 1152; j += 256) {
    int qq = j / 288, r = j % 288;
    sm[TB_WD + qq*296 + r] = tw2t[(qq*8)*288 + r];
  }
  if (t < 32) { sm[TB_BN + t] = tg2[t]*BN_RS; sm[TB_BN + 32 + t] = tb2[t]; }
  __syncthreads();

  const int g = t >> 5, q = (t >> 3) & 3, cp = t & 7;
  float acc[4][8][2];
  #pragma unroll
  for (int o = 0; o < 4; ++o)
    #pragma unroll
    for (int r = 0; r < 8; ++r) { acc[o][r][0] = 0.f; acc[o][r][1] = 0.f; }

  for (int cc = 0; cc < 8; ++cc) {
    if (cc < 7) {
      for (int j = t; j < 1152; j += 256) {
        int qq = j / 288, r = j % 288;
        sm[TB_WD + ((cc+1)&1)*1184 + qq*296 + r] = tw2t[(qq*8 + cc+1)*288 + r];
      }
    }
    const float* wb = &sm[TB_WD + (cc&1)*1184 + q*296];
    float w[4][9];
    #pragma unroll
    for (int k = 0; k < 9; ++k) {
      float4 wv = *(const float4*)&wb[k*32 + 4*g];
      w[0][k] = wv.x; w[1][k] = wv.y; w[2][k] = wv.z; w[3][k] = wv.w;
    }
    const float* src = &sm[TB_SLAB + (q*8+cc)*202 + 2*cp];
    #pragma unroll
    for (int rr = 0; rr < 10; ++rr) {
      float2 va = *(const float2*)&src[rr*20];
      float2 vb = *(const float2*)&src[rr*20 + 2];
      const float i0 = va.x, i1 = va.y, i2 = vb.x, i3 = vb.y;
      #pragma unroll
      for (int dr = 0; dr < 3; ++dr) {
        const int r = rr - dr;
        if (r < 0 || r > 7) continue;
        #pragma unroll
        for (int o = 0; o < 4; ++o) {
          acc[o][r][0] = fmaf(w[o][dr*3+0], i0, acc[o][r][0]);
          acc[o][r][1] = fmaf(w[o][dr*3+0], i1, acc[o][r][1]);
          acc[o][r][0] = fmaf(w[o][dr*3+1], i1, acc[o][r][0]);
          acc[o][r][1] = fmaf(w[o][dr*3+1], i2, acc[o][r][1]);
          acc[o][r][0] = fmaf(w[o][dr*3+2], i2, acc[o][r][0]);
          acc[o][r][1] = fmaf(w[o][dr*3+2], i3, acc[o][r][1]);
        }
      }
    }
    __syncthreads();
  }

  // 4-way ic-split combine: q2->R0,q3->R1; q0+=R0,q1+=R1; q1->R0; q0+=R0
  const int slot = g*8 + cp;
  if (q >= 2) {
    float* dst = &sm[(q-2)*4168 + slot*65];
    #pragma unroll
    for (int o = 0; o < 4; ++o)
      #pragma unroll
      for (int r = 0; r < 8; ++r) {
        dst[o*16 + r*2 + 0] = acc[o][r][0];
        dst[o*16 + r*2 + 1] = acc[o][r][1];
      }
  }
  __syncthreads();
  if (q < 2) {
    const float* s0 = &sm[q*4168 + slot*65];
    #pragma unroll
    for (int o = 0; o < 4; ++o)
      #pragma unroll
      for (int r = 0; r < 8; ++r) {
        acc[o][r][0] += s0[o*16 + r*2 + 0];
        acc[o][r][1] += s0[o*16 + r*2 + 1];
      }
  }
  __syncthreads();
  if (q == 1) {
    float* dst = &sm[slot*65];
    #pragma unroll
    for (int o = 0; o < 4; ++o)
      #pragma unroll
      for (int r = 0; r < 8; ++r) {
        dst[o*16 + r*2 + 0] = acc[o][r][0];
        dst[o*16 + r*2 + 1] = acc[o][r][1];
      }
  }
  __syncthreads();
  if (q == 0) {
    const float* s0 = &sm[slot*65];
    #pragma unroll
    for (int o = 0; o < 4; ++o) {
      const int oc = 4*g + o;
      const float s = sm[TB_BN + oc], bo = sm[TB_BN + 32 + oc];
      float ps = 0.f;
      #pragma unroll
      for (int pr = 0; pr < 4; ++pr) {
        float c00 = acc[o][2*pr][0]   + s0[o*16 + (2*pr)*2 + 0];
        float c01 = acc[o][2*pr][1]   + s0[o*16 + (2*pr)*2 + 1];
        float c10 = acc[o][2*pr+1][0] + s0[o*16 + (2*pr+1)*2 + 0];
        float c11 = acc[o][2*pr+1][1] + s0[o*16 + (2*pr+1)*2 + 1];
        float v0 = fmaxf(fmaf(c00, s, bo), 0.f);
        float v1 = fmaxf(fmaf(c01, s, bo), 0.f);
        float v2 = fmaxf(fmaf(c10, s, bo), 0.f);
        float v3 = fmaxf(fmaf(c11, s, bo), 0.f);
        ps += fmaxf(fmaxf(v0, v1), fmaxf(v2, v3));
      }
      ps += __shfl_xor(ps, 1);
      ps += __shfl_xor(ps, 2);
      ps += __shfl_xor(ps, 4);
      if ((t & 31) == 0) tfp[b*256 + (rs*2 + ch)*32 + oc] = ps;
    }
  }
}

// ============================== gate + top2 ================================
__global__ __launch_bounds__(64) void gate_kernel(
    const float* __restrict__ tfp, const float* __restrict__ tfw, const float* __restrict__ tfb,
    const float* __restrict__ gw1, const float* __restrict__ gb1,
    const float* __restrict__ gw2, const float* __restrict__ gb2,
    float* __restrict__ outBal, int* __restrict__ tk)
{
  __shared__ float feat[128], rf[64], g1[32], bal[8];
  const int b = blockIdx.x, t = threadIdx.x;
  #pragma unroll
  for (int h = 0; h < 2; ++h) {
    const int f = t + 64*h;
    const int oc = f >> 2, qy = (f >> 1) & 1, qx = f & 1;
    feat[f] = (tfp[b*256 + (4*qy + qx)*32 + oc] +
               tfp[b*256 + (4*qy + 2 + qx)*32 + oc]) * (1.f/64.f);
  }
  __syncthreads();
  {
    float a = tfb[t];
    const float4* wp = (const float4*)&tfw[t*128];
    #pragma unroll 8
    for (int i4 = 0; i4 < 32; ++i4) {
      float4 wv = wp[i4];
      a = fmaf(wv.x, feat[4*i4], a);   a = fmaf(wv.y, feat[4*i4+1], a);
      a = fmaf(wv.z, feat[4*i4+2], a); a = fmaf(wv.w, feat[4*i4+3], a);
    }
    rf[t] = fmaxf(a, 0.f);
  }
  __syncthreads();
  if (t < 32) {
    float a = gb1[t];
    const float4* wp = (const float4*)&gw1[t*64];
    #pragma unroll
    for (int i4 = 0; i4 < 16; ++i4) {
      float4 wv = wp[i4];
      a = fmaf(wv.x, rf[4*i4], a);   a = fmaf(wv.y, rf[4*i4+1], a);
      a = fmaf(wv.z, rf[4*i4+2], a); a = fmaf(wv.w, rf[4*i4+3], a);
    }
    g1[t] = fmaxf(a, 0.f);
  }
  __syncthreads();
  if (t < 8) {
    float a = gb2[t];
    const float4* wp = (const float4*)&gw2[t*32];
    #pragma unroll
    for (int i4 = 0; i4 < 8; ++i4) {
      float4 wv = wp[i4];
      a = fmaf(wv.x, g1[4*i4], a);   a = fmaf(wv.y, g1[4*i4+1], a);
      a = fmaf(wv.z, g1[4*i4+2], a); a = fmaf(wv.w, g1[4*i4+3], a);
    }
    const float v = a - 0.25f;   // boost=0, -LOAD_PEN*usage = -0.25
    bal[t] = v;
    outBal[b*8 + t] = v;
  }
  __syncthreads();
  if (t == 0) {
    int t0 = 0; float b0 = bal[0];
    #pragma unroll
    for (int e2 = 1; e2 < 8; ++e2) if (bal[e2] > b0) { b0 = bal[e2]; t0 = e2; }
    int t1 = -1; float b1 = -3.4e38f;
    #pragma unroll
    for (int e2 = 0; e2 < 8; ++e2) if (e2 != t0 && bal[e2] > b1) { b1 = bal[e2]; t1 = e2; }
    tk[b*2] = t0; tk[b*2 + 1] = t1;
  }
}

// =================== serial capacity-constrained routing ===================
__global__ __launch_bounds__(256) void route_kernel(const int* __restrict__ tk,
                                                    int* __restrict__ chosen,
                                                    float* __restrict__ outD)
{
  __shared__ int stk[512];
  __shared__ int sch[256];
  const int t = threadIdx.x;
  stk[t] = tk[t]; stk[256 + t] = tk[256 + t];
  __syncthreads();
  if (t == 0) {
    float L0=0,L1=0,L2=0,L3=0,L4=0,L5=0,L6=0,L7=0;
    for (int i = 0; i < 256; ++i) {
      const int a = stk[2*i], c = stk[2*i+1];
      const float la = (a==0)?L0:(a==1)?L1:(a==2)?L2:(a==3)?L3:(a==4)?L4:(a==5)?L5:(a==6)?L6:L7;
      const float lc = (c==0)?L0:(c==1)?L1:(c==2)?L2:(c==3)?L3:(c==4)?L4:(c==5)?L5:(c==6)?L6:L7;
      const int ch = (la < 48.f) ? a : ((lc < 48.f) ? c : ((la <= lc) ? a : c));
      L0 += (ch==0)?1.f:0.f; L1 += (ch==1)?1.f:0.f; L2 += (ch==2)?1.f:0.f; L3 += (ch==3)?1.f:0.f;
      L4 += (ch==4)?1.f:0.f; L5 += (ch==5)?1.f:0.f; L6 += (ch==6)?1.f:0.f; L7 += (ch==7)?1.f:0.f;
      sch[i] = ch;
    }
  }
  __syncthreads();
  const int ch = sch[t];
  chosen[t] = ch;
  #pragma unroll
  for (int e2 = 0; e2 < 8; ++e2) outD[t*8 + e2] = (ch == e2) ? 1.f : 0.f;
}

// ===== expA: conv1 3->32 (32x32) + pool -> padded P1g [32][18][20] =========
// grid 1024 = b*4 + rowslab; 256 thr = g8(4oc) x c32
__global__ __launch_bounds__(256) void expA_kernel(
    const float* __restrict__ x, const int* __restrict__ chosen,
    const float* __restrict__ ew1, const float* __restrict__ eg1,
    const float* __restrict__ eb1, float* __restrict__ P1g)
{
  __shared__ __align__(16) float sxa[1020];
  __shared__ __align__(16) float sw1t[864];
  __shared__ float bs[32], bb[32];
  const int t = threadIdx.x;
  const int b = blockIdx.x >> 2, rs = blockIdx.x & 3;
  const int r0 = rs * 8;
  const int e = chosen[b];

  // zero this block's share of P1g borders (rows 0,17 full 20c; cols 0,17)
  for (int j = t; j < 576; j += 256) {
    int idx = rs*576 + j;
    int ic = idx / 72, r2 = idx % 72, row, col;
    if (r2 < 20)      { row = 0;  col = r2; }
    else if (r2 < 40) { row = 17; col = r2 - 20; }
    else if (r2 < 56) { row = 1 + (r2 - 40); col = 0; }
    else              { row = 1 + (r2 - 56); col = 17; }
    P1g[b*11520 + ic*360 + row*20 + col] = 0.f;
  }
  for (int j = t; j < 1020; j += 256) {
    int ic = j / 340, r = (j % 340) / 34, cxx = j % 34;
    int gy = r0 - 1 + r, gx = cxx - 1;
    float v = 0.f;
    if (gy >= 0 && gy < 32 && gx >= 0 && gx < 32) v = x[b*3072 + ic*1024 + gy*32 + gx];
    sxa[j] = v;
  }
  for (int j = t; j < 864; j += 256) {
    int oc = j / 27, r = j % 27, ic = r / 9, k = r % 9;
    sw1t[ic*288 + k*32 + oc] = ew1[e*864 + j];
  }
  if (t < 32) { bs[t] = eg1[e*32 + t]*BN_RS; bb[t] = eb1[e*32 + t]; }
  __syncthreads();

  const int g = t >> 5, c = t & 31;
  float acc[4][8];
  #pragma unroll
  for (int o = 0; o < 4; ++o)
    #pragma unroll
    for (int r = 0; r < 8; ++r) acc[o][r] = 0.f;

  for (int ic = 0; ic < 3; ++ic) {
    float w[4][9];
    #pragma unroll
    for (int k = 0; k < 9; ++k) {
      float4 wv = *(const float4*)&sw1t[ic*288 + k*32 + 4*g];
      w[0][k] = wv.x; w[1][k] = wv.y; w[2][k] = wv.z; w[3][k] = wv.w;
    }
    const float* src = &sxa[ic*340 + c];
    #pragma unroll
    for (int rr = 0; rr < 10; ++rr) {
      const float i0 = src[rr*34], i1 = src[rr*34 + 1], i2 = src[rr*34 + 2];
      #pragma unroll
      for (int dr = 0; dr < 3; ++dr) {
        const int r = rr - dr;
        if (r < 0 || r > 7) continue;
        #pragma unroll
        for (int o = 0; o < 4; ++o) {
          acc[o][r] = fmaf(w[o][dr*3+0], i0, acc[o][r]);
          acc[o][r] = fmaf(w[o][dr*3+1], i1, acc[o][r]);
          acc[o][r] = fmaf(w[o][dr*3+2], i2, acc[o][r]);
        }
      }
    }
  }
  #pragma unroll
  for (int o = 0; o < 4; ++o) {
    const int oc = 4*g + o;
    const float s = bs[oc], bo = bb[oc];
    float m[4];
    #pragma unroll
    for (int pr = 0; pr < 4; ++pr) {
      float v0 = fmaxf(fmaf(acc[o][2*pr],   s, bo), 0.f);
      float v1 = fmaxf(fmaf(acc[o][2*pr+1], s, bo), 0.f);
      m[pr] = fmaxf(v0, v1);
    }
    #pragma unroll
    for (int pr = 0; pr < 4; ++pr) {
      float nb = __shfl_xor(m[pr], 1);
      m[pr] = fmaxf(m[pr], nb);
    }
    if (!(c & 1)) {
      const int pc = c >> 1;
      #pragma unroll
      for (int pr = 0; pr < 4; ++pr)
        P1g[b*11520 + oc*360 + (rs*4 + pr + 1)*20 + pc + 1] = m[pr];
    }
  }
}

// ====== expB: conv2 32->64 (16x16) + pool -> padded P2g [64][10][12] =======
// grid 1024 = b*4 + (och(2)*2 + rs(2)); 256 thr = g8 x q4 x cp8
__global__ __launch_bounds__(256, 4) void expB_kernel(
    const int* __restrict__ chosen, const float* __restrict__ P1g,
    const float* __restrict__ ew2t, const float* __restrict__ eg2,
    const float* __restrict__ eb2, float* __restrict__ P2g)
{
  __shared__ __align__(16) float sm[8896];
  const int t = threadIdx.x;
  const int b = blockIdx.x >> 2, blk = blockIdx.x & 3;
  const int och = blk >> 1, rs = blk & 1;
  const int r0 = rs*8;
  const int e = chosen[b];

  // zero this block's share of P2g borders (rows 0,9 full 12c; cols 0,9)
  for (int j = t; j < 640; j += 256) {
    int idx = blk*640 + j;
    int ic = idx / 40, r2 = idx % 40, row, col;
    if (r2 < 12)      { row = 0; col = r2; }
    else if (r2 < 24) { row = 9; col = r2 - 12; }
    else if (r2 < 32) { row = 1 + (r2 - 24); col = 0; }
    else              { row = 1 + (r2 - 32); col = 9; }
    P2g[b*7680 + ic*120 + row*12 + col] = 0.f;
  }
  for (int j = t; j < 1600; j += 256) {
    int ic = j / 50, rem = j % 50, rr = rem / 5, c4 = rem % 5;
    float4 v = *(const float4*)&P1g[b*11520 + ic*360 + (r0+rr)*20 + 4*c4];
    float* d = &sm[TB_SLAB + ic*202 + rr*20 + 4*c4];
    d[0] = v.x; d[1] = v.y; d[2] = v.z; d[3] = v.w;
  }
  for (int j = t; j < 1152; j += 256) {
    int qq = j / 288, r = j % 288, k = r / 32, ocl = r & 31;
    sm[TB_WD + qq*296 + r] = ew2t[e*18432 + (qq*8)*576 + k*64 + och*32 + ocl];
  }
  if (t < 32) {
    sm[TB_BN + t] = eg2[e*64 + och*32 + t]*BN_RS;
    sm[TB_BN + 32 + t] = eb2[e*64 + och*32 + t];
  }
  __syncthreads();

  const int g = t >> 5, q = (t >> 3) & 3, cp = t & 7;
  float acc[4][8][2];
  #pragma unroll
  for (int o = 0; o < 4; ++o)
    #pragma unroll
    for (int r = 0; r < 8; ++r) { acc[o][r][0] = 0.f; acc[o][r][1] = 0.f; }

  for (int cc = 0; cc < 8; ++cc) {
    if (cc < 7) {
      for (int j = t; j < 1152; j += 256) {
        int qq = j / 288, r = j % 288, k = r / 32, ocl = r & 31;
        sm[TB_WD + ((cc+1)&1)*1184 + qq*296 + r] =
            ew2t[e*18432 + (qq*8 + cc+1)*576 + k*64 + och*32 + ocl];
      }
    }
    const float* wb = &sm[TB_WD + (cc&1)*1184 + q*296];
    float w[4][9];
    #pragma unroll
    for (int k = 0; k < 9; ++k) {
      float4 wv = *(const float4*)&wb[k*32 + 4*g];
      w[0][k] = wv.x; w[1][k] = wv.y; w[2][k] = wv.z; w[3][k] = wv.w;
    }
    const float* src = &sm[TB_SLAB + (q*8+cc)*202 + 2*cp];
    #pragma unroll
    for (int rr = 0; rr < 10; ++rr) {
      float2 va = *(const float2*)&src[rr*20];
      float2 vb = *(const float2*)&src[rr*20 + 2];
      const float i0 = va.x, i1 = va.y, i2 = vb.x, i3 = vb.y;
      #pragma unroll
      for (int dr = 0; dr < 3; ++dr) {
        const int r = rr - dr;
        if (r < 0 || r > 7) continue;
        #pragma unroll
        for (int o = 0; o < 4; ++o) {
          acc[o][r][0] = fmaf(w[o][dr*3+0], i0, acc[o][r][0]);
          acc[o][r][1] = fmaf(w[o][dr*3+0], i1, acc[o][r][1]);
          acc[o][r][0] = fmaf(w[o][dr*3+1], i1, acc[o][r][0]);
          acc[o][r][1] = fmaf(w[o][dr*3+1], i2, acc[o][r][1]);
          acc[o][r][0] = fmaf(w[o][dr*3+2], i2, acc[o][r][0]);
          acc[o][r][1] = fmaf(w[o][dr*3+2], i3, acc[o][r][1]);
        }
      }
    }
    __syncthreads();
  }

  const int slot = g*8 + cp;
  if (q >= 2) {
    float* dst = &sm[(q-2)*4168 + slot*65];
    #pragma unroll
    for (int o = 0; o < 4; ++o)
      #pragma unroll
      for (int r = 0; r < 8; ++r) {
        dst[o*16 + r*2 + 0] = acc[o][r][0];
        dst[o*16 + r*2 + 1] = acc[o][r][1];
      }
  }
  __syncthreads();
  if (q < 2) {
    const float* s0 = &sm[q*4168 + slot*65];
    #pragma unroll
    for (int o = 0; o < 4; ++o)
      #pragma unroll
      for (int r = 0; r < 8; ++r) {
        acc[o][r][0] += s0[o*16 + r*2 + 0];
        acc[o][r][1] += s0[o*16 + r*2 + 1];
      }
  }
  __syncthreads();
  if (q == 1) {
    float* dst = &sm[slot*65];
    #pragma unroll
    for (int o = 0; o < 4; ++o)
      #pragma unroll
      for (int r = 0; r < 8; ++r) {
        dst[o*16 + r*2 + 0] = acc[o][r][0];
        dst[o*16 + r*2 + 1] = acc[o][r][1];
      }
  }
  __syncthreads();
  if (q == 0) {
    const float* s0 = &sm[slot*65];
    #pragma unroll
    for (int o = 0; o < 4; ++o) {
      const int ocl = 4*g + o;
      const float s = sm[TB_BN + ocl], bo = sm[TB_BN + 32 + ocl];
      #pragma unroll
      for (int pr = 0; pr < 4; ++pr) {
        float c00 = acc[o][2*pr][0]   + s0[o*16 + (2*pr)*2 + 0];
        float c01 = acc[o][2*pr][1]   + s0[o*16 + (2*pr)*2 + 1];
        float c10 = acc[o][2*pr+1][0] + s0[o*16 + (2*pr+1)*2 + 0];
        float c11 = acc[o][2*pr+1][1] + s0[o*16 + (2*pr+1)*2 + 1];
        float v0 = fmaxf(fmaf(c00, s, bo), 0.f);
        float v1 = fmaxf(fmaf(c01, s, bo), 0.f);
        float v2 = fmaxf(fmaf(c10, s, bo), 0.f);
        float v3 = fmaxf(fmaf(c11, s, bo), 0.f);
        float m = fmaxf(fmaxf(v0, v1), fmaxf(v2, v3));
        P2g[b*7680 + (och*32 + ocl)*120 + (rs*4 + pr + 1)*12 + cp + 1] = m;
      }
    }
  }
}

// ====== expC: conv3 64->128 (8x8) + bn/relu + GAP -> featg =================
// grid 1024 = b*4 + ocq; 256 thr = g8(4oc) x qq8(8ic) x cp4(2c)
#define XC_SLAB 0      // [8 grp stride 968][8ic stride 120]([10r][12c])
#define XC_WD   7744   // dbuf 2 x [8qq stride 296][9][32oc]
#define XC_BN   12480  // 64
__global__ __launch_bounds__(256, 4) void expC_kernel(
    const int* __restrict__ chosen, const float* __restrict__ P2g,
    const float* __restrict__ ew3t, const float* __restrict__ eg3,
    const float* __restrict__ eb3, float* __restrict__ featg)
{
  __shared__ __align__(16) float sm[12544];
  const int t = threadIdx.x;
  const int b = blockIdx.x >> 2, ocq = blockIdx.x & 3;
  const int e = chosen[b];

  for (int j = t; j < 1920; j += 256) {
    int ic = j / 30, rem = j % 30, rr = rem / 3, c4 = rem % 3;
    float4 v = *(const float4*)&P2g[b*7680 + ic*120 + rr*12 + 4*c4];
    float* d = &sm[XC_SLAB + (ic >> 3)*968 + (ic & 7)*120 + rr*12 + 4*c4];
    d[0] = v.x; d[1] = v.y; d[2] = v.z; d[3] = v.w;
  }
  for (int j = t; j < 2304; j += 256) {
    int qq = j / 288, r = j % 288, k = r / 32, ocl = r & 31;
    sm[XC_WD + qq*296 + r] = ew3t[e*73728 + (qq*8)*1152 + k*128 + ocq*32 + ocl];
  }
  if (t < 32) {
    sm[XC_BN + t] = eg3[e*128 + ocq*32 + t]*BN_RS;
    sm[XC_BN + 32 + t] = eb3[e*128 + ocq*32 + t];
  }
  __syncthreads();

  const int g = t >> 5, qq = (t >> 2) & 7, cp = t & 3;
  float acc[4][8][2];
  #pragma unroll
  for (int o = 0; o < 4; ++o)
    #pragma unroll
    for (int r = 0; r < 8; ++r) { acc[o][r][0] = 0.f; acc[o][r][1] = 0.f; }

  for (int cc = 0; cc < 8; ++cc) {
    if (cc < 7) {
      for (int j = t; j < 2304; j += 256) {
        int q2 = j / 288, r = j % 288, k = r / 32, ocl = r & 31;
        sm[XC_WD + ((cc+1)&1)*2368 + q2*296 + r] =
            ew3t[e*73728 + (q2*8 + cc+1)*1152 + k*128 + ocq*32 + ocl];
      }
    }
    const float* wb = &sm[XC_WD + (cc&1)*2368 + qq*296];
    float w[4][9];
    #pragma unroll
    for (int k = 0; k < 9; ++k) {
      float4 wv = *(const float4*)&wb[k*32 + 4*g];
      w[0][k] = wv.x; w[1][k] = wv.y; w[2][k] = wv.z; w[3][k] = wv.w;
    }
    const float* src = &sm[XC_SLAB + qq*968 + cc*120 + 2*cp];
    #pragma unroll
    for (int rr = 0; rr < 10; ++rr) {
      float2 va = *(const float2*)&src[rr*12];
      float2 vb = *(const float2*)&src[rr*12 + 2];
      const float i0 = va.x, i1 = va.y, i2 = vb.x, i3 = vb.y;
      #pragma unroll
      for (int dr = 0; dr < 3; ++dr) {
        const int r = rr - dr;
        if (r < 0 || r > 7) continue;
        #pragma unroll
        for (int o = 0; o < 4; ++o) {
          acc[o][r][0] = fmaf(w[o][dr*3+0], i0, acc[o][r][0]);
          acc[o][r][1] = fmaf(w[o][dr*3+0], i1, acc[o][r][1]);
          acc[o][r][0] = fmaf(w[o][dr*3+1], i1, acc[o][r][0]);
          acc[o][r][1] = fmaf(w[o][dr*3+1], i2, acc[o][r][1]);
          acc[o][r][0] = fmaf(w[o][dr*3+2], i2, acc[o][r][0]);
          acc[o][r][1] = fmaf(w[o][dr*3+2], i3, acc[o][r][1]);
        }
      }
    }
    __syncthreads();
  }

  // 8-way ic-split combine (3 steps), regions stride 2088
  const int slot = g*4 + cp;
  if (qq >= 4) {
    float* dst = &sm[(qq-4)*2088 + slot*65];
    #pragma unroll
    for (int o = 0; o < 4; ++o)
      #pragma unroll
      for (int r = 0; r < 8; ++r) {
        dst[o*16 + r*2 + 0] = acc[o][r][0];
        dst[o*16 + r*2 + 1] = acc[o][r][1];
      }
  }
  __syncthreads();
  if (qq < 4) {
    const float* s0 = &sm[qq*2088 + slot*65];
    #pragma unroll
    for (int o = 0; o < 4; ++o)
      #pragma unroll
      for (int r = 0; r < 8; ++r) {
        acc[o][r][0] += s0[o*16 + r*2 + 0];
        acc[o][r][1] += s0[o*16 + r*2 + 1];
      }
  }
  __syncthreads();
  if (qq == 2 || qq == 3) {
    float* dst = &sm[(qq-2)*2088 + slot*65];
    #pragma unroll
    for (int o = 0; o < 4; ++o)
      #pragma unroll
      for (int r = 0; r < 8; ++r) {
        dst[o*16 + r*2 + 0] = acc[o][r][0];
        dst[o*16 + r*2 + 1] = acc[o][r][1];
      }
  }
  __syncthreads();
  if (qq < 2) {
    const float* s0 = &sm[qq*2088 + slot*65];
    #pragma unroll
    for (int o = 0; o < 4; ++o)
      #pragma unroll
      for (int r = 0; r < 8; ++r) {
        acc[o][r][0] += s0[o*16 + r*2 + 0];
        acc[o][r][1] += s0[o*16 + r*2 + 1];
      }
  }
  __syncthreads();
  if (qq == 1) {
    float* dst = &sm[slot*65];
    #pragma unroll
    for (int o = 0; o < 4; ++o)
      #pragma unroll
      for (int r = 0; r < 8; ++r) {
        dst[o*16 + r*2 + 0] = acc[o][r][0];
        dst[o*16 + r*2 + 1] = acc[o][r][1];
      }
  }
  __syncthreads();
  if (qq == 0) {
    const float* s0 = &sm[slot*65];
    #pragma unroll
    for (int o = 0; o < 4; ++o) {
      const int ocl = 4*g + o;
      const float s = sm[XC_BN + ocl], bo = sm[XC_BN + 32 + ocl];
      float gsum = 0.f;
      #pragma unroll
      for (int r = 0; r < 8; ++r) {
        float c0 = acc[o][r][0] + s0[o*16 + r*2 + 0];
        float c1 = acc[o][r][1] + s0[o*16 + r*2 + 1];
        gsum += fmaxf(fmaf(c0, s, bo), 0.f);
        gsum += fmaxf(fmaf(c1, s, bo), 0.f);
      }
      gsum += __shfl_xor(gsum, 1);
      gsum += __shfl_xor(gsum, 2);
      if ((t & 31) == 0) featg[b*128 + ocq*32 + ocl] = gsum * (1.f/64.f);
    }
  }
}

// ================= expD: FC chain -> final =================================
__global__ __launch_bounds__(128) void expD_kernel(
    const int* __restrict__ chosen, const float* __restrict__ featg,
    const float* __restrict__ efw, const float* __restrict__ efb,
    const float* __restrict__ cw1, const float* __restrict__ cb1,
    const float* __restrict__ cw2, const float* __restrict__ cb2,
    float* __restrict__ outF)
{
  __shared__ float sf[128], sff[128], sgg[64];
  const int b = blockIdx.x, t = threadIdx.x;
  const int e = chosen[b];
  sf[t] = featg[b*128 + t];
  __syncthreads();
  {
    float a = efb[e*128 + t];
    const float4* wp = (const float4*)&efw[e*16384 + t*128];
    #pragma unroll 8
    for (int i4 = 0; i4 < 32; ++i4) {
      float4 wv = wp[i4];
      a = fmaf(wv.x, sf[4*i4], a);   a = fmaf(wv.y, sf[4*i4+1], a);
      a = fmaf(wv.z, sf[4*i4+2], a); a = fmaf(wv.w, sf[4*i4+3], a);
    }
    sff[t] = fmaxf(a, 0.f);
  }
  __syncthreads();
  if (t < 64) {
    float a = cb1[e*64 + t];
    const float4* wp = (const float4*)&cw1[e*8192 + t*128];
    #pragma unroll 8
    for (int i4 = 0; i4 < 32; ++i4) {
      float4 wv = wp[i4];
      a = fmaf(wv.x, sff[4*i4], a);   a = fmaf(wv.y, sff[4*i4+1], a);
      a = fmaf(wv.z, sff[4*i4+2], a); a = fmaf(wv.w, sff[4*i4+3], a);
    }
    sgg[t] = fmaxf(a, 0.f);
  }
  __syncthreads();
  if (t < 10) {
    float a = cb2[e*10 + t];
    const float4* wp = (const float4*)&cw2[e*640 + t*64];
    #pragma unroll
    for (int i4 = 0; i4 < 16; ++i4) {
      float4 wv = wp[i4];
      a = fmaf(wv.x, sgg[4*i4], a);   a = fmaf(wv.y, sgg[4*i4+1], a);
      a = fmaf(wv.z, sgg[4*i4+2], a); a = fmaf(wv.w, sgg[4*i4+3], a);
    }
    outF[b*10 + t] = a;   // routing weight is exactly 1.0 for the chosen expert
  }
}

// ================================ host =====================================
extern "C" void kernel_launch(void* const* d_in, const int* in_sizes, int n_in,
                              void* d_out, int out_size, void* d_ws, size_t ws_size,
                              hipStream_t stream)
{
  const float* x   = (const float*)d_in[0];
  const float* tw1 = (const float*)d_in[1];
  const float* tg1 = (const float*)d_in[2];
  const float* tb1 = (const float*)d_in[3];
  const float* tw2 = (const float*)d_in[4];
  const float* tg2 = (const float*)d_in[5];
  const float* tb2 = (const float*)d_in[6];
  const float* tfw = (const float*)d_in[7];
  const float* tfb = (const float*)d_in[8];
  const float* gw1 = (const float*)d_in[9];
  const float* gb1 = (const float*)d_in[10];
  const float* gw2 = (const float*)d_in[11];
  const float* gb2 = (const float*)d_in[12];
  const float* ew1 = (const float*)d_in[13];
  const float* eg1 = (const float*)d_in[14];
  const float* eb1 = (const float*)d_in[15];
  const float* ew2 = (const float*)d_in[16];
  const float* eg2 = (const float*)d_in[17];
  const float* eb2 = (const float*)d_in[18];
  const float* ew3 = (const float*)d_in[19];
  const float* eg3 = (const float*)d_in[20];
  const float* eb3 = (const float*)d_in[21];
  const float* efw = (const float*)d_in[22];
  const float* efb = (const float*)d_in[23];
  const float* cw1 = (const float*)d_in[24];
  const float* cb1 = (const float*)d_in[25];
  const float* cw2 = (const float*)d_in[26];
  const float* cb2 = (const float*)d_in[27];

  float* out    = (float*)d_out;
  char*  ws     = (char*)d_ws;
  float* tfp    = (float*)(ws + WS_TFP);
  int*   tk     = (int*)(ws + WS_TK);
  int*   chosen = (int*)(ws + WS_CHOSEN);
  float* tw2t   = (float*)(ws + WS_TW2T);
  float* ew2t   = (float*)(ws + WS_EW2T);
  float* ew3t   = (float*)(ws + WS_EW3T);
  float* featg  = (float*)(ws + WS_FEATG);
  float* a1g    = (float*)(ws + WS_A1G);
  float* P1g    = (float*)(ws + WS_P1G);   // overlays a1g (dead after trunkB)
  float* P2g    = (float*)(ws + WS_P2G);

  prep_kernel<<<2916, 256, 0, stream>>>(tw2, ew2, ew3, tw2t, ew2t, ew3t);
  trunkA_kernel<<<1024, 256, 0, stream>>>(x, tw1, tg1, tb1, a1g);
  trunkB_kernel<<<2048, 256, 0, stream>>>(a1g, tw2t, tg2, tb2, tfp);
  gate_kernel<<<256, 64, 0, stream>>>(tfp, tfw, tfb, gw1, gb1, gw2, gb2, out + 2560, tk);
  route_kernel<<<1, 256, 0, stream>>>(tk, chosen, out + 4608);
  expA_kernel<<<1024, 256, 0, stream>>>(x, chosen, ew1, eg1, eb1, P1g);
  expB_kernel<<<1024, 256, 0, stream>>>(chosen, P1g, ew2t, eg2, eb2, P2g);
  expC_kernel<<<1024, 256, 0, stream>>>(chosen, P2g, ew3t, eg3, eb3, featg);
  expD_kernel<<<256, 128, 0, stream>>>(chosen, featg, efw, efb, cw1, cb1, cw2, cb2, out);
}

// Round 6
// 429.096 us; speedup vs baseline: 1.0298x; 1.0298x over previous
//
#include <hip/hip_runtime.h>
#include <hip/hip_bf16.h>
#include <math.h>

// ---------------------------------------------------------------------------
// DistributedMoE forward, MI355X — R6: fused trunk conv1+conv2 per 8x16 tile.
// R5 lesson: the a1g global intermediate cost 100MB of HBM round-trip traffic
// (FETCH 57MB + writeback 42MB on trunkB) and made trunkB stall ~50%. This
// round computes conv1 directly into the LDS slab layout trunkB staged from
// global, deleting trunkA and a1g. conv2 loop / summation order / tfp format
// are byte-identical to R5 (routing digits preserved). Everything else
// unchanged to isolate the delta.
// One expert per sample (softmax over one dispatched element == 1).
//
// out (fp32): final[256,10] @0, balanced[256,8] @2560, D[256,8] @4608
// ---------------------------------------------------------------------------

#define BN_RS (1.0f / sqrtf(1.00001f))

// ws byte offsets
#define WS_TFP    0           // f32[256][8][32] trunk partial sums
#define WS_TK     262144      // i32[512]
#define WS_CHOSEN 264192      // i32[256]
#define WS_TW2T   265216      // f32[32ic][9][32oc]
#define WS_EW2T   302080      // f32[8][32ic][9][64oc]
#define WS_EW3T   891904      // f32[8][64ic][9][128oc]
#define WS_FEATG  3251200     // f32[256*128]
#define WS_P1G    3382272     // f32[256][32][18][20] padded
#define WS_P2G    15178752    // f32[256][64][10][12] padded

// =================== prep: weight transposes to [ic][k][oc] ================
__global__ __launch_bounds__(256) void prep_kernel(
    const float* __restrict__ tw2, const float* __restrict__ ew2,
    const float* __restrict__ ew3, float* __restrict__ tw2t,
    float* __restrict__ ew2t, float* __restrict__ ew3t)
{
  const int j = blockIdx.x * 256 + threadIdx.x;
  if (j < 9216) {
    int ic = j / 288, rem = j % 288, k = rem / 32, oc = rem % 32;
    tw2t[j] = tw2[oc*288 + ic*9 + k];
  } else if (j < 156672) {
    int jj = j - 9216;
    int e = jj / 18432, r2 = jj % 18432, ic = r2 / 576, r3 = r2 % 576;
    int k = r3 / 64, oc = r3 % 64;
    ew2t[jj] = ew2[e*18432 + oc*288 + ic*9 + k];
  } else if (j < 746496) {
    int jj = j - 156672;
    int e = jj / 73728, r2 = jj % 73728, ic = r2 / 1152, r3 = r2 % 1152;
    int k = r3 / 128, oc = r3 % 128;
    ew3t[jj] = ew3[e*73728 + oc*576 + ic*9 + k];
  }
}

// ====== fused trunk: conv1 (in-LDS) + conv2 + pool + partial sums ==========
// grid 2048 = b*8 + (rs(4)*2 + ch(2)); 256 thr; LDS 35840 B -> 4 blocks/CU.
// SA1: conv1 out slab [32oc][10r][20c], ic-stride 202 (== R5 slab layout,
//   slab row rr = image row r0-1+rr, slab col cx = image col c0-1+cx)
// conv2 thread = g8(4oc) x q4(ic quarter) x cp8(2 cols); acc[4][8][2].
#define TF_SA1 0       // 32 x 202 = 6464
#define TF_WD  6464    // dbuf 2 x [4q stride 296][9][32oc] = 2368
#define TF_X   6464    // phase-1 overlay: x tile [3][12][20] = 720
#define TF_W1  7184    // phase-1 overlay: conv1 weights 864
#define TF_BN  8832    // s1[32] o1[32] s2[32] o2[32]
__global__ __launch_bounds__(256, 4) void trunk_kernel(
    const float* __restrict__ x, const float* __restrict__ tw1,
    const float* __restrict__ tg1, const float* __restrict__ tb1,
    const float* __restrict__ tw2t, const float* __restrict__ tg2,
    const float* __restrict__ tb2, float* __restrict__ tfp)
{
  __shared__ __align__(16) float sm[8960];
  const int t = threadIdx.x;
  const int b = blockIdx.x >> 3, blk = blockIdx.x & 7;
  const int rs = blk >> 1, ch = blk & 1;
  const int r0 = rs*8, c0 = ch*16;

  // ---- stage x tile [3][12][20] (rows r0-2..r0+9, cols c0-2..c0+17) ----
  for (int j = t; j < 720; j += 256) {
    int ic = j / 240, rem = j % 240, rr = rem / 20, cx = rem % 20;
    int gy = r0 - 2 + rr, gx = c0 - 2 + cx;
    float v = 0.f;
    if (gy >= 0 && gy < 32 && gx >= 0 && gx < 32) v = x[b*3072 + ic*1024 + gy*32 + gx];
    sm[TF_X + j] = v;
  }
  for (int j = t; j < 864; j += 256) sm[TF_W1 + j] = tw1[j];
  if (t < 32) {
    sm[TF_BN + t] = tg1[t]*BN_RS;      sm[TF_BN + 32 + t] = tb1[t];
    sm[TF_BN + 64 + t] = tg2[t]*BN_RS; sm[TF_BN + 96 + t] = tb2[t];
  }
  __syncthreads();

  // ---- conv1: 320 items = (rr 10) x (oc 32), 18 cols each -> SA1 ----
  // summation order (ic, wr, kx) identical to R2/R5 conv1.
  {
    float acc1[18];
    for (int it = 0; it < 2; ++it) {
      const int item = it*256 + t;
      if (item < 320) {
        const int oc = item & 31, rr = item >> 5;
        const int gy = r0 - 1 + rr;
        #pragma unroll
        for (int c2 = 0; c2 < 18; ++c2) acc1[c2] = 0.f;
        if (gy >= 0 && gy < 32) {
          for (int ic = 0; ic < 3; ++ic) {
            float w[9];
            #pragma unroll
            for (int k = 0; k < 9; ++k) w[k] = sm[TF_W1 + oc*27 + ic*9 + k];
            #pragma unroll
            for (int wr = 0; wr < 3; ++wr) {
              float rv[20];
              const float4* rp = (const float4*)&sm[TF_X + ic*240 + (rr + wr)*20];
              #pragma unroll
              for (int j4 = 0; j4 < 5; ++j4) {
                float4 v4 = rp[j4];
                rv[4*j4] = v4.x; rv[4*j4+1] = v4.y; rv[4*j4+2] = v4.z; rv[4*j4+3] = v4.w;
              }
              #pragma unroll
              for (int c2 = 0; c2 < 18; ++c2)
                #pragma unroll
                for (int kx = 0; kx < 3; ++kx)
                  acc1[c2] = fmaf(w[wr*3 + kx], rv[c2 + kx], acc1[c2]);
            }
          }
        }
        const float s = sm[TF_BN + oc], bo = sm[TF_BN + 32 + oc];
        #pragma unroll
        for (int c2 = 0; c2 < 18; ++c2) {
          const int gx = c0 - 1 + c2;
          float v = 0.f;   // out-of-image conv1 output acts as conv2 zero pad
          if (gy >= 0 && gy < 32 && gx >= 0 && gx < 32)
            v = fmaxf(fmaf(acc1[c2], s, bo), 0.f);
          sm[TF_SA1 + oc*202 + rr*20 + c2] = v;
        }
      }
    }
  }
  __syncthreads();   // x tile / conv1 weights dead -> conv2 weight dbuf

  for (int j = t; j < 1152; j += 256) {    // w2 chunk 0
    int qq = j / 288, r = j % 288;
    sm[TF_WD + qq*296 + r] = tw2t[(qq*8)*288 + r];
  }
  __syncthreads();

  // ---- conv2: verbatim R5 trunkB loop on the LDS slab ----
  const int g = t >> 5, q = (t >> 3) & 3, cp = t & 7;
  float acc[4][8][2];
  #pragma unroll
  for (int o = 0; o < 4; ++o)
    #pragma unroll
    for (int r = 0; r < 8; ++r) { acc[o][r][0] = 0.f; acc[o][r][1] = 0.f; }

  for (int cc = 0; cc < 8; ++cc) {
    if (cc < 7) {
      for (int j = t; j < 1152; j += 256) {
        int qq = j / 288, r = j % 288;
        sm[TF_WD + ((cc+1)&1)*1184 + qq*296 + r] = tw2t[(qq*8 + cc+1)*288 + r];
      }
    }
    const float* wb = &sm[TF_WD + (cc&1)*1184 + q*296];
    float w[4][9];
    #pragma unroll
    for (int k = 0; k < 9; ++k) {
      float4 wv = *(const float4*)&wb[k*32 + 4*g];
      w[0][k] = wv.x; w[1][k] = wv.y; w[2][k] = wv.z; w[3][k] = wv.w;
    }
    const float* src = &sm[TF_SA1 + (q*8+cc)*202 + 2*cp];
    #pragma unroll
    for (int rr = 0; rr < 10; ++rr) {
      float2 va = *(const float2*)&src[rr*20];
      float2 vb = *(const float2*)&src[rr*20 + 2];
      const float i0 = va.x, i1 = va.y, i2 = vb.x, i3 = vb.y;
      #pragma unroll
      for (int dr = 0; dr < 3; ++dr) {
        const int r = rr - dr;
        if (r < 0 || r > 7) continue;
        #pragma unroll
        for (int o = 0; o < 4; ++o) {
          acc[o][r][0] = fmaf(w[o][dr*3+0], i0, acc[o][r][0]);
          acc[o][r][1] = fmaf(w[o][dr*3+0], i1, acc[o][r][1]);
          acc[o][r][0] = fmaf(w[o][dr*3+1], i1, acc[o][r][0]);
          acc[o][r][1] = fmaf(w[o][dr*3+1], i2, acc[o][r][1]);
          acc[o][r][0] = fmaf(w[o][dr*3+2], i2, acc[o][r][0]);
          acc[o][r][1] = fmaf(w[o][dr*3+2], i3, acc[o][r][1]);
        }
      }
    }
    __syncthreads();
  }

  // 4-way ic-split combine (verbatim R5; SA1/WD dead -> exchange overlay)
  const int slot = g*8 + cp;
  if (q >= 2) {
    float* dst = &sm[(q-2)*4168 + slot*65];
    #pragma unroll
    for (int o = 0; o < 4; ++o)
      #pragma unroll
      for (int r = 0; r < 8; ++r) {
        dst[o*16 + r*2 + 0] = acc[o][r][0];
        dst[o*16 + r*2 + 1] = acc[o][r][1];
      }
  }
  __syncthreads();
  if (q < 2) {
    const float* s0 = &sm[q*4168 + slot*65];
    #pragma unroll
    for (int o = 0; o < 4; ++o)
      #pragma unroll
      for (int r = 0; r < 8; ++r) {
        acc[o][r][0] += s0[o*16 + r*2 + 0];
        acc[o][r][1] += s0[o*16 + r*2 + 1];
      }
  }
  __syncthreads();
  if (q == 1) {
    float* dst = &sm[slot*65];
    #pragma unroll
    for (int o = 0; o < 4; ++o)
      #pragma unroll
      for (int r = 0; r < 8; ++r) {
        dst[o*16 + r*2 + 0] = acc[o][r][0];
        dst[o*16 + r*2 + 1] = acc[o][r][1];
      }
  }
  __syncthreads();
  if (q == 0) {
    const float* s0 = &sm[slot*65];
    #pragma unroll
    for (int o = 0; o < 4; ++o) {
      const int oc = 4*g + o;
      const float s = sm[TF_BN + 64 + oc], bo = sm[TF_BN + 96 + oc];
      float ps = 0.f;
      #pragma unroll
      for (int pr = 0; pr < 4; ++pr) {
        float c00 = acc[o][2*pr][0]   + s0[o*16 + (2*pr)*2 + 0];
        float c01 = acc[o][2*pr][1]   + s0[o*16 + (2*pr)*2 + 1];
        float c10 = acc[o][2*pr+1][0] + s0[o*16 + (2*pr+1)*2 + 0];
        float c11 = acc[o][2*pr+1][1] + s0[o*16 + (2*pr+1)*2 + 1];
        float v0 = fmaxf(fmaf(c00, s, bo), 0.f);
        float v1 = fmaxf(fmaf(c01, s, bo), 0.f);
        float v2 = fmaxf(fmaf(c10, s, bo), 0.f);
        float v3 = fmaxf(fmaf(c11, s, bo), 0.f);
        ps += fmaxf(fmaxf(v0, v1), fmaxf(v2, v3));
      }
      ps += __shfl_xor(ps, 1);
      ps += __shfl_xor(ps, 2);
      ps += __shfl_xor(ps, 4);
      if ((t & 31) == 0) tfp[b*256 + (rs*2 + ch)*32 + oc] = ps;
    }
  }
}

// ============================== gate + top2 ================================
__global__ __launch_bounds__(64) void gate_kernel(
    const float* __restrict__ tfp, const float* __restrict__ tfw, const float* __restrict__ tfb,
    const float* __restrict__ gw1, const float* __restrict__ gb1,
    const float* __restrict__ gw2, const float* __restrict__ gb2,
    float* __restrict__ outBal, int* __restrict__ tk)
{
  __shared__ float feat[128], rf[64], g1[32], bal[8];
  const int b = blockIdx.x, t = threadIdx.x;
  #pragma unroll
  for (int h = 0; h < 2; ++h) {
    const int f = t + 64*h;
    const int oc = f >> 2, qy = (f >> 1) & 1, qx = f & 1;
    feat[f] = (tfp[b*256 + (4*qy + qx)*32 + oc] +
               tfp[b*256 + (4*qy + 2 + qx)*32 + oc]) * (1.f/64.f);
  }
  __syncthreads();
  {
    float a = tfb[t];
    const float4* wp = (const float4*)&tfw[t*128];
    #pragma unroll 8
    for (int i4 = 0; i4 < 32; ++i4) {
      float4 wv = wp[i4];
      a = fmaf(wv.x, feat[4*i4], a);   a = fmaf(wv.y, feat[4*i4+1], a);
      a = fmaf(wv.z, feat[4*i4+2], a); a = fmaf(wv.w, feat[4*i4+3], a);
    }
    rf[t] = fmaxf(a, 0.f);
  }
  __syncthreads();
  if (t < 32) {
    float a = gb1[t];
    const float4* wp = (const float4*)&gw1[t*64];
    #pragma unroll
    for (int i4 = 0; i4 < 16; ++i4) {
      float4 wv = wp[i4];
      a = fmaf(wv.x, rf[4*i4], a);   a = fmaf(wv.y, rf[4*i4+1], a);
      a = fmaf(wv.z, rf[4*i4+2], a); a = fmaf(wv.w, rf[4*i4+3], a);
    }
    g1[t] = fmaxf(a, 0.f);
  }
  __syncthreads();
  if (t < 8) {
    float a = gb2[t];
    const float4* wp = (const float4*)&gw2[t*32];
    #pragma unroll
    for (int i4 = 0; i4 < 8; ++i4) {
      float4 wv = wp[i4];
      a = fmaf(wv.x, g1[4*i4], a);   a = fmaf(wv.y, g1[4*i4+1], a);
      a = fmaf(wv.z, g1[4*i4+2], a); a = fmaf(wv.w, g1[4*i4+3], a);
    }
    const float v = a - 0.25f;   // boost=0, -LOAD_PEN*usage = -0.25
    bal[t] = v;
    outBal[b*8 + t] = v;
  }
  __syncthreads();
  if (t == 0) {
    int t0 = 0; float b0 = bal[0];
    #pragma unroll
    for (int e2 = 1; e2 < 8; ++e2) if (bal[e2] > b0) { b0 = bal[e2]; t0 = e2; }
    int t1 = -1; float b1 = -3.4e38f;
    #pragma unroll
    for (int e2 = 0; e2 < 8; ++e2) if (e2 != t0 && bal[e2] > b1) { b1 = bal[e2]; t1 = e2; }
    tk[b*2] = t0; tk[b*2 + 1] = t1;
  }
}

// =================== serial capacity-constrained routing ===================
__global__ __launch_bounds__(256) void route_kernel(const int* __restrict__ tk,
                                                    int* __restrict__ chosen,
                                                    float* __restrict__ outD)
{
  __shared__ int stk[512];
  __shared__ int sch[256];
  const int t = threadIdx.x;
  stk[t] = tk[t]; stk[256 + t] = tk[256 + t];
  __syncthreads();
  if (t == 0) {
    float L0=0,L1=0,L2=0,L3=0,L4=0,L5=0,L6=0,L7=0;
    for (int i = 0; i < 256; ++i) {
      const int a = stk[2*i], c = stk[2*i+1];
      const float la = (a==0)?L0:(a==1)?L1:(a==2)?L2:(a==3)?L3:(a==4)?L4:(a==5)?L5:(a==6)?L6:L7;
      const float lc = (c==0)?L0:(c==1)?L1:(c==2)?L2:(c==3)?L3:(c==4)?L4:(c==5)?L5:(c==6)?L6:L7;
      const int ch = (la < 48.f) ? a : ((lc < 48.f) ? c : ((la <= lc) ? a : c));
      L0 += (ch==0)?1.f:0.f; L1 += (ch==1)?1.f:0.f; L2 += (ch==2)?1.f:0.f; L3 += (ch==3)?1.f:0.f;
      L4 += (ch==4)?1.f:0.f; L5 += (ch==5)?1.f:0.f; L6 += (ch==6)?1.f:0.f; L7 += (ch==7)?1.f:0.f;
      sch[i] = ch;
    }
  }
  __syncthreads();
  const int ch = sch[t];
  chosen[t] = ch;
  #pragma unroll
  for (int e2 = 0; e2 < 8; ++e2) outD[t*8 + e2] = (ch == e2) ? 1.f : 0.f;
}

// ===== expA: conv1 3->32 (32x32) + pool -> padded P1g [32][18][20] =========
// grid 1024 = b*4 + rowslab; 256 thr = g8(4oc) x c32
__global__ __launch_bounds__(256) void expA_kernel(
    const float* __restrict__ x, const int* __restrict__ chosen,
    const float* __restrict__ ew1, const float* __restrict__ eg1,
    const float* __restrict__ eb1, float* __restrict__ P1g)
{
  __shared__ __align__(16) float sxa[1020];
  __shared__ __align__(16) float sw1t[864];
  __shared__ float bs[32], bb[32];
  const int t = threadIdx.x;
  const int b = blockIdx.x >> 2, rs = blockIdx.x & 3;
  const int r0 = rs * 8;
  const int e = chosen[b];

  for (int j = t; j < 576; j += 256) {
    int idx = rs*576 + j;
    int ic = idx / 72, r2 = idx % 72, row, col;
    if (r2 < 20)      { row = 0;  col = r2; }
    else if (r2 < 40) { row = 17; col = r2 - 20; }
    else if (r2 < 56) { row = 1 + (r2 - 40); col = 0; }
    else              { row = 1 + (r2 - 56); col = 17; }
    P1g[b*11520 + ic*360 + row*20 + col] = 0.f;
  }
  for (int j = t; j < 1020; j += 256) {
    int ic = j / 340, r = (j % 340) / 34, cxx = j % 34;
    int gy = r0 - 1 + r, gx = cxx - 1;
    float v = 0.f;
    if (gy >= 0 && gy < 32 && gx >= 0 && gx < 32) v = x[b*3072 + ic*1024 + gy*32 + gx];
    sxa[j] = v;
  }
  for (int j = t; j < 864; j += 256) {
    int oc = j / 27, r = j % 27, ic = r / 9, k = r % 9;
    sw1t[ic*288 + k*32 + oc] = ew1[e*864 + j];
  }
  if (t < 32) { bs[t] = eg1[e*32 + t]*BN_RS; bb[t] = eb1[e*32 + t]; }
  __syncthreads();

  const int g = t >> 5, c = t & 31;
  float acc[4][8];
  #pragma unroll
  for (int o = 0; o < 4; ++o)
    #pragma unroll
    for (int r = 0; r < 8; ++r) acc[o][r] = 0.f;

  for (int ic = 0; ic < 3; ++ic) {
    float w[4][9];
    #pragma unroll
    for (int k = 0; k < 9; ++k) {
      float4 wv = *(const float4*)&sw1t[ic*288 + k*32 + 4*g];
      w[0][k] = wv.x; w[1][k] = wv.y; w[2][k] = wv.z; w[3][k] = wv.w;
    }
    const float* src = &sxa[ic*340 + c];
    #pragma unroll
    for (int rr = 0; rr < 10; ++rr) {
      const float i0 = src[rr*34], i1 = src[rr*34 + 1], i2 = src[rr*34 + 2];
      #pragma unroll
      for (int dr = 0; dr < 3; ++dr) {
        const int r = rr - dr;
        if (r < 0 || r > 7) continue;
        #pragma unroll
        for (int o = 0; o < 4; ++o) {
          acc[o][r] = fmaf(w[o][dr*3+0], i0, acc[o][r]);
          acc[o][r] = fmaf(w[o][dr*3+1], i1, acc[o][r]);
          acc[o][r] = fmaf(w[o][dr*3+2], i2, acc[o][r]);
        }
      }
    }
  }
  #pragma unroll
  for (int o = 0; o < 4; ++o) {
    const int oc = 4*g + o;
    const float s = bs[oc], bo = bb[oc];
    float m[4];
    #pragma unroll
    for (int pr = 0; pr < 4; ++pr) {
      float v0 = fmaxf(fmaf(acc[o][2*pr],   s, bo), 0.f);
      float v1 = fmaxf(fmaf(acc[o][2*pr+1], s, bo), 0.f);
      m[pr] = fmaxf(v0, v1);
    }
    #pragma unroll
    for (int pr = 0; pr < 4; ++pr) {
      float nb = __shfl_xor(m[pr], 1);
      m[pr] = fmaxf(m[pr], nb);
    }
    if (!(c & 1)) {
      const int pc = c >> 1;
      #pragma unroll
      for (int pr = 0; pr < 4; ++pr)
        P1g[b*11520 + oc*360 + (rs*4 + pr + 1)*20 + pc + 1] = m[pr];
    }
  }
}

// ====== expB: conv2 32->64 (16x16) + pool -> padded P2g [64][10][12] =======
// grid 1024 = b*4 + (och(2)*2 + rs(2)); 256 thr = g8 x q4 x cp8
#define TB_SLAB 0      // [32ic] stride 202 ([10r][20c] data)
#define TB_WD   6464   // dbuf 2 x [4q stride 296][9][32oc]
#define TB_BN   8832   // 64
__global__ __launch_bounds__(256, 4) void expB_kernel(
    const int* __restrict__ chosen, const float* __restrict__ P1g,
    const float* __restrict__ ew2t, const float* __restrict__ eg2,
    const float* __restrict__ eb2, float* __restrict__ P2g)
{
  __shared__ __align__(16) float sm[8896];
  const int t = threadIdx.x;
  const int b = blockIdx.x >> 2, blk = blockIdx.x & 3;
  const int och = blk >> 1, rs = blk & 1;
  const int r0 = rs*8;
  const int e = chosen[b];

  for (int j = t; j < 640; j += 256) {
    int idx = blk*640 + j;
    int ic = idx / 40, r2 = idx % 40, row, col;
    if (r2 < 12)      { row = 0; col = r2; }
    else if (r2 < 24) { row = 9; col = r2 - 12; }
    else if (r2 < 32) { row = 1 + (r2 - 24); col = 0; }
    else              { row = 1 + (r2 - 32); col = 9; }
    P2g[b*7680 + ic*120 + row*12 + col] = 0.f;
  }
  for (int j = t; j < 1600; j += 256) {
    int ic = j / 50, rem = j % 50, rr = rem / 5, c4 = rem % 5;
    float4 v = *(const float4*)&P1g[b*11520 + ic*360 + (r0+rr)*20 + 4*c4];
    float* d = &sm[TB_SLAB + ic*202 + rr*20 + 4*c4];
    d[0] = v.x; d[1] = v.y; d[2] = v.z; d[3] = v.w;
  }
  for (int j = t; j < 1152; j += 256) {
    int qq = j / 288, r = j % 288, k = r / 32, ocl = r & 31;
    sm[TB_WD + qq*296 + r] = ew2t[e*18432 + (qq*8)*576 + k*64 + och*32 + ocl];
  }
  if (t < 32) {
    sm[TB_BN + t] = eg2[e*64 + och*32 + t]*BN_RS;
    sm[TB_BN + 32 + t] = eb2[e*64 + och*32 + t];
  }
  __syncthreads();

  const int g = t >> 5, q = (t >> 3) & 3, cp = t & 7;
  float acc[4][8][2];
  #pragma unroll
  for (int o = 0; o < 4; ++o)
    #pragma unroll
    for (int r = 0; r < 8; ++r) { acc[o][r][0] = 0.f; acc[o][r][1] = 0.f; }

  for (int cc = 0; cc < 8; ++cc) {
    if (cc < 7) {
      for (int j = t; j < 1152; j += 256) {
        int qq = j / 288, r = j % 288, k = r / 32, ocl = r & 31;
        sm[TB_WD + ((cc+1)&1)*1184 + qq*296 + r] =
            ew2t[e*18432 + (qq*8 + cc+1)*576 + k*64 + och*32 + ocl];
      }
    }
    const float* wb = &sm[TB_WD + (cc&1)*1184 + q*296];
    float w[4][9];
    #pragma unroll
    for (int k = 0; k < 9; ++k) {
      float4 wv = *(const float4*)&wb[k*32 + 4*g];
      w[0][k] = wv.x; w[1][k] = wv.y; w[2][k] = wv.z; w[3][k] = wv.w;
    }
    const float* src = &sm[TB_SLAB + (q*8+cc)*202 + 2*cp];
    #pragma unroll
    for (int rr = 0; rr < 10; ++rr) {
      float2 va = *(const float2*)&src[rr*20];
      float2 vb = *(const float2*)&src[rr*20 + 2];
      const float i0 = va.x, i1 = va.y, i2 = vb.x, i3 = vb.y;
      #pragma unroll
      for (int dr = 0; dr < 3; ++dr) {
        const int r = rr - dr;
        if (r < 0 || r > 7) continue;
        #pragma unroll
        for (int o = 0; o < 4; ++o) {
          acc[o][r][0] = fmaf(w[o][dr*3+0], i0, acc[o][r][0]);
          acc[o][r][1] = fmaf(w[o][dr*3+0], i1, acc[o][r][1]);
          acc[o][r][0] = fmaf(w[o][dr*3+1], i1, acc[o][r][0]);
          acc[o][r][1] = fmaf(w[o][dr*3+1], i2, acc[o][r][1]);
          acc[o][r][0] = fmaf(w[o][dr*3+2], i2, acc[o][r][0]);
          acc[o][r][1] = fmaf(w[o][dr*3+2], i3, acc[o][r][1]);
        }
      }
    }
    __syncthreads();
  }

  const int slot = g*8 + cp;
  if (q >= 2) {
    float* dst = &sm[(q-2)*4168 + slot*65];
    #pragma unroll
    for (int o = 0; o < 4; ++o)
      #pragma unroll
      for (int r = 0; r < 8; ++r) {
        dst[o*16 + r*2 + 0] = acc[o][r][0];
        dst[o*16 + r*2 + 1] = acc[o][r][1];
      }
  }
  __syncthreads();
  if (q < 2) {
    const float* s0 = &sm[q*4168 + slot*65];
    #pragma unroll
    for (int o = 0; o < 4; ++o)
      #pragma unroll
      for (int r = 0; r < 8; ++r) {
        acc[o][r][0] += s0[o*16 + r*2 + 0];
        acc[o][r][1] += s0[o*16 + r*2 + 1];
      }
  }
  __syncthreads();
  if (q == 1) {
    float* dst = &sm[slot*65];
    #pragma unroll
    for (int o = 0; o < 4; ++o)
      #pragma unroll
      for (int r = 0; r < 8; ++r) {
        dst[o*16 + r*2 + 0] = acc[o][r][0];
        dst[o*16 + r*2 + 1] = acc[o][r][1];
      }
  }
  __syncthreads();
  if (q == 0) {
    const float* s0 = &sm[slot*65];
    #pragma unroll
    for (int o = 0; o < 4; ++o) {
      const int ocl = 4*g + o;
      const float s = sm[TB_BN + ocl], bo = sm[TB_BN + 32 + ocl];
      #pragma unroll
      for (int pr = 0; pr < 4; ++pr) {
        float c00 = acc[o][2*pr][0]   + s0[o*16 + (2*pr)*2 + 0];
        float c01 = acc[o][2*pr][1]   + s0[o*16 + (2*pr)*2 + 1];
        float c10 = acc[o][2*pr+1][0] + s0[o*16 + (2*pr+1)*2 + 0];
        float c11 = acc[o][2*pr+1][1] + s0[o*16 + (2*pr+1)*2 + 1];
        float v0 = fmaxf(fmaf(c00, s, bo), 0.f);
        float v1 = fmaxf(fmaf(c01, s, bo), 0.f);
        float v2 = fmaxf(fmaf(c10, s, bo), 0.f);
        float v3 = fmaxf(fmaf(c11, s, bo), 0.f);
        float m = fmaxf(fmaxf(v0, v1), fmaxf(v2, v3));
        P2g[b*7680 + (och*32 + ocl)*120 + (rs*4 + pr + 1)*12 + cp + 1] = m;
      }
    }
  }
}

// ====== expC: conv3 64->128 (8x8) + bn/relu + GAP -> featg =================
// grid 1024 = b*4 + ocq; 256 thr = g8(4oc) x qq8(8ic) x cp4(2c)
#define XC_SLAB 0      // [8 grp stride 968][8ic stride 120]([10r][12c])
#define XC_WD   7744   // dbuf 2 x [8qq stride 296][9][32oc]
#define XC_BN   12480  // 64
__global__ __launch_bounds__(256, 4) void expC_kernel(
    const int* __restrict__ chosen, const float* __restrict__ P2g,
    const float* __restrict__ ew3t, const float* __restrict__ eg3,
    const float* __restrict__ eb3, float* __restrict__ featg)
{
  __shared__ __align__(16) float sm[12544];
  const int t = threadIdx.x;
  const int b = blockIdx.x >> 2, ocq = blockIdx.x & 3;
  const int e = chosen[b];

  for (int j = t; j < 1920; j += 256) {
    int ic = j / 30, rem = j % 30, rr = rem / 3, c4 = rem % 3;
    float4 v = *(const float4*)&P2g[b*7680 + ic*120 + rr*12 + 4*c4];
    float* d = &sm[XC_SLAB + (ic >> 3)*968 + (ic & 7)*120 + rr*12 + 4*c4];
    d[0] = v.x; d[1] = v.y; d[2] = v.z; d[3] = v.w;
  }
  for (int j = t; j < 2304; j += 256) {
    int qq = j / 288, r = j % 288, k = r / 32, ocl = r & 31;
    sm[XC_WD + qq*296 + r] = ew3t[e*73728 + (qq*8)*1152 + k*128 + ocq*32 + ocl];
  }
  if (t < 32) {
    sm[XC_BN + t] = eg3[e*128 + ocq*32 + t]*BN_RS;
    sm[XC_BN + 32 + t] = eb3[e*128 + ocq*32 + t];
  }
  __syncthreads();

  const int g = t >> 5, qq = (t >> 2) & 7, cp = t & 3;
  float acc[4][8][2];
  #pragma unroll
  for (int o = 0; o < 4; ++o)
    #pragma unroll
    for (int r = 0; r < 8; ++r) { acc[o][r][0] = 0.f; acc[o][r][1] = 0.f; }

  for (int cc = 0; cc < 8; ++cc) {
    if (cc < 7) {
      for (int j = t; j < 2304; j += 256) {
        int q2 = j / 288, r = j % 288, k = r / 32, ocl = r & 31;
        sm[XC_WD + ((cc+1)&1)*2368 + q2*296 + r] =
            ew3t[e*73728 + (q2*8 + cc+1)*1152 + k*128 + ocq*32 + ocl];
      }
    }
    const float* wb = &sm[XC_WD + (cc&1)*2368 + qq*296];
    float w[4][9];
    #pragma unroll
    for (int k = 0; k < 9; ++k) {
      float4 wv = *(const float4*)&wb[k*32 + 4*g];
      w[0][k] = wv.x; w[1][k] = wv.y; w[2][k] = wv.z; w[3][k] = wv.w;
    }
    const float* src = &sm[XC_SLAB + qq*968 + cc*120 + 2*cp];
    #pragma unroll
    for (int rr = 0; rr < 10; ++rr) {
      float2 va = *(const float2*)&src[rr*12];
      float2 vb = *(const float2*)&src[rr*12 + 2];
      const float i0 = va.x, i1 = va.y, i2 = vb.x, i3 = vb.y;
      #pragma unroll
      for (int dr = 0; dr < 3; ++dr) {
        const int r = rr - dr;
        if (r < 0 || r > 7) continue;
        #pragma unroll
        for (int o = 0; o < 4; ++o) {
          acc[o][r][0] = fmaf(w[o][dr*3+0], i0, acc[o][r][0]);
          acc[o][r][1] = fmaf(w[o][dr*3+0], i1, acc[o][r][1]);
          acc[o][r][0] = fmaf(w[o][dr*3+1], i1, acc[o][r][0]);
          acc[o][r][1] = fmaf(w[o][dr*3+1], i2, acc[o][r][1]);
          acc[o][r][0] = fmaf(w[o][dr*3+2], i2, acc[o][r][0]);
          acc[o][r][1] = fmaf(w[o][dr*3+2], i3, acc[o][r][1]);
        }
      }
    }
    __syncthreads();
  }

  // 8-way ic-split combine (3 steps), regions stride 2088
  const int slot = g*4 + cp;
  if (qq >= 4) {
    float* dst = &sm[(qq-4)*2088 + slot*65];
    #pragma unroll
    for (int o = 0; o < 4; ++o)
      #pragma unroll
      for (int r = 0; r < 8; ++r) {
        dst[o*16 + r*2 + 0] = acc[o][r][0];
        dst[o*16 + r*2 + 1] = acc[o][r][1];
      }
  }
  __syncthreads();
  if (qq < 4) {
    const float* s0 = &sm[qq*2088 + slot*65];
    #pragma unroll
    for (int o = 0; o < 4; ++o)
      #pragma unroll
      for (int r = 0; r < 8; ++r) {
        acc[o][r][0] += s0[o*16 + r*2 + 0];
        acc[o][r][1] += s0[o*16 + r*2 + 1];
      }
  }
  __syncthreads();
  if (qq == 2 || qq == 3) {
    float* dst = &sm[(qq-2)*2088 + slot*65];
    #pragma unroll
    for (int o = 0; o < 4; ++o)
      #pragma unroll
      for (int r = 0; r < 8; ++r) {
        dst[o*16 + r*2 + 0] = acc[o][r][0];
        dst[o*16 + r*2 + 1] = acc[o][r][1];
      }
  }
  __syncthreads();
  if (qq < 2) {
    const float* s0 = &sm[qq*2088 + slot*65];
    #pragma unroll
    for (int o = 0; o < 4; ++o)
      #pragma unroll
      for (int r = 0; r < 8; ++r) {
        acc[o][r][0] += s0[o*16 + r*2 + 0];
        acc[o][r][1] += s0[o*16 + r*2 + 1];
      }
  }
  __syncthreads();
  if (qq == 1) {
    float* dst = &sm[slot*65];
    #pragma unroll
    for (int o = 0; o < 4; ++o)
      #pragma unroll
      for (int r = 0; r < 8; ++r) {
        dst[o*16 + r*2 + 0] = acc[o][r][0];
        dst[o*16 + r*2 + 1] = acc[o][r][1];
      }
  }
  __syncthreads();
  if (qq == 0) {
    const float* s0 = &sm[slot*65];
    #pragma unroll
    for (int o = 0; o < 4; ++o) {
      const int ocl = 4*g + o;
      const float s = sm[XC_BN + ocl], bo = sm[XC_BN + 32 + ocl];
      float gsum = 0.f;
      #pragma unroll
      for (int r = 0; r < 8; ++r) {
        float c0 = acc[o][r][0] + s0[o*16 + r*2 + 0];
        float c1 = acc[o][r][1] + s0[o*16 + r*2 + 1];
        gsum += fmaxf(fmaf(c0, s, bo), 0.f);
        gsum += fmaxf(fmaf(c1, s, bo), 0.f);
      }
      gsum += __shfl_xor(gsum, 1);
      gsum += __shfl_xor(gsum, 2);
      if ((t & 31) == 0) featg[b*128 + ocq*32 + ocl] = gsum * (1.f/64.f);
    }
  }
}

// ================= expD: FC chain -> final =================================
__global__ __launch_bounds__(128) void expD_kernel(
    const int* __restrict__ chosen, const float* __restrict__ featg,
    const float* __restrict__ efw, const float* __restrict__ efb,
    const float* __restrict__ cw1, const float* __restrict__ cb1,
    const float* __restrict__ cw2, const float* __restrict__ cb2,
    float* __restrict__ outF)
{
  __shared__ float sf[128], sff[128], sgg[64];
  const int b = blockIdx.x, t = threadIdx.x;
  const int e = chosen[b];
  sf[t] = featg[b*128 + t];
  __syncthreads();
  {
    float a = efb[e*128 + t];
    const float4* wp = (const float4*)&efw[e*16384 + t*128];
    #pragma unroll 8
    for (int i4 = 0; i4 < 32; ++i4) {
      float4 wv = wp[i4];
      a = fmaf(wv.x, sf[4*i4], a);   a = fmaf(wv.y, sf[4*i4+1], a);
      a = fmaf(wv.z, sf[4*i4+2], a); a = fmaf(wv.w, sf[4*i4+3], a);
    }
    sff[t] = fmaxf(a, 0.f);
  }
  __syncthreads();
  if (t < 64) {
    float a = cb1[e*64 + t];
    const float4* wp = (const float4*)&cw1[e*8192 + t*128];
    #pragma unroll 8
    for (int i4 = 0; i4 < 32; ++i4) {
      float4 wv = wp[i4];
      a = fmaf(wv.x, sff[4*i4], a);   a = fmaf(wv.y, sff[4*i4+1], a);
      a = fmaf(wv.z, sff[4*i4+2], a); a = fmaf(wv.w, sff[4*i4+3], a);
    }
    sgg[t] = fmaxf(a, 0.f);
  }
  __syncthreads();
  if (t < 10) {
    float a = cb2[e*10 + t];
    const float4* wp = (const float4*)&cw2[e*640 + t*64];
    #pragma unroll
    for (int i4 = 0; i4 < 16; ++i4) {
      float4 wv = wp[i4];
      a = fmaf(wv.x, sgg[4*i4], a);   a = fmaf(wv.y, sgg[4*i4+1], a);
      a = fmaf(wv.z, sgg[4*i4+2], a); a = fmaf(wv.w, sgg[4*i4+3], a);
    }
    outF[b*10 + t] = a;   // routing weight is exactly 1.0 for the chosen expert
  }
}

// ================================ host =====================================
extern "C" void kernel_launch(void* const* d_in, const int* in_sizes, int n_in,
                              void* d_out, int out_size, void* d_ws, size_t ws_size,
                              hipStream_t stream)
{
  const float* x   = (const float*)d_in[0];
  const float* tw1 = (const float*)d_in[1];
  const float* tg1 = (const float*)d_in[2];
  const float* tb1 = (const float*)d_in[3];
  const float* tw2 = (const float*)d_in[4];
  const float* tg2 = (const float*)d_in[5];
  const float* tb2 = (const float*)d_in[6];
  const float* tfw = (const float*)d_in[7];
  const float* tfb = (const float*)d_in[8];
  const float* gw1 = (const float*)d_in[9];
  const float* gb1 = (const float*)d_in[10];
  const float* gw2 = (const float*)d_in[11];
  const float* gb2 = (const float*)d_in[12];
  const float* ew1 = (const float*)d_in[13];
  const float* eg1 = (const float*)d_in[14];
  const float* eb1 = (const float*)d_in[15];
  const float* ew2 = (const float*)d_in[16];
  const float* eg2 = (const float*)d_in[17];
  const float* eb2 = (const float*)d_in[18];
  const float* ew3 = (const float*)d_in[19];
  const float* eg3 = (const float*)d_in[20];
  const float* eb3 = (const float*)d_in[21];
  const float* efw = (const float*)d_in[22];
  const float* efb = (const float*)d_in[23];
  const float* cw1 = (const float*)d_in[24];
  const float* cb1 = (const float*)d_in[25];
  const float* cw2 = (const float*)d_in[26];
  const float* cb2 = (const float*)d_in[27];

  float* out    = (float*)d_out;
  char*  ws     = (char*)d_ws;
  float* tfp    = (float*)(ws + WS_TFP);
  int*   tk     = (int*)(ws + WS_TK);
  int*   chosen = (int*)(ws + WS_CHOSEN);
  float* tw2t   = (float*)(ws + WS_TW2T);
  float* ew2t   = (float*)(ws + WS_EW2T);
  float* ew3t   = (float*)(ws + WS_EW3T);
  float* featg  = (float*)(ws + WS_FEATG);
  float* P1g    = (float*)(ws + WS_P1G);
  float* P2g    = (float*)(ws + WS_P2G);

  prep_kernel<<<2916, 256, 0, stream>>>(tw2, ew2, ew3, tw2t, ew2t, ew3t);
  trunk_kernel<<<2048, 256, 0, stream>>>(x, tw1, tg1, tb1, tw2t, tg2, tb2, tfp);
  gate_kernel<<<256, 64, 0, stream>>>(tfp, tfw, tfb, gw1, gb1, gw2, gb2, out + 2560, tk);
  route_kernel<<<1, 256, 0, stream>>>(tk, chosen, out + 4608);
  expA_kernel<<<1024, 256, 0, stream>>>(x, chosen, ew1, eg1, eb1, P1g);
  expB_kernel<<<1024, 256, 0, stream>>>(chosen, P1g, ew2t, eg2, eb2, P2g);
  expC_kernel<<<1024, 256, 0, stream>>>(chosen, P2g, ew3t, eg3, eb3, featg);
  expD_kernel<<<256, 128, 0, stream>>>(chosen, featg, efw, efb, cw1, cb1, cw2, cb2, out);
}

// Round 7
// 386.079 us; speedup vs baseline: 1.1445x; 1.1114x over previous
//
#include <hip/hip_runtime.h>
#include <hip/hip_bf16.h>
#include <math.h>

// ---------------------------------------------------------------------------
// DistributedMoE forward, MI355X — R7: expC -> bf16 MFMA implicit GEMM.
// R6 lesson: the fp32 conv template plateaus (VALU 57%, LDS ~50%, rest
// barriers) at ~90-110us per conv kernel. Expert convs are matmul-shaped
// (K=576 for conv3) -> matrix cores. bf16 enters ONLY the post-routing
// expert path (budget 2.3e-2); trunk/gate/routing stay fp32-exact.
// expC as 9-tap implicit GEMM: C[64x128] += A_tap[64x64] * W_tap[64x128],
// A_tap = shifted P2 image in LDS bf16 [row][col][ic] (slot stride 72).
// GAP epilogue is invariant to lane->m permutation, shrinking layout risk
// to the A/B operand roles only.
//
// out (fp32): final[256,10] @0, balanced[256,8] @2560, D[256,8] @4608
// ---------------------------------------------------------------------------

#define BN_RS (1.0f / sqrtf(1.00001f))

typedef __attribute__((ext_vector_type(8))) short short8;
typedef __attribute__((ext_vector_type(4))) float floatx4;

static __device__ __forceinline__ ushort f2bf(float f) {
  unsigned u = __float_as_uint(f);
  unsigned r = (u + 0x7fffu + ((u >> 16) & 1u)) >> 16;   // RNE
  return (ushort)r;
}

// ws byte offsets (16B aligned)
#define WS_TFP    0           // f32[256][8][32]
#define WS_TK     262144      // i32[512]
#define WS_CHOSEN 264192      // i32[256]
#define WS_TW2T   265216      // f32[32ic][9][32oc]
#define WS_EW2T   302080      // f32[8][32ic][9][64oc]
#define WS_EW3B   891904      // bf16[8][9tap][128oc][64ic]
#define WS_FEATG  2071552     // f32[256*128]
#define WS_P1G    2202624     // f32[256][32][18][20] padded
#define WS_P2GT   13999104    // bf16[256][10][10][64]  (padded, borders zero)

// =================== prep: weight transposes ===============================
__global__ __launch_bounds__(256) void prep_kernel(
    const float* __restrict__ tw2, const float* __restrict__ ew2,
    const float* __restrict__ ew3, float* __restrict__ tw2t,
    float* __restrict__ ew2t, ushort* __restrict__ ew3b)
{
  const int j = blockIdx.x * 256 + threadIdx.x;
  if (j < 9216) {
    int ic = j / 288, rem = j % 288, k = rem / 32, oc = rem % 32;
    tw2t[j] = tw2[oc*288 + ic*9 + k];
  } else if (j < 156672) {
    int jj = j - 9216;
    int e = jj / 18432, r2 = jj % 18432, ic = r2 / 576, r3 = r2 % 576;
    int k = r3 / 64, oc = r3 % 64;
    ew2t[jj] = ew2[e*18432 + oc*288 + ic*9 + k];
  } else if (j < 746496) {
    int jj = j - 156672;
    int e = jj / 73728, r2 = jj % 73728;
    int tap = r2 / 8192, r3 = r2 % 8192;
    int oc = r3 / 64, ic = r3 % 64;
    ew3b[jj] = f2bf(ew3[e*73728 + oc*576 + ic*9 + tap]);
  }
}

// ====== fused trunk: conv1 (in-LDS) + conv2 + pool + partial sums ==========
// (unchanged from R6 — fp32, routing-critical digits preserved)
#define TF_SA1 0
#define TF_WD  6464
#define TF_X   6464
#define TF_W1  7184
#define TF_BN  8832
__global__ __launch_bounds__(256, 4) void trunk_kernel(
    const float* __restrict__ x, const float* __restrict__ tw1,
    const float* __restrict__ tg1, const float* __restrict__ tb1,
    const float* __restrict__ tw2t, const float* __restrict__ tg2,
    const float* __restrict__ tb2, float* __restrict__ tfp)
{
  __shared__ __align__(16) float sm[8960];
  const int t = threadIdx.x;
  const int b = blockIdx.x >> 3, blk = blockIdx.x & 7;
  const int rs = blk >> 1, ch = blk & 1;
  const int r0 = rs*8, c0 = ch*16;

  for (int j = t; j < 720; j += 256) {
    int ic = j / 240, rem = j % 240, rr = rem / 20, cx = rem % 20;
    int gy = r0 - 2 + rr, gx = c0 - 2 + cx;
    float v = 0.f;
    if (gy >= 0 && gy < 32 && gx >= 0 && gx < 32) v = x[b*3072 + ic*1024 + gy*32 + gx];
    sm[TF_X + j] = v;
  }
  for (int j = t; j < 864; j += 256) sm[TF_W1 + j] = tw1[j];
  if (t < 32) {
    sm[TF_BN + t] = tg1[t]*BN_RS;      sm[TF_BN + 32 + t] = tb1[t];
    sm[TF_BN + 64 + t] = tg2[t]*BN_RS; sm[TF_BN + 96 + t] = tb2[t];
  }
  __syncthreads();

  {
    float acc1[18];
    for (int it = 0; it < 2; ++it) {
      const int item = it*256 + t;
      if (item < 320) {
        const int oc = item & 31, rr = item >> 5;
        const int gy = r0 - 1 + rr;
        #pragma unroll
        for (int c2 = 0; c2 < 18; ++c2) acc1[c2] = 0.f;
        if (gy >= 0 && gy < 32) {
          for (int ic = 0; ic < 3; ++ic) {
            float w[9];
            #pragma unroll
            for (int k = 0; k < 9; ++k) w[k] = sm[TF_W1 + oc*27 + ic*9 + k];
            #pragma unroll
            for (int wr = 0; wr < 3; ++wr) {
              float rv[20];
              const float4* rp = (const float4*)&sm[TF_X + ic*240 + (rr + wr)*20];
              #pragma unroll
              for (int j4 = 0; j4 < 5; ++j4) {
                float4 v4 = rp[j4];
                rv[4*j4] = v4.x; rv[4*j4+1] = v4.y; rv[4*j4+2] = v4.z; rv[4*j4+3] = v4.w;
              }
              #pragma unroll
              for (int c2 = 0; c2 < 18; ++c2)
                #pragma unroll
                for (int kx = 0; kx < 3; ++kx)
                  acc1[c2] = fmaf(w[wr*3 + kx], rv[c2 + kx], acc1[c2]);
            }
          }
        }
        const float s = sm[TF_BN + oc], bo = sm[TF_BN + 32 + oc];
        #pragma unroll
        for (int c2 = 0; c2 < 18; ++c2) {
          const int gx = c0 - 1 + c2;
          float v = 0.f;
          if (gy >= 0 && gy < 32 && gx >= 0 && gx < 32)
            v = fmaxf(fmaf(acc1[c2], s, bo), 0.f);
          sm[TF_SA1 + oc*202 + rr*20 + c2] = v;
        }
      }
    }
  }
  __syncthreads();

  for (int j = t; j < 1152; j += 256) {
    int qq = j / 288, r = j % 288;
    sm[TF_WD + qq*296 + r] = tw2t[(qq*8)*288 + r];
  }
  __syncthreads();

  const int g = t >> 5, q = (t >> 3) & 3, cp = t & 7;
  float acc[4][8][2];
  #pragma unroll
  for (int o = 0; o < 4; ++o)
    #pragma unroll
    for (int r = 0; r < 8; ++r) { acc[o][r][0] = 0.f; acc[o][r][1] = 0.f; }

  for (int cc = 0; cc < 8; ++cc) {
    if (cc < 7) {
      for (int j = t; j < 1152; j += 256) {
        int qq = j / 288, r = j % 288;
        sm[TF_WD + ((cc+1)&1)*1184 + qq*296 + r] = tw2t[(qq*8 + cc+1)*288 + r];
      }
    }
    const float* wb = &sm[TF_WD + (cc&1)*1184 + q*296];
    float w[4][9];
    #pragma unroll
    for (int k = 0; k < 9; ++k) {
      float4 wv = *(const float4*)&wb[k*32 + 4*g];
      w[0][k] = wv.x; w[1][k] = wv.y; w[2][k] = wv.z; w[3][k] = wv.w;
    }
    const float* src = &sm[TF_SA1 + (q*8+cc)*202 + 2*cp];
    #pragma unroll
    for (int rr = 0; rr < 10; ++rr) {
      float2 va = *(const float2*)&src[rr*20];
      float2 vb = *(const float2*)&src[rr*20 + 2];
      const float i0 = va.x, i1 = va.y, i2 = vb.x, i3 = vb.y;
      #pragma unroll
      for (int dr = 0; dr < 3; ++dr) {
        const int r = rr - dr;
        if (r < 0 || r > 7) continue;
        #pragma unroll
        for (int o = 0; o < 4; ++o) {
          acc[o][r][0] = fmaf(w[o][dr*3+0], i0, acc[o][r][0]);
          acc[o][r][1] = fmaf(w[o][dr*3+0], i1, acc[o][r][1]);
          acc[o][r][0] = fmaf(w[o][dr*3+1], i1, acc[o][r][0]);
          acc[o][r][1] = fmaf(w[o][dr*3+1], i2, acc[o][r][1]);
          acc[o][r][0] = fmaf(w[o][dr*3+2], i2, acc[o][r][0]);
          acc[o][r][1] = fmaf(w[o][dr*3+2], i3, acc[o][r][1]);
        }
      }
    }
    __syncthreads();
  }

  const int slot = g*8 + cp;
  if (q >= 2) {
    float* dst = &sm[(q-2)*4168 + slot*65];
    #pragma unroll
    for (int o = 0; o < 4; ++o)
      #pragma unroll
      for (int r = 0; r < 8; ++r) {
        dst[o*16 + r*2 + 0] = acc[o][r][0];
        dst[o*16 + r*2 + 1] = acc[o][r][1];
      }
  }
  __syncthreads();
  if (q < 2) {
    const float* s0 = &sm[q*4168 + slot*65];
    #pragma unroll
    for (int o = 0; o < 4; ++o)
      #pragma unroll
      for (int r = 0; r < 8; ++r) {
        acc[o][r][0] += s0[o*16 + r*2 + 0];
        acc[o][r][1] += s0[o*16 + r*2 + 1];
      }
  }
  __syncthreads();
  if (q == 1) {
    float* dst = &sm[slot*65];
    #pragma unroll
    for (int o = 0; o < 4; ++o)
      #pragma unroll
      for (int r = 0; r < 8; ++r) {
        dst[o*16 + r*2 + 0] = acc[o][r][0];
        dst[o*16 + r*2 + 1] = acc[o][r][1];
      }
  }
  __syncthreads();
  if (q == 0) {
    const float* s0 = &sm[slot*65];
    #pragma unroll
    for (int o = 0; o < 4; ++o) {
      const int oc = 4*g + o;
      const float s = sm[TF_BN + 64 + oc], bo = sm[TF_BN + 96 + oc];
      float ps = 0.f;
      #pragma unroll
      for (int pr = 0; pr < 4; ++pr) {
        float c00 = acc[o][2*pr][0]   + s0[o*16 + (2*pr)*2 + 0];
        float c01 = acc[o][2*pr][1]   + s0[o*16 + (2*pr)*2 + 1];
        float c10 = acc[o][2*pr+1][0] + s0[o*16 + (2*pr+1)*2 + 0];
        float c11 = acc[o][2*pr+1][1] + s0[o*16 + (2*pr+1)*2 + 1];
        float v0 = fmaxf(fmaf(c00, s, bo), 0.f);
        float v1 = fmaxf(fmaf(c01, s, bo), 0.f);
        float v2 = fmaxf(fmaf(c10, s, bo), 0.f);
        float v3 = fmaxf(fmaf(c11, s, bo), 0.f);
        ps += fmaxf(fmaxf(v0, v1), fmaxf(v2, v3));
      }
      ps += __shfl_xor(ps, 1);
      ps += __shfl_xor(ps, 2);
      ps += __shfl_xor(ps, 4);
      if ((t & 31) == 0) tfp[b*256 + (rs*2 + ch)*32 + oc] = ps;
    }
  }
}

// ============================== gate + top2 ================================
__global__ __launch_bounds__(64) void gate_kernel(
    const float* __restrict__ tfp, const float* __restrict__ tfw, const float* __restrict__ tfb,
    const float* __restrict__ gw1, const float* __restrict__ gb1,
    const float* __restrict__ gw2, const float* __restrict__ gb2,
    float* __restrict__ outBal, int* __restrict__ tk)
{
  __shared__ float feat[128], rf[64], g1[32], bal[8];
  const int b = blockIdx.x, t = threadIdx.x;
  #pragma unroll
  for (int h = 0; h < 2; ++h) {
    const int f = t + 64*h;
    const int oc = f >> 2, qy = (f >> 1) & 1, qx = f & 1;
    feat[f] = (tfp[b*256 + (4*qy + qx)*32 + oc] +
               tfp[b*256 + (4*qy + 2 + qx)*32 + oc]) * (1.f/64.f);
  }
  __syncthreads();
  {
    float a = tfb[t];
    const float4* wp = (const float4*)&tfw[t*128];
    #pragma unroll 8
    for (int i4 = 0; i4 < 32; ++i4) {
      float4 wv = wp[i4];
      a = fmaf(wv.x, feat[4*i4], a);   a = fmaf(wv.y, feat[4*i4+1], a);
      a = fmaf(wv.z, feat[4*i4+2], a); a = fmaf(wv.w, feat[4*i4+3], a);
    }
    rf[t] = fmaxf(a, 0.f);
  }
  __syncthreads();
  if (t < 32) {
    float a = gb1[t];
    const float4* wp = (const float4*)&gw1[t*64];
    #pragma unroll
    for (int i4 = 0; i4 < 16; ++i4) {
      float4 wv = wp[i4];
      a = fmaf(wv.x, rf[4*i4], a);   a = fmaf(wv.y, rf[4*i4+1], a);
      a = fmaf(wv.z, rf[4*i4+2], a); a = fmaf(wv.w, rf[4*i4+3], a);
    }
    g1[t] = fmaxf(a, 0.f);
  }
  __syncthreads();
  if (t < 8) {
    float a = gb2[t];
    const float4* wp = (const float4*)&gw2[t*32];
    #pragma unroll
    for (int i4 = 0; i4 < 8; ++i4) {
      float4 wv = wp[i4];
      a = fmaf(wv.x, g1[4*i4], a);   a = fmaf(wv.y, g1[4*i4+1], a);
      a = fmaf(wv.z, g1[4*i4+2], a); a = fmaf(wv.w, g1[4*i4+3], a);
    }
    const float v = a - 0.25f;
    bal[t] = v;
    outBal[b*8 + t] = v;
  }
  __syncthreads();
  if (t == 0) {
    int t0 = 0; float b0 = bal[0];
    #pragma unroll
    for (int e2 = 1; e2 < 8; ++e2) if (bal[e2] > b0) { b0 = bal[e2]; t0 = e2; }
    int t1 = -1; float b1 = -3.4e38f;
    #pragma unroll
    for (int e2 = 0; e2 < 8; ++e2) if (e2 != t0 && bal[e2] > b1) { b1 = bal[e2]; t1 = e2; }
    tk[b*2] = t0; tk[b*2 + 1] = t1;
  }
}

// =================== serial capacity-constrained routing ===================
__global__ __launch_bounds__(256) void route_kernel(const int* __restrict__ tk,
                                                    int* __restrict__ chosen,
                                                    float* __restrict__ outD)
{
  __shared__ int stk[512];
  __shared__ int sch[256];
  const int t = threadIdx.x;
  stk[t] = tk[t]; stk[256 + t] = tk[256 + t];
  __syncthreads();
  if (t == 0) {
    float L0=0,L1=0,L2=0,L3=0,L4=0,L5=0,L6=0,L7=0;
    for (int i = 0; i < 256; ++i) {
      const int a = stk[2*i], c = stk[2*i+1];
      const float la = (a==0)?L0:(a==1)?L1:(a==2)?L2:(a==3)?L3:(a==4)?L4:(a==5)?L5:(a==6)?L6:L7;
      const float lc = (c==0)?L0:(c==1)?L1:(c==2)?L2:(c==3)?L3:(c==4)?L4:(c==5)?L5:(c==6)?L6:L7;
      const int ch = (la < 48.f) ? a : ((lc < 48.f) ? c : ((la <= lc) ? a : c));
      L0 += (ch==0)?1.f:0.f; L1 += (ch==1)?1.f:0.f; L2 += (ch==2)?1.f:0.f; L3 += (ch==3)?1.f:0.f;
      L4 += (ch==4)?1.f:0.f; L5 += (ch==5)?1.f:0.f; L6 += (ch==6)?1.f:0.f; L7 += (ch==7)?1.f:0.f;
      sch[i] = ch;
    }
  }
  __syncthreads();
  const int ch = sch[t];
  chosen[t] = ch;
  #pragma unroll
  for (int e2 = 0; e2 < 8; ++e2) outD[t*8 + e2] = (ch == e2) ? 1.f : 0.f;
}

// ===== expA: conv1 3->32 (32x32) + pool -> padded P1g [32][18][20] =========
__global__ __launch_bounds__(256) void expA_kernel(
    const float* __restrict__ x, const int* __restrict__ chosen,
    const float* __restrict__ ew1, const float* __restrict__ eg1,
    const float* __restrict__ eb1, float* __restrict__ P1g)
{
  __shared__ __align__(16) float sxa[1020];
  __shared__ __align__(16) float sw1t[864];
  __shared__ float bs[32], bb[32];
  const int t = threadIdx.x;
  const int b = blockIdx.x >> 2, rs = blockIdx.x & 3;
  const int r0 = rs * 8;
  const int e = chosen[b];

  for (int j = t; j < 576; j += 256) {
    int idx = rs*576 + j;
    int ic = idx / 72, r2 = idx % 72, row, col;
    if (r2 < 20)      { row = 0;  col = r2; }
    else if (r2 < 40) { row = 17; col = r2 - 20; }
    else if (r2 < 56) { row = 1 + (r2 - 40); col = 0; }
    else              { row = 1 + (r2 - 56); col = 17; }
    P1g[b*11520 + ic*360 + row*20 + col] = 0.f;
  }
  for (int j = t; j < 1020; j += 256) {
    int ic = j / 340, r = (j % 340) / 34, cxx = j % 34;
    int gy = r0 - 1 + r, gx = cxx - 1;
    float v = 0.f;
    if (gy >= 0 && gy < 32 && gx >= 0 && gx < 32) v = x[b*3072 + ic*1024 + gy*32 + gx];
    sxa[j] = v;
  }
  for (int j = t; j < 864; j += 256) {
    int oc = j / 27, r = j % 27, ic = r / 9, k = r % 9;
    sw1t[ic*288 + k*32 + oc] = ew1[e*864 + j];
  }
  if (t < 32) { bs[t] = eg1[e*32 + t]*BN_RS; bb[t] = eb1[e*32 + t]; }
  __syncthreads();

  const int g = t >> 5, c = t & 31;
  float acc[4][8];
  #pragma unroll
  for (int o = 0; o < 4; ++o)
    #pragma unroll
    for (int r = 0; r < 8; ++r) acc[o][r] = 0.f;

  for (int ic = 0; ic < 3; ++ic) {
    float w[4][9];
    #pragma unroll
    for (int k = 0; k < 9; ++k) {
      float4 wv = *(const float4*)&sw1t[ic*288 + k*32 + 4*g];
      w[0][k] = wv.x; w[1][k] = wv.y; w[2][k] = wv.z; w[3][k] = wv.w;
    }
    const float* src = &sxa[ic*340 + c];
    #pragma unroll
    for (int rr = 0; rr < 10; ++rr) {
      const float i0 = src[rr*34], i1 = src[rr*34 + 1], i2 = src[rr*34 + 2];
      #pragma unroll
      for (int dr = 0; dr < 3; ++dr) {
        const int r = rr - dr;
        if (r < 0 || r > 7) continue;
        #pragma unroll
        for (int o = 0; o < 4; ++o) {
          acc[o][r] = fmaf(w[o][dr*3+0], i0, acc[o][r]);
          acc[o][r] = fmaf(w[o][dr*3+1], i1, acc[o][r]);
          acc[o][r] = fmaf(w[o][dr*3+2], i2, acc[o][r]);
        }
      }
    }
  }
  #pragma unroll
  for (int o = 0; o < 4; ++o) {
    const int oc = 4*g + o;
    const float s = bs[oc], bo = bb[oc];
    float m[4];
    #pragma unroll
    for (int pr = 0; pr < 4; ++pr) {
      float v0 = fmaxf(fmaf(acc[o][2*pr],   s, bo), 0.f);
      float v1 = fmaxf(fmaf(acc[o][2*pr+1], s, bo), 0.f);
      m[pr] = fmaxf(v0, v1);
    }
    #pragma unroll
    for (int pr = 0; pr < 4; ++pr) {
      float nb = __shfl_xor(m[pr], 1);
      m[pr] = fmaxf(m[pr], nb);
    }
    if (!(c & 1)) {
      const int pc = c >> 1;
      #pragma unroll
      for (int pr = 0; pr < 4; ++pr)
        P1g[b*11520 + oc*360 + (rs*4 + pr + 1)*20 + pc + 1] = m[pr];
    }
  }
}

// ====== expB: conv2 32->64 (16x16) + pool -> bf16 P2gT [10][10][64] ========
// grid 1024 = b*4 + (och(2)*2 + rs(2)); 256 thr = g8 x q4 x cp8
#define TB_SLAB 0
#define TB_WD   6464
#define TB_BN   8832
__global__ __launch_bounds__(256, 4) void expB_kernel(
    const int* __restrict__ chosen, const float* __restrict__ P1g,
    const float* __restrict__ ew2t, const float* __restrict__ eg2,
    const float* __restrict__ eb2, ushort* __restrict__ P2gT)
{
  __shared__ __align__(16) float sm[8896];
  const int t = threadIdx.x;
  const int b = blockIdx.x >> 2, blk = blockIdx.x & 3;
  const int och = blk >> 1, rs = blk & 1;
  const int r0 = rs*8;
  const int e = chosen[b];

  // zero this block's share of P2gT borders (36 border slots x 64 ic)
  for (int j = t; j < 576; j += 256) {
    int idx = blk*576 + j;
    int slot = idx / 64, ic = idx % 64, row, col;
    if (slot < 10)      { row = 0; col = slot; }
    else if (slot < 20) { row = 9; col = slot - 10; }
    else if (slot < 28) { row = 1 + (slot - 20); col = 0; }
    else                { row = 1 + (slot - 28); col = 9; }
    P2gT[b*6400 + (row*10 + col)*64 + ic] = 0;
  }
  for (int j = t; j < 1600; j += 256) {
    int ic = j / 50, rem = j % 50, rr = rem / 5, c4 = rem % 5;
    float4 v = *(const float4*)&P1g[b*11520 + ic*360 + (r0+rr)*20 + 4*c4];
    float* d = &sm[TB_SLAB + ic*202 + rr*20 + 4*c4];
    d[0] = v.x; d[1] = v.y; d[2] = v.z; d[3] = v.w;
  }
  for (int j = t; j < 1152; j += 256) {
    int qq = j / 288, r = j % 288, k = r / 32, ocl = r & 31;
    sm[TB_WD + qq*296 + r] = ew2t[e*18432 + (qq*8)*576 + k*64 + och*32 + ocl];
  }
  if (t < 32) {
    sm[TB_BN + t] = eg2[e*64 + och*32 + t]*BN_RS;
    sm[TB_BN + 32 + t] = eb2[e*64 + och*32 + t];
  }
  __syncthreads();

  const int g = t >> 5, q = (t >> 3) & 3, cp = t & 7;
  float acc[4][8][2];
  #pragma unroll
  for (int o = 0; o < 4; ++o)
    #pragma unroll
    for (int r = 0; r < 8; ++r) { acc[o][r][0] = 0.f; acc[o][r][1] = 0.f; }

  for (int cc = 0; cc < 8; ++cc) {
    if (cc < 7) {
      for (int j = t; j < 1152; j += 256) {
        int qq = j / 288, r = j % 288, k = r / 32, ocl = r & 31;
        sm[TB_WD + ((cc+1)&1)*1184 + qq*296 + r] =
            ew2t[e*18432 + (qq*8 + cc+1)*576 + k*64 + och*32 + ocl];
      }
    }
    const float* wb = &sm[TB_WD + (cc&1)*1184 + q*296];
    float w[4][9];
    #pragma unroll
    for (int k = 0; k < 9; ++k) {
      float4 wv = *(const float4*)&wb[k*32 + 4*g];
      w[0][k] = wv.x; w[1][k] = wv.y; w[2][k] = wv.z; w[3][k] = wv.w;
    }
    const float* src = &sm[TB_SLAB + (q*8+cc)*202 + 2*cp];
    #pragma unroll
    for (int rr = 0; rr < 10; ++rr) {
      float2 va = *(const float2*)&src[rr*20];
      float2 vb = *(const float2*)&src[rr*20 + 2];
      const float i0 = va.x, i1 = va.y, i2 = vb.x, i3 = vb.y;
      #pragma unroll
      for (int dr = 0; dr < 3; ++dr) {
        const int r = rr - dr;
        if (r < 0 || r > 7) continue;
        #pragma unroll
        for (int o = 0; o < 4; ++o) {
          acc[o][r][0] = fmaf(w[o][dr*3+0], i0, acc[o][r][0]);
          acc[o][r][1] = fmaf(w[o][dr*3+0], i1, acc[o][r][1]);
          acc[o][r][0] = fmaf(w[o][dr*3+1], i1, acc[o][r][0]);
          acc[o][r][1] = fmaf(w[o][dr*3+1], i2, acc[o][r][1]);
          acc[o][r][0] = fmaf(w[o][dr*3+2], i2, acc[o][r][0]);
          acc[o][r][1] = fmaf(w[o][dr*3+2], i3, acc[o][r][1]);
        }
      }
    }
    __syncthreads();
  }

  const int slot = g*8 + cp;
  if (q >= 2) {
    float* dst = &sm[(q-2)*4168 + slot*65];
    #pragma unroll
    for (int o = 0; o < 4; ++o)
      #pragma unroll
      for (int r = 0; r < 8; ++r) {
        dst[o*16 + r*2 + 0] = acc[o][r][0];
        dst[o*16 + r*2 + 1] = acc[o][r][1];
      }
  }
  __syncthreads();
  if (q < 2) {
    const float* s0 = &sm[q*4168 + slot*65];
    #pragma unroll
    for (int o = 0; o < 4; ++o)
      #pragma unroll
      for (int r = 0; r < 8; ++r) {
        acc[o][r][0] += s0[o*16 + r*2 + 0];
        acc[o][r][1] += s0[o*16 + r*2 + 1];
      }
  }
  __syncthreads();
  if (q == 1) {
    float* dst = &sm[slot*65];
    #pragma unroll
    for (int o = 0; o < 4; ++o)
      #pragma unroll
      for (int r = 0; r < 8; ++r) {
        dst[o*16 + r*2 + 0] = acc[o][r][0];
        dst[o*16 + r*2 + 1] = acc[o][r][1];
      }
  }
  __syncthreads();
  if (q == 0) {
    const float* s0 = &sm[slot*65];
    #pragma unroll
    for (int o = 0; o < 4; ++o) {
      const int ocl = 4*g + o;
      const float s = sm[TB_BN + ocl], bo = sm[TB_BN + 32 + ocl];
      #pragma unroll
      for (int pr = 0; pr < 4; ++pr) {
        float c00 = acc[o][2*pr][0]   + s0[o*16 + (2*pr)*2 + 0];
        float c01 = acc[o][2*pr][1]   + s0[o*16 + (2*pr)*2 + 1];
        float c10 = acc[o][2*pr+1][0] + s0[o*16 + (2*pr+1)*2 + 0];
        float c11 = acc[o][2*pr+1][1] + s0[o*16 + (2*pr+1)*2 + 1];
        float v0 = fmaxf(fmaf(c00, s, bo), 0.f);
        float v1 = fmaxf(fmaf(c01, s, bo), 0.f);
        float v2 = fmaxf(fmaf(c10, s, bo), 0.f);
        float v3 = fmaxf(fmaf(c11, s, bo), 0.f);
        float m = fmaxf(fmaxf(v0, v1), fmaxf(v2, v3));
        // bf16 store into padded transposed image [row][col][ic]
        P2gT[b*6400 + ((rs*4 + pr + 1)*10 + (cp + 1))*64 + och*32 + ocl] = f2bf(m);
      }
    }
  }
}

// ====== expC (MFMA): conv3 64->128 + bn/relu + GAP -> featg ================
// grid 256 = one block/sample; 4 waves; 9-tap implicit GEMM, bf16 MFMA.
// A[m=lane&15][k=quad*8+j], B[k=quad*8+j][n=lane&15], D[col=lane&15].
#define MC_P2T 0      // 100 slots x 72 ushort (64 data + 8 pad) = 7200
#define MC_WT  7200   // 128 oc x 72 ushort = 9216; total 16416 us = 32832 B
__global__ __launch_bounds__(256) void expC_mfma(
    const int* __restrict__ chosen, const ushort* __restrict__ P2gT,
    const ushort* __restrict__ ew3b, const float* __restrict__ eg3,
    const float* __restrict__ eb3, float* __restrict__ featg)
{
  __shared__ __align__(16) ushort smu[16416];
  const int t = threadIdx.x, b = blockIdx.x;
  const int e = chosen[b];
  const int w = t >> 6, l = t & 63;
  const int col = l & 15, quad = l >> 4;

  // stage P2T image (6400 ushort) into padded-slot layout
  for (int j = t; j < 800; j += 256) {
    int slot = j >> 3, ico = (j & 7) * 8;
    *(uint4*)&smu[MC_P2T + slot*72 + ico] = *(const uint4*)&P2gT[b*6400 + j*8];
  }

  floatx4 acc[2][4];
  #pragma unroll
  for (int nt = 0; nt < 2; ++nt)
    #pragma unroll
    for (int mt = 0; mt < 4; ++mt)
      #pragma unroll
      for (int i = 0; i < 4; ++i) acc[nt][mt][i] = 0.f;

  for (int tap = 0; tap < 9; ++tap) {
    __syncthreads();   // prior compute done before overwriting W
    for (int j = t; j < 1024; j += 256) {
      int oc = j >> 3, ico = (j & 7) * 8;
      *(uint4*)&smu[MC_WT + oc*72 + ico] =
          *(const uint4*)&ew3b[(e*9 + tap)*8192 + j*8];
    }
    __syncthreads();
    const int dy = tap / 3, dx = tap % 3;
    #pragma unroll
    for (int ks = 0; ks < 2; ++ks) {
      short8 bfr[2];
      #pragma unroll
      for (int nt = 0; nt < 2; ++nt) {
        const int oc = w*32 + nt*16 + col;
        bfr[nt] = *(const short8*)&smu[MC_WT + oc*72 + ks*32 + quad*8];
      }
      #pragma unroll
      for (int mt = 0; mt < 4; ++mt) {
        const int m = mt*16 + col;
        const int y = m >> 3, xx = m & 7;
        short8 afr = *(const short8*)
            &smu[MC_P2T + ((y + dy)*10 + (xx + dx))*72 + ks*32 + quad*8];
        acc[0][mt] = __builtin_amdgcn_mfma_f32_16x16x32_bf16(afr, bfr[0], acc[0][mt], 0, 0, 0);
        acc[1][mt] = __builtin_amdgcn_mfma_f32_16x16x32_bf16(afr, bfr[1], acc[1][mt], 0, 0, 0);
      }
    }
  }

  // epilogue: bn + relu + GAP (invariant to m permutation)
  #pragma unroll
  for (int nt = 0; nt < 2; ++nt) {
    const int oc = w*32 + nt*16 + col;
    const float s = eg3[e*128 + oc]*BN_RS, bo = eb3[e*128 + oc];
    float gsum = 0.f;
    #pragma unroll
    for (int mt = 0; mt < 4; ++mt)
      #pragma unroll
      for (int i = 0; i < 4; ++i)
        gsum += fmaxf(fmaf(acc[nt][mt][i], s, bo), 0.f);
    gsum += __shfl_xor(gsum, 16);
    gsum += __shfl_xor(gsum, 32);
    if (quad == 0) featg[b*128 + oc] = gsum * (1.f/64.f);
  }
}

// ================= expD: FC chain -> final =================================
__global__ __launch_bounds__(128) void expD_kernel(
    const int* __restrict__ chosen, const float* __restrict__ featg,
    const float* __restrict__ efw, const float* __restrict__ efb,
    const float* __restrict__ cw1, const float* __restrict__ cb1,
    const float* __restrict__ cw2, const float* __restrict__ cb2,
    float* __restrict__ outF)
{
  __shared__ float sf[128], sff[128], sgg[64];
  const int b = blockIdx.x, t = threadIdx.x;
  const int e = chosen[b];
  sf[t] = featg[b*128 + t];
  __syncthreads();
  {
    float a = efb[e*128 + t];
    const float4* wp = (const float4*)&efw[e*16384 + t*128];
    #pragma unroll 8
    for (int i4 = 0; i4 < 32; ++i4) {
      float4 wv = wp[i4];
      a = fmaf(wv.x, sf[4*i4], a);   a = fmaf(wv.y, sf[4*i4+1], a);
      a = fmaf(wv.z, sf[4*i4+2], a); a = fmaf(wv.w, sf[4*i4+3], a);
    }
    sff[t] = fmaxf(a, 0.f);
  }
  __syncthreads();
  if (t < 64) {
    float a = cb1[e*64 + t];
    const float4* wp = (const float4*)&cw1[e*8192 + t*128];
    #pragma unroll 8
    for (int i4 = 0; i4 < 32; ++i4) {
      float4 wv = wp[i4];
      a = fmaf(wv.x, sff[4*i4], a);   a = fmaf(wv.y, sff[4*i4+1], a);
      a = fmaf(wv.z, sff[4*i4+2], a); a = fmaf(wv.w, sff[4*i4+3], a);
    }
    sgg[t] = fmaxf(a, 0.f);
  }
  __syncthreads();
  if (t < 10) {
    float a = cb2[e*10 + t];
    const float4* wp = (const float4*)&cw2[e*640 + t*64];
    #pragma unroll
    for (int i4 = 0; i4 < 16; ++i4) {
      float4 wv = wp[i4];
      a = fmaf(wv.x, sgg[4*i4], a);   a = fmaf(wv.y, sgg[4*i4+1], a);
      a = fmaf(wv.z, sgg[4*i4+2], a); a = fmaf(wv.w, sgg[4*i4+3], a);
    }
    outF[b*10 + t] = a;
  }
}

// ================================ host =====================================
extern "C" void kernel_launch(void* const* d_in, const int* in_sizes, int n_in,
                              void* d_out, int out_size, void* d_ws, size_t ws_size,
                              hipStream_t stream)
{
  const float* x   = (const float*)d_in[0];
  const float* tw1 = (const float*)d_in[1];
  const float* tg1 = (const float*)d_in[2];
  const float* tb1 = (const float*)d_in[3];
  const float* tw2 = (const float*)d_in[4];
  const float* tg2 = (const float*)d_in[5];
  const float* tb2 = (const float*)d_in[6];
  const float* tfw = (const float*)d_in[7];
  const float* tfb = (const float*)d_in[8];
  const float* gw1 = (const float*)d_in[9];
  const float* gb1 = (const float*)d_in[10];
  const float* gw2 = (const float*)d_in[11];
  const float* gb2 = (const float*)d_in[12];
  const float* ew1 = (const float*)d_in[13];
  const float* eg1 = (const float*)d_in[14];
  const float* eb1 = (const float*)d_in[15];
  const float* ew2 = (const float*)d_in[16];
  const float* eg2 = (const float*)d_in[17];
  const float* eb2 = (const float*)d_in[18];
  const float* ew3 = (const float*)d_in[19];
  const float* eg3 = (const float*)d_in[20];
  const float* eb3 = (const float*)d_in[21];
  const float* efw = (const float*)d_in[22];
  const float* efb = (const float*)d_in[23];
  const float* cw1 = (const float*)d_in[24];
  const float* cb1 = (const float*)d_in[25];
  const float* cw2 = (const float*)d_in[26];
  const float* cb2 = (const float*)d_in[27];

  float*  out    = (float*)d_out;
  char*   ws     = (char*)d_ws;
  float*  tfp    = (float*)(ws + WS_TFP);
  int*    tk     = (int*)(ws + WS_TK);
  int*    chosen = (int*)(ws + WS_CHOSEN);
  float*  tw2t   = (float*)(ws + WS_TW2T);
  float*  ew2t   = (float*)(ws + WS_EW2T);
  ushort* ew3b   = (ushort*)(ws + WS_EW3B);
  float*  featg  = (float*)(ws + WS_FEATG);
  float*  P1g    = (float*)(ws + WS_P1G);
  ushort* P2gT   = (ushort*)(ws + WS_P2GT);

  prep_kernel<<<2916, 256, 0, stream>>>(tw2, ew2, ew3, tw2t, ew2t, ew3b);
  trunk_kernel<<<2048, 256, 0, stream>>>(x, tw1, tg1, tb1, tw2t, tg2, tb2, tfp);
  gate_kernel<<<256, 64, 0, stream>>>(tfp, tfw, tfb, gw1, gb1, gw2, gb2, out + 2560, tk);
  route_kernel<<<1, 256, 0, stream>>>(tk, chosen, out + 4608);
  expA_kernel<<<1024, 256, 0, stream>>>(x, chosen, ew1, eg1, eb1, P1g);
  expB_kernel<<<1024, 256, 0, stream>>>(chosen, P1g, ew2t, eg2, eb2, P2gT);
  expC_mfma<<<256, 256, 0, stream>>>(chosen, P2gT, ew3b, eg3, eb3, featg);
  expD_kernel<<<256, 128, 0, stream>>>(chosen, featg, efw, efb, cw1, cb1, cw2, cb2, out);
}

// Round 8
// 355.785 us; speedup vs baseline: 1.2419x; 1.0851x over previous
//
#include <hip/hip_runtime.h>
#include <hip/hip_bf16.h>
#include <math.h>

// ---------------------------------------------------------------------------
// DistributedMoE forward, MI355X — R8: expB -> bf16 MFMA (template verified
// by R7's expC); trunk reads conv2 weights straight from global (36KB,
// L1/L2-shared by all blocks) deleting 16 barriers/block; expA stores bf16
// P1gT [18][18][32]. Routing path (trunk/gate/route) stays fp32-identical.
// One expert per sample (softmax over one dispatched element == 1).
//
// out (fp32): final[256,10] @0, balanced[256,8] @2560, D[256,8] @4608
// ---------------------------------------------------------------------------

#define BN_RS (1.0f / sqrtf(1.00001f))

typedef __attribute__((ext_vector_type(8))) short short8;
typedef __attribute__((ext_vector_type(4))) float floatx4;

static __device__ __forceinline__ ushort f2bf(float f) {
  unsigned u = __float_as_uint(f);
  unsigned r = (u + 0x7fffu + ((u >> 16) & 1u)) >> 16;   // RNE
  return (ushort)r;
}

// ws byte offsets (16B aligned)
#define WS_TFP    0           // f32[256][8][32]
#define WS_TK     262144      // i32[512]
#define WS_CHOSEN 264192      // i32[256]
#define WS_TW2T   265216      // f32[32ic][9][32oc]           (36864 B)
#define WS_EW2B   302080      // bf16[8][9tap][64oc][32ic]    (294912 B)
#define WS_EW3B   596992      // bf16[8][9tap][128oc][64ic]   (1179648 B)
#define WS_FEATG  1776640     // f32[256*128]                 (131072 B)
#define WS_P1GT   1907712     // bf16[256][18][18][32] padded (5308416 B)
#define WS_P2GT   7216128     // bf16[256][10][10][64] padded (3276800 B)

// =================== prep: weight transposes ===============================
__global__ __launch_bounds__(256) void prep_kernel(
    const float* __restrict__ tw2, const float* __restrict__ ew2,
    const float* __restrict__ ew3, float* __restrict__ tw2t,
    ushort* __restrict__ ew2b, ushort* __restrict__ ew3b)
{
  const int j = blockIdx.x * 256 + threadIdx.x;
  if (j < 9216) {
    int ic = j / 288, rem = j % 288, k = rem / 32, oc = rem % 32;
    tw2t[j] = tw2[oc*288 + ic*9 + k];
  } else if (j < 156672) {
    int jj = j - 9216;                       // [e][tap][oc64][ic32]
    int e = jj / 18432, r2 = jj % 18432;
    int tap = r2 / 2048, r3 = r2 % 2048;
    int oc = r3 / 32, ic = r3 % 32;
    ew2b[jj] = f2bf(ew2[e*18432 + oc*288 + ic*9 + tap]);
  } else if (j < 746496) {
    int jj = j - 156672;                     // [e][tap][oc128][ic64]
    int e = jj / 73728, r2 = jj % 73728;
    int tap = r2 / 8192, r3 = r2 % 8192;
    int oc = r3 / 64, ic = r3 % 64;
    ew3b[jj] = f2bf(ew3[e*73728 + oc*576 + ic*9 + tap]);
  }
}

// ====== fused trunk: conv1 (in-LDS) + conv2 + pool + partial sums ==========
// grid 2048 = b*8 + (rs(4)*2 + ch(2)); 256 thr; weights read from global.
#define TF_SA1 0
#define TF_X   6464
#define TF_W1  7184
#define TF_BN  8832
__global__ __launch_bounds__(256, 4) void trunk_kernel(
    const float* __restrict__ x, const float* __restrict__ tw1,
    const float* __restrict__ tg1, const float* __restrict__ tb1,
    const float* __restrict__ tw2t, const float* __restrict__ tg2,
    const float* __restrict__ tb2, float* __restrict__ tfp)
{
  __shared__ __align__(16) float sm[8960];
  const int t = threadIdx.x;
  const int b = blockIdx.x >> 3, blk = blockIdx.x & 7;
  const int rs = blk >> 1, ch = blk & 1;
  const int r0 = rs*8, c0 = ch*16;

  for (int j = t; j < 720; j += 256) {
    int ic = j / 240, rem = j % 240, rr = rem / 20, cx = rem % 20;
    int gy = r0 - 2 + rr, gx = c0 - 2 + cx;
    float v = 0.f;
    if (gy >= 0 && gy < 32 && gx >= 0 && gx < 32) v = x[b*3072 + ic*1024 + gy*32 + gx];
    sm[TF_X + j] = v;
  }
  for (int j = t; j < 864; j += 256) sm[TF_W1 + j] = tw1[j];
  if (t < 32) {
    sm[TF_BN + t] = tg1[t]*BN_RS;      sm[TF_BN + 32 + t] = tb1[t];
    sm[TF_BN + 64 + t] = tg2[t]*BN_RS; sm[TF_BN + 96 + t] = tb2[t];
  }
  __syncthreads();

  // conv1 (order identical to R6/R7)
  {
    float acc1[18];
    for (int it = 0; it < 2; ++it) {
      const int item = it*256 + t;
      if (item < 320) {
        const int oc = item & 31, rr = item >> 5;
        const int gy = r0 - 1 + rr;
        #pragma unroll
        for (int c2 = 0; c2 < 18; ++c2) acc1[c2] = 0.f;
        if (gy >= 0 && gy < 32) {
          for (int ic = 0; ic < 3; ++ic) {
            float w[9];
            #pragma unroll
            for (int k = 0; k < 9; ++k) w[k] = sm[TF_W1 + oc*27 + ic*9 + k];
            #pragma unroll
            for (int wr = 0; wr < 3; ++wr) {
              float rv[20];
              const float4* rp = (const float4*)&sm[TF_X + ic*240 + (rr + wr)*20];
              #pragma unroll
              for (int j4 = 0; j4 < 5; ++j4) {
                float4 v4 = rp[j4];
                rv[4*j4] = v4.x; rv[4*j4+1] = v4.y; rv[4*j4+2] = v4.z; rv[4*j4+3] = v4.w;
              }
              #pragma unroll
              for (int c2 = 0; c2 < 18; ++c2)
                #pragma unroll
                for (int kx = 0; kx < 3; ++kx)
                  acc1[c2] = fmaf(w[wr*3 + kx], rv[c2 + kx], acc1[c2]);
            }
          }
        }
        const float s = sm[TF_BN + oc], bo = sm[TF_BN + 32 + oc];
        #pragma unroll
        for (int c2 = 0; c2 < 18; ++c2) {
          const int gx = c0 - 1 + c2;
          float v = 0.f;
          if (gy >= 0 && gy < 32 && gx >= 0 && gx < 32)
            v = fmaxf(fmaf(acc1[c2], s, bo), 0.f);
          sm[TF_SA1 + oc*202 + rr*20 + c2] = v;
        }
      }
    }
  }
  __syncthreads();

  // conv2: weights straight from global (L1/L2-resident), no barriers
  const int g = t >> 5, q = (t >> 3) & 3, cp = t & 7;
  float acc[4][8][2];
  #pragma unroll
  for (int o = 0; o < 4; ++o)
    #pragma unroll
    for (int r = 0; r < 8; ++r) { acc[o][r][0] = 0.f; acc[o][r][1] = 0.f; }

  for (int cc = 0; cc < 8; ++cc) {
    const float* wb = &tw2t[(q*8 + cc)*288];
    float w[4][9];
    #pragma unroll
    for (int k = 0; k < 9; ++k) {
      float4 wv = *(const float4*)&wb[k*32 + 4*g];
      w[0][k] = wv.x; w[1][k] = wv.y; w[2][k] = wv.z; w[3][k] = wv.w;
    }
    const float* src = &sm[TF_SA1 + (q*8+cc)*202 + 2*cp];
    #pragma unroll
    for (int rr = 0; rr < 10; ++rr) {
      float2 va = *(const float2*)&src[rr*20];
      float2 vb = *(const float2*)&src[rr*20 + 2];
      const float i0 = va.x, i1 = va.y, i2 = vb.x, i3 = vb.y;
      #pragma unroll
      for (int dr = 0; dr < 3; ++dr) {
        const int r = rr - dr;
        if (r < 0 || r > 7) continue;
        #pragma unroll
        for (int o = 0; o < 4; ++o) {
          acc[o][r][0] = fmaf(w[o][dr*3+0], i0, acc[o][r][0]);
          acc[o][r][1] = fmaf(w[o][dr*3+0], i1, acc[o][r][1]);
          acc[o][r][0] = fmaf(w[o][dr*3+1], i1, acc[o][r][0]);
          acc[o][r][1] = fmaf(w[o][dr*3+1], i2, acc[o][r][1]);
          acc[o][r][0] = fmaf(w[o][dr*3+2], i2, acc[o][r][0]);
          acc[o][r][1] = fmaf(w[o][dr*3+2], i3, acc[o][r][1]);
        }
      }
    }
  }
  __syncthreads();   // SA1 dead -> exchange overlay

  const int slot = g*8 + cp;
  if (q >= 2) {
    float* dst = &sm[(q-2)*4168 + slot*65];
    #pragma unroll
    for (int o = 0; o < 4; ++o)
      #pragma unroll
      for (int r = 0; r < 8; ++r) {
        dst[o*16 + r*2 + 0] = acc[o][r][0];
        dst[o*16 + r*2 + 1] = acc[o][r][1];
      }
  }
  __syncthreads();
  if (q < 2) {
    const float* s0 = &sm[q*4168 + slot*65];
    #pragma unroll
    for (int o = 0; o < 4; ++o)
      #pragma unroll
      for (int r = 0; r < 8; ++r) {
        acc[o][r][0] += s0[o*16 + r*2 + 0];
        acc[o][r][1] += s0[o*16 + r*2 + 1];
      }
  }
  __syncthreads();
  if (q == 1) {
    float* dst = &sm[slot*65];
    #pragma unroll
    for (int o = 0; o < 4; ++o)
      #pragma unroll
      for (int r = 0; r < 8; ++r) {
        dst[o*16 + r*2 + 0] = acc[o][r][0];
        dst[o*16 + r*2 + 1] = acc[o][r][1];
      }
  }
  __syncthreads();
  if (q == 0) {
    const float* s0 = &sm[slot*65];
    #pragma unroll
    for (int o = 0; o < 4; ++o) {
      const int oc = 4*g + o;
      const float s = sm[TF_BN + 64 + oc], bo = sm[TF_BN + 96 + oc];
      float ps = 0.f;
      #pragma unroll
      for (int pr = 0; pr < 4; ++pr) {
        float c00 = acc[o][2*pr][0]   + s0[o*16 + (2*pr)*2 + 0];
        float c01 = acc[o][2*pr][1]   + s0[o*16 + (2*pr)*2 + 1];
        float c10 = acc[o][2*pr+1][0] + s0[o*16 + (2*pr+1)*2 + 0];
        float c11 = acc[o][2*pr+1][1] + s0[o*16 + (2*pr+1)*2 + 1];
        float v0 = fmaxf(fmaf(c00, s, bo), 0.f);
        float v1 = fmaxf(fmaf(c01, s, bo), 0.f);
        float v2 = fmaxf(fmaf(c10, s, bo), 0.f);
        float v3 = fmaxf(fmaf(c11, s, bo), 0.f);
        ps += fmaxf(fmaxf(v0, v1), fmaxf(v2, v3));
      }
      ps += __shfl_xor(ps, 1);
      ps += __shfl_xor(ps, 2);
      ps += __shfl_xor(ps, 4);
      if ((t & 31) == 0) tfp[b*256 + (rs*2 + ch)*32 + oc] = ps;
    }
  }
}

// ============================== gate + top2 ================================
__global__ __launch_bounds__(64) void gate_kernel(
    const float* __restrict__ tfp, const float* __restrict__ tfw, const float* __restrict__ tfb,
    const float* __restrict__ gw1, const float* __restrict__ gb1,
    const float* __restrict__ gw2, const float* __restrict__ gb2,
    float* __restrict__ outBal, int* __restrict__ tk)
{
  __shared__ float feat[128], rf[64], g1[32], bal[8];
  const int b = blockIdx.x, t = threadIdx.x;
  #pragma unroll
  for (int h = 0; h < 2; ++h) {
    const int f = t + 64*h;
    const int oc = f >> 2, qy = (f >> 1) & 1, qx = f & 1;
    feat[f] = (tfp[b*256 + (4*qy + qx)*32 + oc] +
               tfp[b*256 + (4*qy + 2 + qx)*32 + oc]) * (1.f/64.f);
  }
  __syncthreads();
  {
    float a = tfb[t];
    const float4* wp = (const float4*)&tfw[t*128];
    #pragma unroll 8
    for (int i4 = 0; i4 < 32; ++i4) {
      float4 wv = wp[i4];
      a = fmaf(wv.x, feat[4*i4], a);   a = fmaf(wv.y, feat[4*i4+1], a);
      a = fmaf(wv.z, feat[4*i4+2], a); a = fmaf(wv.w, feat[4*i4+3], a);
    }
    rf[t] = fmaxf(a, 0.f);
  }
  __syncthreads();
  if (t < 32) {
    float a = gb1[t];
    const float4* wp = (const float4*)&gw1[t*64];
    #pragma unroll
    for (int i4 = 0; i4 < 16; ++i4) {
      float4 wv = wp[i4];
      a = fmaf(wv.x, rf[4*i4], a);   a = fmaf(wv.y, rf[4*i4+1], a);
      a = fmaf(wv.z, rf[4*i4+2], a); a = fmaf(wv.w, rf[4*i4+3], a);
    }
    g1[t] = fmaxf(a, 0.f);
  }
  __syncthreads();
  if (t < 8) {
    float a = gb2[t];
    const float4* wp = (const float4*)&gw2[t*32];
    #pragma unroll
    for (int i4 = 0; i4 < 8; ++i4) {
      float4 wv = wp[i4];
      a = fmaf(wv.x, g1[4*i4], a);   a = fmaf(wv.y, g1[4*i4+1], a);
      a = fmaf(wv.z, g1[4*i4+2], a); a = fmaf(wv.w, g1[4*i4+3], a);
    }
    const float v = a - 0.25f;
    bal[t] = v;
    outBal[b*8 + t] = v;
  }
  __syncthreads();
  if (t == 0) {
    int t0 = 0; float b0 = bal[0];
    #pragma unroll
    for (int e2 = 1; e2 < 8; ++e2) if (bal[e2] > b0) { b0 = bal[e2]; t0 = e2; }
    int t1 = -1; float b1 = -3.4e38f;
    #pragma unroll
    for (int e2 = 0; e2 < 8; ++e2) if (e2 != t0 && bal[e2] > b1) { b1 = bal[e2]; t1 = e2; }
    tk[b*2] = t0; tk[b*2 + 1] = t1;
  }
}

// =================== serial capacity-constrained routing ===================
__global__ __launch_bounds__(256) void route_kernel(const int* __restrict__ tk,
                                                    int* __restrict__ chosen,
                                                    float* __restrict__ outD)
{
  __shared__ int stk[512];
  __shared__ int sch[256];
  const int t = threadIdx.x;
  stk[t] = tk[t]; stk[256 + t] = tk[256 + t];
  __syncthreads();
  if (t == 0) {
    float L0=0,L1=0,L2=0,L3=0,L4=0,L5=0,L6=0,L7=0;
    for (int i = 0; i < 256; ++i) {
      const int a = stk[2*i], c = stk[2*i+1];
      const float la = (a==0)?L0:(a==1)?L1:(a==2)?L2:(a==3)?L3:(a==4)?L4:(a==5)?L5:(a==6)?L6:L7;
      const float lc = (c==0)?L0:(c==1)?L1:(c==2)?L2:(c==3)?L3:(c==4)?L4:(c==5)?L5:(c==6)?L6:L7;
      const int ch = (la < 48.f) ? a : ((lc < 48.f) ? c : ((la <= lc) ? a : c));
      L0 += (ch==0)?1.f:0.f; L1 += (ch==1)?1.f:0.f; L2 += (ch==2)?1.f:0.f; L3 += (ch==3)?1.f:0.f;
      L4 += (ch==4)?1.f:0.f; L5 += (ch==5)?1.f:0.f; L6 += (ch==6)?1.f:0.f; L7 += (ch==7)?1.f:0.f;
      sch[i] = ch;
    }
  }
  __syncthreads();
  const int ch = sch[t];
  chosen[t] = ch;
  #pragma unroll
  for (int e2 = 0; e2 < 8; ++e2) outD[t*8 + e2] = (ch == e2) ? 1.f : 0.f;
}

// ===== expA: conv1 3->32 (32x32) + pool -> bf16 P1gT [18][18][32] ==========
// grid 1024 = b*4 + rowslab; 256 thr = g8(4oc) x c32; compute fp32
__global__ __launch_bounds__(256) void expA_kernel(
    const float* __restrict__ x, const int* __restrict__ chosen,
    const float* __restrict__ ew1, const float* __restrict__ eg1,
    const float* __restrict__ eb1, ushort* __restrict__ P1gT)
{
  __shared__ __align__(16) float sxa[1020];
  __shared__ __align__(16) float sw1t[864];
  __shared__ float bs[32], bb[32];
  const int t = threadIdx.x;
  const int b = blockIdx.x >> 2, rs = blockIdx.x & 3;
  const int r0 = rs * 8;
  const int e = chosen[b];

  // zero this block's share of P1gT borders (68 slots x 32 ic)
  for (int j = t; j < 544; j += 256) {
    int idx = rs*544 + j;
    int slot = idx >> 5, ic = idx & 31, row, col;
    if (slot < 18)      { row = 0;  col = slot; }
    else if (slot < 36) { row = 17; col = slot - 18; }
    else if (slot < 52) { row = 1 + (slot - 36); col = 0; }
    else                { row = 1 + (slot - 52); col = 17; }
    P1gT[b*10368 + (row*18 + col)*32 + ic] = 0;
  }
  for (int j = t; j < 1020; j += 256) {
    int ic = j / 340, r = (j % 340) / 34, cxx = j % 34;
    int gy = r0 - 1 + r, gx = cxx - 1;
    float v = 0.f;
    if (gy >= 0 && gy < 32 && gx >= 0 && gx < 32) v = x[b*3072 + ic*1024 + gy*32 + gx];
    sxa[j] = v;
  }
  for (int j = t; j < 864; j += 256) {
    int oc = j / 27, r = j % 27, ic = r / 9, k = r % 9;
    sw1t[ic*288 + k*32 + oc] = ew1[e*864 + j];
  }
  if (t < 32) { bs[t] = eg1[e*32 + t]*BN_RS; bb[t] = eb1[e*32 + t]; }
  __syncthreads();

  const int g = t >> 5, c = t & 31;
  float acc[4][8];
  #pragma unroll
  for (int o = 0; o < 4; ++o)
    #pragma unroll
    for (int r = 0; r < 8; ++r) acc[o][r] = 0.f;

  for (int ic = 0; ic < 3; ++ic) {
    float w[4][9];
    #pragma unroll
    for (int k = 0; k < 9; ++k) {
      float4 wv = *(const float4*)&sw1t[ic*288 + k*32 + 4*g];
      w[0][k] = wv.x; w[1][k] = wv.y; w[2][k] = wv.z; w[3][k] = wv.w;
    }
    const float* src = &sxa[ic*340 + c];
    #pragma unroll
    for (int rr = 0; rr < 10; ++rr) {
      const float i0 = src[rr*34], i1 = src[rr*34 + 1], i2 = src[rr*34 + 2];
      #pragma unroll
      for (int dr = 0; dr < 3; ++dr) {
        const int r = rr - dr;
        if (r < 0 || r > 7) continue;
        #pragma unroll
        for (int o = 0; o < 4; ++o) {
          acc[o][r] = fmaf(w[o][dr*3+0], i0, acc[o][r]);
          acc[o][r] = fmaf(w[o][dr*3+1], i1, acc[o][r]);
          acc[o][r] = fmaf(w[o][dr*3+2], i2, acc[o][r]);
        }
      }
    }
  }
  #pragma unroll
  for (int o = 0; o < 4; ++o) {
    const int oc = 4*g + o;
    const float s = bs[oc], bo = bb[oc];
    float m[4];
    #pragma unroll
    for (int pr = 0; pr < 4; ++pr) {
      float v0 = fmaxf(fmaf(acc[o][2*pr],   s, bo), 0.f);
      float v1 = fmaxf(fmaf(acc[o][2*pr+1], s, bo), 0.f);
      m[pr] = fmaxf(v0, v1);
    }
    #pragma unroll
    for (int pr = 0; pr < 4; ++pr) {
      float nb = __shfl_xor(m[pr], 1);
      m[pr] = fmaxf(m[pr], nb);
    }
    if (!(c & 1)) {
      const int pc = c >> 1;
      #pragma unroll
      for (int pr = 0; pr < 4; ++pr)
        P1gT[b*10368 + ((rs*4 + pr + 1)*18 + (pc + 1))*32 + oc] = f2bf(m[pr]);
    }
  }
}

// ====== expB (MFMA): conv2 32->64 + bn/relu + maxpool -> P2gT ==============
// grid 256 = one block/sample; 4 waves (wave w owns n-tile w: oc=w*16+col).
// 9-tap implicit GEMM, K=32 per tap. Image slots stride 40 us (16B-aligned).
#define MB_IMG 0       // 324 slots x 40 us = 12960
#define MB_W   12960   // dbuf 2 x (64 oc x 40 us) = 5120; total 18080 us
__global__ __launch_bounds__(256) void expB_mfma(
    const int* __restrict__ chosen, const ushort* __restrict__ P1gT,
    const ushort* __restrict__ ew2b, const float* __restrict__ eg2,
    const float* __restrict__ eb2, ushort* __restrict__ P2gT)
{
  __shared__ __align__(16) ushort smu[18080];
  const int t = threadIdx.x, b = blockIdx.x;
  const int e = chosen[b];
  const int w = t >> 6, l = t & 63;
  const int col = l & 15, quad = l >> 4;

  // zero P2gT borders (36 slots x 64 ic = 288 uint4)
  for (int j = t; j < 288; j += 256) {
    int slot = j >> 3, ofs = (j & 7) * 8, row, cl;
    if (slot < 10)      { row = 0; cl = slot; }
    else if (slot < 20) { row = 9; cl = slot - 10; }
    else if (slot < 28) { row = 1 + (slot - 20); cl = 0; }
    else                { row = 1 + (slot - 28); cl = 9; }
    uint4 z; z.x = 0; z.y = 0; z.z = 0; z.w = 0;
    *(uint4*)&P2gT[b*6400 + (row*10 + cl)*64 + ofs] = z;
  }
  // stage image (10368 us = 1296 uint4)
  for (int j = t; j < 1296; j += 256) {
    int slot = j >> 2, ofs = (j & 3) * 8;
    *(uint4*)&smu[MB_IMG + slot*40 + ofs] = *(const uint4*)&P1gT[b*10368 + j*8];
  }
  // stage W tap 0 (2048 us = 256 uint4)
  {
    int oc = t >> 2, ofs = (t & 3) * 8;
    *(uint4*)&smu[MB_W + oc*40 + ofs] = *(const uint4*)&ew2b[(e*9 + 0)*2048 + t*8];
  }
  __syncthreads();

  floatx4 acc[16];
  #pragma unroll
  for (int mt = 0; mt < 16; ++mt)
    #pragma unroll
    for (int i = 0; i < 4; ++i) acc[mt][i] = 0.f;

  for (int tap = 0; tap < 9; ++tap) {
    if (tap < 8) {
      int oc = t >> 2, ofs = (t & 3) * 8;
      *(uint4*)&smu[MB_W + ((tap+1)&1)*2560 + oc*40 + ofs] =
          *(const uint4*)&ew2b[(e*9 + tap + 1)*2048 + t*8];
    }
    const ushort* wb = &smu[MB_W + (tap&1)*2560];
    short8 bfr = *(const short8*)&wb[(w*16 + col)*40 + quad*8];
    const int dy = tap / 3, dx = tap % 3;
    #pragma unroll
    for (int mt = 0; mt < 16; ++mt) {
      // A: m = mt*16 + col -> y = mt, x = col; pixel (mt+dy, col+dx)
      short8 afr = *(const short8*)
          &smu[MB_IMG + ((mt + dy)*18 + col + dx)*40 + quad*8];
      acc[mt] = __builtin_amdgcn_mfma_f32_16x16x32_bf16(afr, bfr, acc[mt], 0, 0, 0);
    }
    __syncthreads();
  }

  // epilogue: D tile mt -> y = mt, x = quad*4 + reg, oc = w*16 + col.
  // maxpool 2x2 entirely in-lane: y pairs (2mtp,2mtp+1), x pairs (reg 0/1, 2/3)
  const int oc = w*16 + col;
  const float s = eg2[e*64 + oc]*BN_RS, bo = eb2[e*64 + oc];
  #pragma unroll
  for (int mtp = 0; mtp < 8; ++mtp) {
    float a00 = fmaxf(fmaf(acc[2*mtp][0],   s, bo), 0.f);
    float a01 = fmaxf(fmaf(acc[2*mtp][1],   s, bo), 0.f);
    float a02 = fmaxf(fmaf(acc[2*mtp][2],   s, bo), 0.f);
    float a03 = fmaxf(fmaf(acc[2*mtp][3],   s, bo), 0.f);
    float a10 = fmaxf(fmaf(acc[2*mtp+1][0], s, bo), 0.f);
    float a11 = fmaxf(fmaf(acc[2*mtp+1][1], s, bo), 0.f);
    float a12 = fmaxf(fmaf(acc[2*mtp+1][2], s, bo), 0.f);
    float a13 = fmaxf(fmaf(acc[2*mtp+1][3], s, bo), 0.f);
    float p0 = fmaxf(fmaxf(a00, a01), fmaxf(a10, a11));   // px = quad*2
    float p1 = fmaxf(fmaxf(a02, a03), fmaxf(a12, a13));   // px = quad*2+1
    P2gT[b*6400 + ((mtp + 1)*10 + (quad*2 + 1))*64 + oc] = f2bf(p0);
    P2gT[b*6400 + ((mtp + 1)*10 + (quad*2 + 2))*64 + oc] = f2bf(p1);
  }
}

// ====== expC (MFMA): conv3 64->128 + bn/relu + GAP -> featg ================
#define MC_P2T 0      // 100 slots x 72 us
#define MC_WT  7200   // 128 oc x 72 us
__global__ __launch_bounds__(256) void expC_mfma(
    const int* __restrict__ chosen, const ushort* __restrict__ P2gT,
    const ushort* __restrict__ ew3b, const float* __restrict__ eg3,
    const float* __restrict__ eb3, float* __restrict__ featg)
{
  __shared__ __align__(16) ushort smu[16416];
  const int t = threadIdx.x, b = blockIdx.x;
  const int e = chosen[b];
  const int w = t >> 6, l = t & 63;
  const int col = l & 15, quad = l >> 4;

  for (int j = t; j < 800; j += 256) {
    int slot = j >> 3, ico = (j & 7) * 8;
    *(uint4*)&smu[MC_P2T + slot*72 + ico] = *(const uint4*)&P2gT[b*6400 + j*8];
  }

  floatx4 acc[2][4];
  #pragma unroll
  for (int nt = 0; nt < 2; ++nt)
    #pragma unroll
    for (int mt = 0; mt < 4; ++mt)
      #pragma unroll
      for (int i = 0; i < 4; ++i) acc[nt][mt][i] = 0.f;

  for (int tap = 0; tap < 9; ++tap) {
    __syncthreads();
    for (int j = t; j < 1024; j += 256) {
      int oc = j >> 3, ico = (j & 7) * 8;
      *(uint4*)&smu[MC_WT + oc*72 + ico] =
          *(const uint4*)&ew3b[(e*9 + tap)*8192 + j*8];
    }
    __syncthreads();
    const int dy = tap / 3, dx = tap % 3;
    #pragma unroll
    for (int ks = 0; ks < 2; ++ks) {
      short8 bfr[2];
      #pragma unroll
      for (int nt = 0; nt < 2; ++nt) {
        const int oc = w*32 + nt*16 + col;
        bfr[nt] = *(const short8*)&smu[MC_WT + oc*72 + ks*32 + quad*8];
      }
      #pragma unroll
      for (int mt = 0; mt < 4; ++mt) {
        const int m = mt*16 + col;
        const int y = m >> 3, xx = m & 7;
        short8 afr = *(const short8*)
            &smu[MC_P2T + ((y + dy)*10 + (xx + dx))*72 + ks*32 + quad*8];
        acc[0][mt] = __builtin_amdgcn_mfma_f32_16x16x32_bf16(afr, bfr[0], acc[0][mt], 0, 0, 0);
        acc[1][mt] = __builtin_amdgcn_mfma_f32_16x16x32_bf16(afr, bfr[1], acc[1][mt], 0, 0, 0);
      }
    }
  }

  #pragma unroll
  for (int nt = 0; nt < 2; ++nt) {
    const int oc = w*32 + nt*16 + col;
    const float s = eg3[e*128 + oc]*BN_RS, bo = eb3[e*128 + oc];
    float gsum = 0.f;
    #pragma unroll
    for (int mt = 0; mt < 4; ++mt)
      #pragma unroll
      for (int i = 0; i < 4; ++i)
        gsum += fmaxf(fmaf(acc[nt][mt][i], s, bo), 0.f);
    gsum += __shfl_xor(gsum, 16);
    gsum += __shfl_xor(gsum, 32);
    if (quad == 0) featg[b*128 + oc] = gsum * (1.f/64.f);
  }
}

// ================= expD: FC chain -> final =================================
__global__ __launch_bounds__(128) void expD_kernel(
    const int* __restrict__ chosen, const float* __restrict__ featg,
    const float* __restrict__ efw, const float* __restrict__ efb,
    const float* __restrict__ cw1, const float* __restrict__ cb1,
    const float* __restrict__ cw2, const float* __restrict__ cb2,
    float* __restrict__ outF)
{
  __shared__ float sf[128], sff[128], sgg[64];
  const int b = blockIdx.x, t = threadIdx.x;
  const int e = chosen[b];
  sf[t] = featg[b*128 + t];
  __syncthreads();
  {
    float a = efb[e*128 + t];
    const float4* wp = (const float4*)&efw[e*16384 + t*128];
    #pragma unroll 8
    for (int i4 = 0; i4 < 32; ++i4) {
      float4 wv = wp[i4];
      a = fmaf(wv.x, sf[4*i4], a);   a = fmaf(wv.y, sf[4*i4+1], a);
      a = fmaf(wv.z, sf[4*i4+2], a); a = fmaf(wv.w, sf[4*i4+3], a);
    }
    sff[t] = fmaxf(a, 0.f);
  }
  __syncthreads();
  if (t < 64) {
    float a = cb1[e*64 + t];
    const float4* wp = (const float4*)&cw1[e*8192 + t*128];
    #pragma unroll 8
    for (int i4 = 0; i4 < 32; ++i4) {
      float4 wv = wp[i4];
      a = fmaf(wv.x, sff[4*i4], a);   a = fmaf(wv.y, sff[4*i4+1], a);
      a = fmaf(wv.z, sff[4*i4+2], a); a = fmaf(wv.w, sff[4*i4+3], a);
    }
    sgg[t] = fmaxf(a, 0.f);
  }
  __syncthreads();
  if (t < 10) {
    float a = cb2[e*10 + t];
    const float4* wp = (const float4*)&cw2[e*640 + t*64];
    #pragma unroll
    for (int i4 = 0; i4 < 16; ++i4) {
      float4 wv = wp[i4];
      a = fmaf(wv.x, sgg[4*i4], a);   a = fmaf(wv.y, sgg[4*i4+1], a);
      a = fmaf(wv.z, sgg[4*i4+2], a); a = fmaf(wv.w, sgg[4*i4+3], a);
    }
    outF[b*10 + t] = a;
  }
}

// ================================ host =====================================
extern "C" void kernel_launch(void* const* d_in, const int* in_sizes, int n_in,
                              void* d_out, int out_size, void* d_ws, size_t ws_size,
                              hipStream_t stream)
{
  const float* x   = (const float*)d_in[0];
  const float* tw1 = (const float*)d_in[1];
  const float* tg1 = (const float*)d_in[2];
  const float* tb1 = (const float*)d_in[3];
  const float* tw2 = (const float*)d_in[4];
  const float* tg2 = (const float*)d_in[5];
  const float* tb2 = (const float*)d_in[6];
  const float* tfw = (const float*)d_in[7];
  const float* tfb = (const float*)d_in[8];
  const float* gw1 = (const float*)d_in[9];
  const float* gb1 = (const float*)d_in[10];
  const float* gw2 = (const float*)d_in[11];
  const float* gb2 = (const float*)d_in[12];
  const float* ew1 = (const float*)d_in[13];
  const float* eg1 = (const float*)d_in[14];
  const float* eb1 = (const float*)d_in[15];
  const float* ew2 = (const float*)d_in[16];
  const float* eg2 = (const float*)d_in[17];
  const float* eb2 = (const float*)d_in[18];
  const float* ew3 = (const float*)d_in[19];
  const float* eg3 = (const float*)d_in[20];
  const float* eb3 = (const float*)d_in[21];
  const float* efw = (const float*)d_in[22];
  const float* efb = (const float*)d_in[23];
  const float* cw1 = (const float*)d_in[24];
  const float* cb1 = (const float*)d_in[25];
  const float* cw2 = (const float*)d_in[26];
  const float* cb2 = (const float*)d_in[27];

  float*  out    = (float*)d_out;
  char*   ws     = (char*)d_ws;
  float*  tfp    = (float*)(ws + WS_TFP);
  int*    tk     = (int*)(ws + WS_TK);
  int*    chosen = (int*)(ws + WS_CHOSEN);
  float*  tw2t   = (float*)(ws + WS_TW2T);
  ushort* ew2b   = (ushort*)(ws + WS_EW2B);
  ushort* ew3b   = (ushort*)(ws + WS_EW3B);
  float*  featg  = (float*)(ws + WS_FEATG);
  ushort* P1gT   = (ushort*)(ws + WS_P1GT);
  ushort* P2gT   = (ushort*)(ws + WS_P2GT);

  prep_kernel<<<2916, 256, 0, stream>>>(tw2, ew2, ew3, tw2t, ew2b, ew3b);
  trunk_kernel<<<2048, 256, 0, stream>>>(x, tw1, tg1, tb1, tw2t, tg2, tb2, tfp);
  gate_kernel<<<256, 64, 0, stream>>>(tfp, tfw, tfb, gw1, gb1, gw2, gb2, out + 2560, tk);
  route_kernel<<<1, 256, 0, stream>>>(tk, chosen, out + 4608);
  expA_kernel<<<1024, 256, 0, stream>>>(x, chosen, ew1, eg1, eb1, P1gT);
  expB_mfma<<<256, 256, 0, stream>>>(chosen, P1gT, ew2b, eg2, eb2, P2gT);
  expC_mfma<<<256, 256, 0, stream>>>(chosen, P2gT, ew3b, eg3, eb3, featg);
  expD_kernel<<<256, 128, 0, stream>>>(chosen, featg, efw, efb, cw1, cb1, cw2, cb2, out);
}

// Round 9
// 325.855 us; speedup vs baseline: 1.3560x; 1.0919x over previous
//
#include <hip/hip_runtime.h>
#include <hip/hip_bf16.h>
#include <math.h>

// ---------------------------------------------------------------------------
// DistributedMoE forward, MI355X — R9: kernel-count collapse 8 -> 3.
// R8 ledger showed ~10us/kernel launch overhead + small-kernel latency floors
// = ~40% of wall. This round: (1) trunk reverts to R6's LDS weight staging
// (109us measured) but gathers from raw tw2 (prep deleted); (2) bf16 weight
// conversion moved to a grid-stride tail on gate; (3) route deleted — each
// consumer block replays the capacity scan from tk (deterministic); (4) one
// per-sample expert kernel: conv1 fp32 -> LDS bf16 image -> conv2 MFMA ->
// LDS P2 -> conv3 MFMA -> LDS feat -> FC chain. Expert numerics bit-identical
// to R8 (absmax should stay 0.0078125).
//
// out (fp32): final[256,10] @0, balanced[256,8] @2560, D[256,8] @4608
// ---------------------------------------------------------------------------

#define BN_RS (1.0f / sqrtf(1.00001f))

typedef __attribute__((ext_vector_type(8))) short short8;
typedef __attribute__((ext_vector_type(4))) float floatx4;

static __device__ __forceinline__ ushort f2bf(float f) {
  unsigned u = __float_as_uint(f);
  unsigned r = (u + 0x7fffu + ((u >> 16) & 1u)) >> 16;   // RNE
  return (ushort)r;
}

// ws byte offsets
#define WS_TFP    0           // f32[256][8][32]
#define WS_TK     262144      // i32[512]
#define WS_EW2B   264192      // bf16[8][9tap][64oc][32ic]  (294912 B)
#define WS_EW3B   559104      // bf16[8][9tap][128oc][64ic] (1179648 B)

// ====== fused trunk: conv1 (in-LDS) + conv2 + pool + partial sums ==========
// R6 structure (109us measured); weight staging gathers directly from tw2.
#define TF_SA1 0
#define TF_WD  6464
#define TF_X   6464
#define TF_W1  7184
#define TF_BN  8832
__global__ __launch_bounds__(256, 4) void trunk_kernel(
    const float* __restrict__ x, const float* __restrict__ tw1,
    const float* __restrict__ tg1, const float* __restrict__ tb1,
    const float* __restrict__ tw2, const float* __restrict__ tg2,
    const float* __restrict__ tb2, float* __restrict__ tfp)
{
  __shared__ __align__(16) float sm[8960];
  const int t = threadIdx.x;
  const int b = blockIdx.x >> 3, blk = blockIdx.x & 7;
  const int rs = blk >> 1, ch = blk & 1;
  const int r0 = rs*8, c0 = ch*16;

  for (int j = t; j < 720; j += 256) {
    int ic = j / 240, rem = j % 240, rr = rem / 20, cx = rem % 20;
    int gy = r0 - 2 + rr, gx = c0 - 2 + cx;
    float v = 0.f;
    if (gy >= 0 && gy < 32 && gx >= 0 && gx < 32) v = x[b*3072 + ic*1024 + gy*32 + gx];
    sm[TF_X + j] = v;
  }
  for (int j = t; j < 864; j += 256) sm[TF_W1 + j] = tw1[j];
  if (t < 32) {
    sm[TF_BN + t] = tg1[t]*BN_RS;      sm[TF_BN + 32 + t] = tb1[t];
    sm[TF_BN + 64 + t] = tg2[t]*BN_RS; sm[TF_BN + 96 + t] = tb2[t];
  }
  __syncthreads();

  // conv1 (summation order identical to R6/R7/R8)
  {
    float acc1[18];
    for (int it = 0; it < 2; ++it) {
      const int item = it*256 + t;
      if (item < 320) {
        const int oc = item & 31, rr = item >> 5;
        const int gy = r0 - 1 + rr;
        #pragma unroll
        for (int c2 = 0; c2 < 18; ++c2) acc1[c2] = 0.f;
        if (gy >= 0 && gy < 32) {
          for (int ic = 0; ic < 3; ++ic) {
            float w[9];
            #pragma unroll
            for (int k = 0; k < 9; ++k) w[k] = sm[TF_W1 + oc*27 + ic*9 + k];
            #pragma unroll
            for (int wr = 0; wr < 3; ++wr) {
              float rv[20];
              const float4* rp = (const float4*)&sm[TF_X + ic*240 + (rr + wr)*20];
              #pragma unroll
              for (int j4 = 0; j4 < 5; ++j4) {
                float4 v4 = rp[j4];
                rv[4*j4] = v4.x; rv[4*j4+1] = v4.y; rv[4*j4+2] = v4.z; rv[4*j4+3] = v4.w;
              }
              #pragma unroll
              for (int c2 = 0; c2 < 18; ++c2)
                #pragma unroll
                for (int kx = 0; kx < 3; ++kx)
                  acc1[c2] = fmaf(w[wr*3 + kx], rv[c2 + kx], acc1[c2]);
            }
          }
        }
        const float s = sm[TF_BN + oc], bo = sm[TF_BN + 32 + oc];
        #pragma unroll
        for (int c2 = 0; c2 < 18; ++c2) {
          const int gx = c0 - 1 + c2;
          float v = 0.f;
          if (gy >= 0 && gy < 32 && gx >= 0 && gx < 32)
            v = fmaxf(fmaf(acc1[c2], s, bo), 0.f);
          sm[TF_SA1 + oc*202 + rr*20 + c2] = v;
        }
      }
    }
  }
  __syncthreads();

  // stage w2 chunk 0 directly from raw tw2 (same values as old tw2t)
  for (int j = t; j < 1152; j += 256) {
    int qq = j / 288, r = j % 288, k = r / 32, oc = r & 31;
    sm[TF_WD + qq*296 + r] = tw2[oc*288 + (qq*8)*9 + k];
  }
  __syncthreads();

  const int g = t >> 5, q = (t >> 3) & 3, cp = t & 7;
  float acc[4][8][2];
  #pragma unroll
  for (int o = 0; o < 4; ++o)
    #pragma unroll
    for (int r = 0; r < 8; ++r) { acc[o][r][0] = 0.f; acc[o][r][1] = 0.f; }

  for (int cc = 0; cc < 8; ++cc) {
    if (cc < 7) {
      for (int j = t; j < 1152; j += 256) {
        int qq = j / 288, r = j % 288, k = r / 32, oc = r & 31;
        sm[TF_WD + ((cc+1)&1)*1184 + qq*296 + r] =
            tw2[oc*288 + (qq*8 + cc + 1)*9 + k];
      }
    }
    const float* wb = &sm[TF_WD + (cc&1)*1184 + q*296];
    float w[4][9];
    #pragma unroll
    for (int k = 0; k < 9; ++k) {
      float4 wv = *(const float4*)&wb[k*32 + 4*g];
      w[0][k] = wv.x; w[1][k] = wv.y; w[2][k] = wv.z; w[3][k] = wv.w;
    }
    const float* src = &sm[TF_SA1 + (q*8+cc)*202 + 2*cp];
    #pragma unroll
    for (int rr = 0; rr < 10; ++rr) {
      float2 va = *(const float2*)&src[rr*20];
      float2 vb = *(const float2*)&src[rr*20 + 2];
      const float i0 = va.x, i1 = va.y, i2 = vb.x, i3 = vb.y;
      #pragma unroll
      for (int dr = 0; dr < 3; ++dr) {
        const int r = rr - dr;
        if (r < 0 || r > 7) continue;
        #pragma unroll
        for (int o = 0; o < 4; ++o) {
          acc[o][r][0] = fmaf(w[o][dr*3+0], i0, acc[o][r][0]);
          acc[o][r][1] = fmaf(w[o][dr*3+0], i1, acc[o][r][1]);
          acc[o][r][0] = fmaf(w[o][dr*3+1], i1, acc[o][r][0]);
          acc[o][r][1] = fmaf(w[o][dr*3+1], i2, acc[o][r][1]);
          acc[o][r][0] = fmaf(w[o][dr*3+2], i2, acc[o][r][0]);
          acc[o][r][1] = fmaf(w[o][dr*3+2], i3, acc[o][r][1]);
        }
      }
    }
    __syncthreads();
  }

  const int slot = g*8 + cp;
  if (q >= 2) {
    float* dst = &sm[(q-2)*4168 + slot*65];
    #pragma unroll
    for (int o = 0; o < 4; ++o)
      #pragma unroll
      for (int r = 0; r < 8; ++r) {
        dst[o*16 + r*2 + 0] = acc[o][r][0];
        dst[o*16 + r*2 + 1] = acc[o][r][1];
      }
  }
  __syncthreads();
  if (q < 2) {
    const float* s0 = &sm[q*4168 + slot*65];
    #pragma unroll
    for (int o = 0; o < 4; ++o)
      #pragma unroll
      for (int r = 0; r < 8; ++r) {
        acc[o][r][0] += s0[o*16 + r*2 + 0];
        acc[o][r][1] += s0[o*16 + r*2 + 1];
      }
  }
  __syncthreads();
  if (q == 1) {
    float* dst = &sm[slot*65];
    #pragma unroll
    for (int o = 0; o < 4; ++o)
      #pragma unroll
      for (int r = 0; r < 8; ++r) {
        dst[o*16 + r*2 + 0] = acc[o][r][0];
        dst[o*16 + r*2 + 1] = acc[o][r][1];
      }
  }
  __syncthreads();
  if (q == 0) {
    const float* s0 = &sm[slot*65];
    #pragma unroll
    for (int o = 0; o < 4; ++o) {
      const int oc = 4*g + o;
      const float s = sm[TF_BN + 64 + oc], bo = sm[TF_BN + 96 + oc];
      float ps = 0.f;
      #pragma unroll
      for (int pr = 0; pr < 4; ++pr) {
        float c00 = acc[o][2*pr][0]   + s0[o*16 + (2*pr)*2 + 0];
        float c01 = acc[o][2*pr][1]   + s0[o*16 + (2*pr)*2 + 1];
        float c10 = acc[o][2*pr+1][0] + s0[o*16 + (2*pr+1)*2 + 0];
        float c11 = acc[o][2*pr+1][1] + s0[o*16 + (2*pr+1)*2 + 1];
        float v0 = fmaxf(fmaf(c00, s, bo), 0.f);
        float v1 = fmaxf(fmaf(c01, s, bo), 0.f);
        float v2 = fmaxf(fmaf(c10, s, bo), 0.f);
        float v3 = fmaxf(fmaf(c11, s, bo), 0.f);
        ps += fmaxf(fmaxf(v0, v1), fmaxf(v2, v3));
      }
      ps += __shfl_xor(ps, 1);
      ps += __shfl_xor(ps, 2);
      ps += __shfl_xor(ps, 4);
      if ((t & 31) == 0) tfp[b*256 + (rs*2 + ch)*32 + oc] = ps;
    }
  }
}

// ============== gate + top2 (+ bf16 weight-convert tail) ===================
__global__ __launch_bounds__(64) void gate_kernel(
    const float* __restrict__ tfp, const float* __restrict__ tfw, const float* __restrict__ tfb,
    const float* __restrict__ gw1, const float* __restrict__ gb1,
    const float* __restrict__ gw2, const float* __restrict__ gb2,
    const float* __restrict__ ew2, const float* __restrict__ ew3,
    ushort* __restrict__ ew2b, ushort* __restrict__ ew3b,
    float* __restrict__ outBal, int* __restrict__ tk)
{
  __shared__ float feat[128], rf[64], g1[32], bal[8];
  const int b = blockIdx.x, t = threadIdx.x;
  #pragma unroll
  for (int h = 0; h < 2; ++h) {
    const int f = t + 64*h;
    const int oc = f >> 2, qy = (f >> 1) & 1, qx = f & 1;
    feat[f] = (tfp[b*256 + (4*qy + qx)*32 + oc] +
               tfp[b*256 + (4*qy + 2 + qx)*32 + oc]) * (1.f/64.f);
  }
  __syncthreads();
  {
    float a = tfb[t];
    const float4* wp = (const float4*)&tfw[t*128];
    #pragma unroll 8
    for (int i4 = 0; i4 < 32; ++i4) {
      float4 wv = wp[i4];
      a = fmaf(wv.x, feat[4*i4], a);   a = fmaf(wv.y, feat[4*i4+1], a);
      a = fmaf(wv.z, feat[4*i4+2], a); a = fmaf(wv.w, feat[4*i4+3], a);
    }
    rf[t] = fmaxf(a, 0.f);
  }
  __syncthreads();
  if (t < 32) {
    float a = gb1[t];
    const float4* wp = (const float4*)&gw1[t*64];
    #pragma unroll
    for (int i4 = 0; i4 < 16; ++i4) {
      float4 wv = wp[i4];
      a = fmaf(wv.x, rf[4*i4], a);   a = fmaf(wv.y, rf[4*i4+1], a);
      a = fmaf(wv.z, rf[4*i4+2], a); a = fmaf(wv.w, rf[4*i4+3], a);
    }
    g1[t] = fmaxf(a, 0.f);
  }
  __syncthreads();
  if (t < 8) {
    float a = gb2[t];
    const float4* wp = (const float4*)&gw2[t*32];
    #pragma unroll
    for (int i4 = 0; i4 < 8; ++i4) {
      float4 wv = wp[i4];
      a = fmaf(wv.x, g1[4*i4], a);   a = fmaf(wv.y, g1[4*i4+1], a);
      a = fmaf(wv.z, g1[4*i4+2], a); a = fmaf(wv.w, g1[4*i4+3], a);
    }
    const float v = a - 0.25f;   // boost=0, -LOAD_PEN*usage = -0.25
    bal[t] = v;
    outBal[b*8 + t] = v;
  }
  __syncthreads();
  if (t == 0) {
    int t0 = 0; float b0 = bal[0];
    #pragma unroll
    for (int e2 = 1; e2 < 8; ++e2) if (bal[e2] > b0) { b0 = bal[e2]; t0 = e2; }
    int t1 = -1; float b1 = -3.4e38f;
    #pragma unroll
    for (int e2 = 0; e2 < 8; ++e2) if (e2 != t0 && bal[e2] > b1) { b1 = bal[e2]; t1 = e2; }
    tk[b*2] = t0; tk[b*2 + 1] = t1;
  }

  // ---- tail: bf16 weight conversion (was prep_kernel) ----
  for (int j = blockIdx.x*64 + t; j < 737280; j += 16384) {
    if (j < 147456) {                        // ew2b [e][tap][oc64][ic32]
      int e = j / 18432, r2 = j % 18432;
      int tap = r2 / 2048, r3 = r2 % 2048;
      int oc = r3 / 32, ic = r3 % 32;
      ew2b[j] = f2bf(ew2[e*18432 + oc*288 + ic*9 + tap]);
    } else {                                 // ew3b [e][tap][oc128][ic64]
      int jj = j - 147456;
      int e = jj / 73728, r2 = jj % 73728;
      int tap = r2 / 8192, r3 = r2 % 8192;
      int oc = r3 / 64, ic = r3 % 64;
      ew3b[jj] = f2bf(ew3[e*73728 + oc*576 + ic*9 + tap]);
    }
  }
}

// ========== expALL: scan + conv1 + conv2(MFMA) + conv3(MFMA) + FC ==========
// grid 256 = one block/sample, 256 thr. LDS (ushort offsets):
//   IMG   @0      324x40 = 12960 (conv1 out; dead after conv2)
//   P2T   @0      100x72 = 7200  (overlays IMG after conv2)
//   feat  @7200   128 f32 (us 7200..7456); sff @7456; sgg @7712..7840
//   W2    @12960  dbuf 2x2560
//   xf32  @18080  [3][34][34]+w1t+bn1 (floats; dead after conv1)
//   WT    @18080  128x72 = 9216 (conv3 weights, overlays xf32)
#define XA_IMG  0
#define XA_W2   12960
#define XA_WT   18080
#define XA_FEAT 3600      // float offset (us 7200)
#define XA_SFF  3728      // float offset
#define XA_SGG  3856      // float offset
#define XA_XF   9040      // float offset (us 18080)
#define XA_W1F  12508     // float offset
#define XA_BN1F 13372     // float offset
__global__ __launch_bounds__(256) void expALL_kernel(
    const float* __restrict__ x, const int* __restrict__ tk,
    const float* __restrict__ ew1, const float* __restrict__ eg1,
    const float* __restrict__ eb1, const ushort* __restrict__ ew2b,
    const float* __restrict__ eg2, const float* __restrict__ eb2,
    const ushort* __restrict__ ew3b, const float* __restrict__ eg3,
    const float* __restrict__ eb3, const float* __restrict__ efw,
    const float* __restrict__ efb, const float* __restrict__ cw1,
    const float* __restrict__ cb1, const float* __restrict__ cw2,
    const float* __restrict__ cb2, float* __restrict__ outF,
    float* __restrict__ outD)
{
  __shared__ __align__(16) ushort smu[27296];
  __shared__ int stk[512];
  __shared__ int sch;
  float* smf = (float*)smu;
  const int t = threadIdx.x, b = blockIdx.x;

  // ---- 1) capacity scan replay (deterministic; early-exit at own sample) ----
  stk[t] = tk[t]; stk[256 + t] = tk[256 + t];
  __syncthreads();
  if (t == 0) {
    float L0=0,L1=0,L2=0,L3=0,L4=0,L5=0,L6=0,L7=0;
    int chv = 0;
    for (int i = 0; i <= b; ++i) {
      const int a = stk[2*i], c = stk[2*i+1];
      const float la = (a==0)?L0:(a==1)?L1:(a==2)?L2:(a==3)?L3:(a==4)?L4:(a==5)?L5:(a==6)?L6:L7;
      const float lc = (c==0)?L0:(c==1)?L1:(c==2)?L2:(c==3)?L3:(c==4)?L4:(c==5)?L5:(c==6)?L6:L7;
      chv = (la < 48.f) ? a : ((lc < 48.f) ? c : ((la <= lc) ? a : c));
      L0 += (chv==0)?1.f:0.f; L1 += (chv==1)?1.f:0.f; L2 += (chv==2)?1.f:0.f; L3 += (chv==3)?1.f:0.f;
      L4 += (chv==4)?1.f:0.f; L5 += (chv==5)?1.f:0.f; L6 += (chv==6)?1.f:0.f; L7 += (chv==7)?1.f:0.f;
    }
    sch = chv;
  }
  __syncthreads();
  const int e = sch;
  if (t < 8) outD[b*8 + t] = (t == e) ? 1.f : 0.f;

  // ---- 2) zero IMG; stage x [3][34][34] (zero-pad), w1t, bn1 ----
  {
    uint4 z; z.x = 0; z.y = 0; z.z = 0; z.w = 0;
    for (int j = t; j < 1620; j += 256) ((uint4*)smu)[j] = z;
  }
  for (int j = t; j < 3468; j += 256) {
    int ic = j / 1156, rem = j % 1156, p = rem / 34, cpd = rem % 34;
    int gy = p - 1, gx = cpd - 1;
    float v = 0.f;
    if (gy >= 0 && gy < 32 && gx >= 0 && gx < 32) v = x[b*3072 + ic*1024 + gy*32 + gx];
    smf[XA_XF + j] = v;
  }
  for (int j = t; j < 864; j += 256) {
    int oc = j / 27, r = j % 27, ic = r / 9, k = r % 9;
    smf[XA_W1F + ic*288 + k*32 + oc] = ew1[e*864 + j];
  }
  if (t < 32) { smf[XA_BN1F + t] = eg1[e*32 + t]*BN_RS; smf[XA_BN1F + 32 + t] = eb1[e*32 + t]; }
  __syncthreads();

  // ---- 3) conv1 fp32 (expA math, 4 slabs) -> bf16 IMG ----
  {
    const int g = t >> 5, c = t & 31;
    for (int rs = 0; rs < 4; ++rs) {
      const int r0 = rs * 8;
      float acc[4][8];
      #pragma unroll
      for (int o = 0; o < 4; ++o)
        #pragma unroll
        for (int r = 0; r < 8; ++r) acc[o][r] = 0.f;
      for (int ic = 0; ic < 3; ++ic) {
        float w[4][9];
        #pragma unroll
        for (int k = 0; k < 9; ++k) {
          float4 wv = *(const float4*)&smf[XA_W1F + ic*288 + k*32 + 4*g];
          w[0][k] = wv.x; w[1][k] = wv.y; w[2][k] = wv.z; w[3][k] = wv.w;
        }
        const float* src = &smf[XA_XF + ic*1156 + r0*34 + c];
        #pragma unroll
        for (int rr = 0; rr < 10; ++rr) {
          const float i0 = src[rr*34], i1 = src[rr*34 + 1], i2 = src[rr*34 + 2];
          #pragma unroll
          for (int dr = 0; dr < 3; ++dr) {
            const int r = rr - dr;
            if (r < 0 || r > 7) continue;
            #pragma unroll
            for (int o = 0; o < 4; ++o) {
              acc[o][r] = fmaf(w[o][dr*3+0], i0, acc[o][r]);
              acc[o][r] = fmaf(w[o][dr*3+1], i1, acc[o][r]);
              acc[o][r] = fmaf(w[o][dr*3+2], i2, acc[o][r]);
            }
          }
        }
      }
      #pragma unroll
      for (int o = 0; o < 4; ++o) {
        const int oc = 4*g + o;
        const float s = smf[XA_BN1F + oc], bo = smf[XA_BN1F + 32 + oc];
        float m[4];
        #pragma unroll
        for (int pr = 0; pr < 4; ++pr) {
          float v0 = fmaxf(fmaf(acc[o][2*pr],   s, bo), 0.f);
          float v1 = fmaxf(fmaf(acc[o][2*pr+1], s, bo), 0.f);
          m[pr] = fmaxf(v0, v1);
        }
        #pragma unroll
        for (int pr = 0; pr < 4; ++pr) {
          float nb = __shfl_xor(m[pr], 1);
          m[pr] = fmaxf(m[pr], nb);
        }
        if (!(c & 1)) {
          const int pc = c >> 1;
          #pragma unroll
          for (int pr = 0; pr < 4; ++pr)
            smu[XA_IMG + ((rs*4 + pr + 1)*18 + (pc + 1))*40 + oc] = f2bf(m[pr]);
        }
      }
    }
  }
  // stage W2 tap 0 (region disjoint from IMG/xf32)
  {
    int oc = t >> 2, ofs = (t & 3) * 8;
    *(uint4*)&smu[XA_W2 + oc*40 + ofs] = *(const uint4*)&ew2b[(e*9 + 0)*2048 + t*8];
  }
  __syncthreads();

  // ---- 4) conv2 MFMA (expB verbatim) ----
  const int wid = t >> 6, l = t & 63;
  const int col = l & 15, quad = l >> 4;
  {
    floatx4 acc[16];
    #pragma unroll
    for (int mt = 0; mt < 16; ++mt)
      #pragma unroll
      for (int i = 0; i < 4; ++i) acc[mt][i] = 0.f;

    for (int tap = 0; tap < 9; ++tap) {
      if (tap < 8) {
        int oc = t >> 2, ofs = (t & 3) * 8;
        *(uint4*)&smu[XA_W2 + ((tap+1)&1)*2560 + oc*40 + ofs] =
            *(const uint4*)&ew2b[(e*9 + tap + 1)*2048 + t*8];
      }
      const ushort* wb = &smu[XA_W2 + (tap&1)*2560];
      short8 bfr = *(const short8*)&wb[(wid*16 + col)*40 + quad*8];
      const int dy = tap / 3, dx = tap % 3;
      #pragma unroll
      for (int mt = 0; mt < 16; ++mt) {
        short8 afr = *(const short8*)
            &smu[XA_IMG + ((mt + dy)*18 + col + dx)*40 + quad*8];
        acc[mt] = __builtin_amdgcn_mfma_f32_16x16x32_bf16(afr, bfr, acc[mt], 0, 0, 0);
      }
      __syncthreads();
    }

    // ---- 5) P2T into LDS (overlays dead IMG): borders + pooled interior ----
    {
      uint4 z; z.x = 0; z.y = 0; z.z = 0; z.w = 0;
      for (int j = t; j < 288; j += 256) {
        int slot = j >> 3, ofs = (j & 7) * 8, row, cl;
        if (slot < 10)      { row = 0; cl = slot; }
        else if (slot < 20) { row = 9; cl = slot - 10; }
        else if (slot < 28) { row = 1 + (slot - 20); cl = 0; }
        else                { row = 1 + (slot - 28); cl = 9; }
        *(uint4*)&smu[(row*10 + cl)*72 + ofs] = z;
      }
    }
    const int oc2 = wid*16 + col;
    const float s2 = eg2[e*64 + oc2]*BN_RS, bo2 = eb2[e*64 + oc2];
    #pragma unroll
    for (int mtp = 0; mtp < 8; ++mtp) {
      float a00 = fmaxf(fmaf(acc[2*mtp][0],   s2, bo2), 0.f);
      float a01 = fmaxf(fmaf(acc[2*mtp][1],   s2, bo2), 0.f);
      float a02 = fmaxf(fmaf(acc[2*mtp][2],   s2, bo2), 0.f);
      float a03 = fmaxf(fmaf(acc[2*mtp][3],   s2, bo2), 0.f);
      float a10 = fmaxf(fmaf(acc[2*mtp+1][0], s2, bo2), 0.f);
      float a11 = fmaxf(fmaf(acc[2*mtp+1][1], s2, bo2), 0.f);
      float a12 = fmaxf(fmaf(acc[2*mtp+1][2], s2, bo2), 0.f);
      float a13 = fmaxf(fmaf(acc[2*mtp+1][3], s2, bo2), 0.f);
      float p0 = fmaxf(fmaxf(a00, a01), fmaxf(a10, a11));
      float p1 = fmaxf(fmaxf(a02, a03), fmaxf(a12, a13));
      smu[((mtp + 1)*10 + (quad*2 + 1))*72 + oc2] = f2bf(p0);
      smu[((mtp + 1)*10 + (quad*2 + 2))*72 + oc2] = f2bf(p1);
    }
  }
  __syncthreads();

  // ---- 6) conv3 MFMA (expC verbatim; P2T @0 stride 72, WT @XA_WT) ----
  {
    floatx4 acc[2][4];
    #pragma unroll
    for (int nt = 0; nt < 2; ++nt)
      #pragma unroll
      for (int mt = 0; mt < 4; ++mt)
        #pragma unroll
        for (int i = 0; i < 4; ++i) acc[nt][mt][i] = 0.f;

    for (int tap = 0; tap < 9; ++tap) {
      __syncthreads();
      for (int j = t; j < 1024; j += 256) {
        int oc = j >> 3, ico = (j & 7) * 8;
        *(uint4*)&smu[XA_WT + oc*72 + ico] =
            *(const uint4*)&ew3b[(e*9 + tap)*8192 + j*8];
      }
      __syncthreads();
      const int dy = tap / 3, dx = tap % 3;
      #pragma unroll
      for (int ks = 0; ks < 2; ++ks) {
        short8 bfr[2];
        #pragma unroll
        for (int nt = 0; nt < 2; ++nt) {
          const int oc = wid*32 + nt*16 + col;
          bfr[nt] = *(const short8*)&smu[XA_WT + oc*72 + ks*32 + quad*8];
        }
        #pragma unroll
        for (int mt = 0; mt < 4; ++mt) {
          const int m = mt*16 + col;
          const int y = m >> 3, xx = m & 7;
          short8 afr = *(const short8*)
              &smu[((y + dy)*10 + (xx + dx))*72 + ks*32 + quad*8];
          acc[0][mt] = __builtin_amdgcn_mfma_f32_16x16x32_bf16(afr, bfr[0], acc[0][mt], 0, 0, 0);
          acc[1][mt] = __builtin_amdgcn_mfma_f32_16x16x32_bf16(afr, bfr[1], acc[1][mt], 0, 0, 0);
        }
      }
    }

    // epilogue: bn + relu + GAP -> feat in LDS
    #pragma unroll
    for (int nt = 0; nt < 2; ++nt) {
      const int oc = wid*32 + nt*16 + col;
      const float s = eg3[e*128 + oc]*BN_RS, bo = eb3[e*128 + oc];
      float gsum = 0.f;
      #pragma unroll
      for (int mt = 0; mt < 4; ++mt)
        #pragma unroll
        for (int i = 0; i < 4; ++i)
          gsum += fmaxf(fmaf(acc[nt][mt][i], s, bo), 0.f);
      gsum += __shfl_xor(gsum, 16);
      gsum += __shfl_xor(gsum, 32);
      if (quad == 0) smf[XA_FEAT + oc] = gsum * (1.f/64.f);
    }
  }
  __syncthreads();

  // ---- 7) FC chain (expD verbatim, feat from LDS) ----
  if (t < 128) {
    float a = efb[e*128 + t];
    const float4* wp = (const float4*)&efw[e*16384 + t*128];
    #pragma unroll 8
    for (int i4 = 0; i4 < 32; ++i4) {
      float4 wv = wp[i4];
      a = fmaf(wv.x, smf[XA_FEAT + 4*i4],     a);
      a = fmaf(wv.y, smf[XA_FEAT + 4*i4 + 1], a);
      a = fmaf(wv.z, smf[XA_FEAT + 4*i4 + 2], a);
      a = fmaf(wv.w, smf[XA_FEAT + 4*i4 + 3], a);
    }
    smf[XA_SFF + t] = fmaxf(a, 0.f);
  }
  __syncthreads();
  if (t < 64) {
    float a = cb1[e*64 + t];
    const float4* wp = (const float4*)&cw1[e*8192 + t*128];
    #pragma unroll 8
    for (int i4 = 0; i4 < 32; ++i4) {
      float4 wv = wp[i4];
      a = fmaf(wv.x, smf[XA_SFF + 4*i4],     a);
      a = fmaf(wv.y, smf[XA_SFF + 4*i4 + 1], a);
      a = fmaf(wv.z, smf[XA_SFF + 4*i4 + 2], a);
      a = fmaf(wv.w, smf[XA_SFF + 4*i4 + 3], a);
    }
    smf[XA_SGG + t] = fmaxf(a, 0.f);
  }
  __syncthreads();
  if (t < 10) {
    float a = cb2[e*10 + t];
    const float4* wp = (const float4*)&cw2[e*640 + t*64];
    #pragma unroll
    for (int i4 = 0; i4 < 16; ++i4) {
      float4 wv = wp[i4];
      a = fmaf(wv.x, smf[XA_SGG + 4*i4],     a);
      a = fmaf(wv.y, smf[XA_SGG + 4*i4 + 1], a);
      a = fmaf(wv.z, smf[XA_SGG + 4*i4 + 2], a);
      a = fmaf(wv.w, smf[XA_SGG + 4*i4 + 3], a);
    }
    outF[b*10 + t] = a;   // routing weight is exactly 1.0 for the chosen expert
  }
}

// ================================ host =====================================
extern "C" void kernel_launch(void* const* d_in, const int* in_sizes, int n_in,
                              void* d_out, int out_size, void* d_ws, size_t ws_size,
                              hipStream_t stream)
{
  const float* x   = (const float*)d_in[0];
  const float* tw1 = (const float*)d_in[1];
  const float* tg1 = (const float*)d_in[2];
  const float* tb1 = (const float*)d_in[3];
  const float* tw2 = (const float*)d_in[4];
  const float* tg2 = (const float*)d_in[5];
  const float* tb2 = (const float*)d_in[6];
  const float* tfw = (const float*)d_in[7];
  const float* tfb = (const float*)d_in[8];
  const float* gw1 = (const float*)d_in[9];
  const float* gb1 = (const float*)d_in[10];
  const float* gw2 = (const float*)d_in[11];
  const float* gb2 = (const float*)d_in[12];
  const float* ew1 = (const float*)d_in[13];
  const float* eg1 = (const float*)d_in[14];
  const float* eb1 = (const float*)d_in[15];
  const float* ew2 = (const float*)d_in[16];
  const float* eg2 = (const float*)d_in[17];
  const float* eb2 = (const float*)d_in[18];
  const float* ew3 = (const float*)d_in[19];
  const float* eg3 = (const float*)d_in[20];
  const float* eb3 = (const float*)d_in[21];
  const float* efw = (const float*)d_in[22];
  const float* efb = (const float*)d_in[23];
  const float* cw1 = (const float*)d_in[24];
  const float* cb1 = (const float*)d_in[25];
  const float* cw2 = (const float*)d_in[26];
  const float* cb2 = (const float*)d_in[27];

  float*  out  = (float*)d_out;
  char*   ws   = (char*)d_ws;
  float*  tfp  = (float*)(ws + WS_TFP);
  int*    tk   = (int*)(ws + WS_TK);
  ushort* ew2b = (ushort*)(ws + WS_EW2B);
  ushort* ew3b = (ushort*)(ws + WS_EW3B);

  trunk_kernel<<<2048, 256, 0, stream>>>(x, tw1, tg1, tb1, tw2, tg2, tb2, tfp);
  gate_kernel<<<256, 64, 0, stream>>>(tfp, tfw, tfb, gw1, gb1, gw2, gb2,
                                      ew2, ew3, ew2b, ew3b, out + 2560, tk);
  expALL_kernel<<<256, 256, 0, stream>>>(x, tk, ew1, eg1, eb1, ew2b, eg2, eb2,
                                         ew3b, eg3, eb3, efw, efb, cw1, cb1,
                                         cw2, cb2, out, out + 4608);
}

// Round 10
// 325.590 us; speedup vs baseline: 1.3571x; 1.0008x over previous
//
#include <hip/hip_runtime.h>
#include <hip/hip_bf16.h>
#include <math.h>

// ---------------------------------------------------------------------------
// DistributedMoE forward, MI355X — R10: expALL occupancy fix (256->512 thr,
// 1->2 waves/SIMD, per-wave serial work halved) + prep restored (trunk's
// stride-288 weight gather was a 24us regression; linear tw2t staging is the
// measured-109us path; gate tail removed).
// Expert math identical to R9 except FC1/FC2 4-way dot split (fp32 reorder,
// post-routing, ~1e-6). Routing path fp32-identical.
//
// out (fp32): final[256,10] @0, balanced[256,8] @2560, D[256,8] @4608
// ---------------------------------------------------------------------------

#define BN_RS (1.0f / sqrtf(1.00001f))

typedef __attribute__((ext_vector_type(8))) short short8;
typedef __attribute__((ext_vector_type(4))) float floatx4;

static __device__ __forceinline__ ushort f2bf(float f) {
  unsigned u = __float_as_uint(f);
  unsigned r = (u + 0x7fffu + ((u >> 16) & 1u)) >> 16;   // RNE
  return (ushort)r;
}

// ws byte offsets
#define WS_TFP    0           // f32[256][8][32]
#define WS_TK     262144      // i32[512]
#define WS_TW2T   265216      // f32[32ic][9][32oc]           (36864 B)
#define WS_EW2B   302080      // bf16[8][9tap][64oc][32ic]    (294912 B)
#define WS_EW3B   596992      // bf16[8][9tap][128oc][64ic]   (1179648 B)

// =================== prep: weight transposes (R8-proven) ===================
__global__ __launch_bounds__(256) void prep_kernel(
    const float* __restrict__ tw2, const float* __restrict__ ew2,
    const float* __restrict__ ew3, float* __restrict__ tw2t,
    ushort* __restrict__ ew2b, ushort* __restrict__ ew3b)
{
  const int j = blockIdx.x * 256 + threadIdx.x;
  if (j < 9216) {
    int ic = j / 288, rem = j % 288, k = rem / 32, oc = rem % 32;
    tw2t[j] = tw2[oc*288 + ic*9 + k];
  } else if (j < 156672) {
    int jj = j - 9216;                       // [e][tap][oc64][ic32]
    int e = jj / 18432, r2 = jj % 18432;
    int tap = r2 / 2048, r3 = r2 % 2048;
    int oc = r3 / 32, ic = r3 % 32;
    ew2b[jj] = f2bf(ew2[e*18432 + oc*288 + ic*9 + tap]);
  } else if (j < 746496) {
    int jj = j - 156672;                     // [e][tap][oc128][ic64]
    int e = jj / 73728, r2 = jj % 73728;
    int tap = r2 / 8192, r3 = r2 % 8192;
    int oc = r3 / 64, ic = r3 % 64;
    ew3b[jj] = f2bf(ew3[e*73728 + oc*576 + ic*9 + tap]);
  }
}

// ====== fused trunk: conv1 (in-LDS) + conv2 + pool + partial sums ==========
// R6 structure (109us measured), linear tw2t staging.
#define TF_SA1 0
#define TF_WD  6464
#define TF_X   6464
#define TF_W1  7184
#define TF_BN  8832
__global__ __launch_bounds__(256, 4) void trunk_kernel(
    const float* __restrict__ x, const float* __restrict__ tw1,
    const float* __restrict__ tg1, const float* __restrict__ tb1,
    const float* __restrict__ tw2t, const float* __restrict__ tg2,
    const float* __restrict__ tb2, float* __restrict__ tfp)
{
  __shared__ __align__(16) float sm[8960];
  const int t = threadIdx.x;
  const int b = blockIdx.x >> 3, blk = blockIdx.x & 7;
  const int rs = blk >> 1, ch = blk & 1;
  const int r0 = rs*8, c0 = ch*16;

  for (int j = t; j < 720; j += 256) {
    int ic = j / 240, rem = j % 240, rr = rem / 20, cx = rem % 20;
    int gy = r0 - 2 + rr, gx = c0 - 2 + cx;
    float v = 0.f;
    if (gy >= 0 && gy < 32 && gx >= 0 && gx < 32) v = x[b*3072 + ic*1024 + gy*32 + gx];
    sm[TF_X + j] = v;
  }
  for (int j = t; j < 864; j += 256) sm[TF_W1 + j] = tw1[j];
  if (t < 32) {
    sm[TF_BN + t] = tg1[t]*BN_RS;      sm[TF_BN + 32 + t] = tb1[t];
    sm[TF_BN + 64 + t] = tg2[t]*BN_RS; sm[TF_BN + 96 + t] = tb2[t];
  }
  __syncthreads();

  // conv1 (summation order identical to R6..R9)
  {
    float acc1[18];
    for (int it = 0; it < 2; ++it) {
      const int item = it*256 + t;
      if (item < 320) {
        const int oc = item & 31, rr = item >> 5;
        const int gy = r0 - 1 + rr;
        #pragma unroll
        for (int c2 = 0; c2 < 18; ++c2) acc1[c2] = 0.f;
        if (gy >= 0 && gy < 32) {
          for (int ic = 0; ic < 3; ++ic) {
            float w[9];
            #pragma unroll
            for (int k = 0; k < 9; ++k) w[k] = sm[TF_W1 + oc*27 + ic*9 + k];
            #pragma unroll
            for (int wr = 0; wr < 3; ++wr) {
              float rv[20];
              const float4* rp = (const float4*)&sm[TF_X + ic*240 + (rr + wr)*20];
              #pragma unroll
              for (int j4 = 0; j4 < 5; ++j4) {
                float4 v4 = rp[j4];
                rv[4*j4] = v4.x; rv[4*j4+1] = v4.y; rv[4*j4+2] = v4.z; rv[4*j4+3] = v4.w;
              }
              #pragma unroll
              for (int c2 = 0; c2 < 18; ++c2)
                #pragma unroll
                for (int kx = 0; kx < 3; ++kx)
                  acc1[c2] = fmaf(w[wr*3 + kx], rv[c2 + kx], acc1[c2]);
            }
          }
        }
        const float s = sm[TF_BN + oc], bo = sm[TF_BN + 32 + oc];
        #pragma unroll
        for (int c2 = 0; c2 < 18; ++c2) {
          const int gx = c0 - 1 + c2;
          float v = 0.f;
          if (gy >= 0 && gy < 32 && gx >= 0 && gx < 32)
            v = fmaxf(fmaf(acc1[c2], s, bo), 0.f);
          sm[TF_SA1 + oc*202 + rr*20 + c2] = v;
        }
      }
    }
  }
  __syncthreads();

  for (int j = t; j < 1152; j += 256) {
    int qq = j / 288, r = j % 288;
    sm[TF_WD + qq*296 + r] = tw2t[(qq*8)*288 + r];
  }
  __syncthreads();

  const int g = t >> 5, q = (t >> 3) & 3, cp = t & 7;
  float acc[4][8][2];
  #pragma unroll
  for (int o = 0; o < 4; ++o)
    #pragma unroll
    for (int r = 0; r < 8; ++r) { acc[o][r][0] = 0.f; acc[o][r][1] = 0.f; }

  for (int cc = 0; cc < 8; ++cc) {
    if (cc < 7) {
      for (int j = t; j < 1152; j += 256) {
        int qq = j / 288, r = j % 288;
        sm[TF_WD + ((cc+1)&1)*1184 + qq*296 + r] = tw2t[(qq*8 + cc+1)*288 + r];
      }
    }
    const float* wb = &sm[TF_WD + (cc&1)*1184 + q*296];
    float w[4][9];
    #pragma unroll
    for (int k = 0; k < 9; ++k) {
      float4 wv = *(const float4*)&wb[k*32 + 4*g];
      w[0][k] = wv.x; w[1][k] = wv.y; w[2][k] = wv.z; w[3][k] = wv.w;
    }
    const float* src = &sm[TF_SA1 + (q*8+cc)*202 + 2*cp];
    #pragma unroll
    for (int rr = 0; rr < 10; ++rr) {
      float2 va = *(const float2*)&src[rr*20];
      float2 vb = *(const float2*)&src[rr*20 + 2];
      const float i0 = va.x, i1 = va.y, i2 = vb.x, i3 = vb.y;
      #pragma unroll
      for (int dr = 0; dr < 3; ++dr) {
        const int r = rr - dr;
        if (r < 0 || r > 7) continue;
        #pragma unroll
        for (int o = 0; o < 4; ++o) {
          acc[o][r][0] = fmaf(w[o][dr*3+0], i0, acc[o][r][0]);
          acc[o][r][1] = fmaf(w[o][dr*3+0], i1, acc[o][r][1]);
          acc[o][r][0] = fmaf(w[o][dr*3+1], i1, acc[o][r][0]);
          acc[o][r][1] = fmaf(w[o][dr*3+1], i2, acc[o][r][1]);
          acc[o][r][0] = fmaf(w[o][dr*3+2], i2, acc[o][r][0]);
          acc[o][r][1] = fmaf(w[o][dr*3+2], i3, acc[o][r][1]);
        }
      }
    }
    __syncthreads();
  }

  const int slot = g*8 + cp;
  if (q >= 2) {
    float* dst = &sm[(q-2)*4168 + slot*65];
    #pragma unroll
    for (int o = 0; o < 4; ++o)
      #pragma unroll
      for (int r = 0; r < 8; ++r) {
        dst[o*16 + r*2 + 0] = acc[o][r][0];
        dst[o*16 + r*2 + 1] = acc[o][r][1];
      }
  }
  __syncthreads();
  if (q < 2) {
    const float* s0 = &sm[q*4168 + slot*65];
    #pragma unroll
    for (int o = 0; o < 4; ++o)
      #pragma unroll
      for (int r = 0; r < 8; ++r) {
        acc[o][r][0] += s0[o*16 + r*2 + 0];
        acc[o][r][1] += s0[o*16 + r*2 + 1];
      }
  }
  __syncthreads();
  if (q == 1) {
    float* dst = &sm[slot*65];
    #pragma unroll
    for (int o = 0; o < 4; ++o)
      #pragma unroll
      for (int r = 0; r < 8; ++r) {
        dst[o*16 + r*2 + 0] = acc[o][r][0];
        dst[o*16 + r*2 + 1] = acc[o][r][1];
      }
  }
  __syncthreads();
  if (q == 0) {
    const float* s0 = &sm[slot*65];
    #pragma unroll
    for (int o = 0; o < 4; ++o) {
      const int oc = 4*g + o;
      const float s = sm[TF_BN + 64 + oc], bo = sm[TF_BN + 96 + oc];
      float ps = 0.f;
      #pragma unroll
      for (int pr = 0; pr < 4; ++pr) {
        float c00 = acc[o][2*pr][0]   + s0[o*16 + (2*pr)*2 + 0];
        float c01 = acc[o][2*pr][1]   + s0[o*16 + (2*pr)*2 + 1];
        float c10 = acc[o][2*pr+1][0] + s0[o*16 + (2*pr+1)*2 + 0];
        float c11 = acc[o][2*pr+1][1] + s0[o*16 + (2*pr+1)*2 + 1];
        float v0 = fmaxf(fmaf(c00, s, bo), 0.f);
        float v1 = fmaxf(fmaf(c01, s, bo), 0.f);
        float v2 = fmaxf(fmaf(c10, s, bo), 0.f);
        float v3 = fmaxf(fmaf(c11, s, bo), 0.f);
        ps += fmaxf(fmaxf(v0, v1), fmaxf(v2, v3));
      }
      ps += __shfl_xor(ps, 1);
      ps += __shfl_xor(ps, 2);
      ps += __shfl_xor(ps, 4);
      if ((t & 31) == 0) tfp[b*256 + (rs*2 + ch)*32 + oc] = ps;
    }
  }
}

// ============================== gate + top2 ================================
__global__ __launch_bounds__(64) void gate_kernel(
    const float* __restrict__ tfp, const float* __restrict__ tfw, const float* __restrict__ tfb,
    const float* __restrict__ gw1, const float* __restrict__ gb1,
    const float* __restrict__ gw2, const float* __restrict__ gb2,
    float* __restrict__ outBal, int* __restrict__ tk)
{
  __shared__ float feat[128], rf[64], g1[32], bal[8];
  const int b = blockIdx.x, t = threadIdx.x;
  #pragma unroll
  for (int h = 0; h < 2; ++h) {
    const int f = t + 64*h;
    const int oc = f >> 2, qy = (f >> 1) & 1, qx = f & 1;
    feat[f] = (tfp[b*256 + (4*qy + qx)*32 + oc] +
               tfp[b*256 + (4*qy + 2 + qx)*32 + oc]) * (1.f/64.f);
  }
  __syncthreads();
  {
    float a = tfb[t];
    const float4* wp = (const float4*)&tfw[t*128];
    #pragma unroll 8
    for (int i4 = 0; i4 < 32; ++i4) {
      float4 wv = wp[i4];
      a = fmaf(wv.x, feat[4*i4], a);   a = fmaf(wv.y, feat[4*i4+1], a);
      a = fmaf(wv.z, feat[4*i4+2], a); a = fmaf(wv.w, feat[4*i4+3], a);
    }
    rf[t] = fmaxf(a, 0.f);
  }
  __syncthreads();
  if (t < 32) {
    float a = gb1[t];
    const float4* wp = (const float4*)&gw1[t*64];
    #pragma unroll
    for (int i4 = 0; i4 < 16; ++i4) {
      float4 wv = wp[i4];
      a = fmaf(wv.x, rf[4*i4], a);   a = fmaf(wv.y, rf[4*i4+1], a);
      a = fmaf(wv.z, rf[4*i4+2], a); a = fmaf(wv.w, rf[4*i4+3], a);
    }
    g1[t] = fmaxf(a, 0.f);
  }
  __syncthreads();
  if (t < 8) {
    float a = gb2[t];
    const float4* wp = (const float4*)&gw2[t*32];
    #pragma unroll
    for (int i4 = 0; i4 < 8; ++i4) {
      float4 wv = wp[i4];
      a = fmaf(wv.x, g1[4*i4], a);   a = fmaf(wv.y, g1[4*i4+1], a);
      a = fmaf(wv.z, g1[4*i4+2], a); a = fmaf(wv.w, g1[4*i4+3], a);
    }
    const float v = a - 0.25f;   // boost=0, -LOAD_PEN*usage = -0.25
    bal[t] = v;
    outBal[b*8 + t] = v;
  }
  __syncthreads();
  if (t == 0) {
    int t0 = 0; float b0 = bal[0];
    #pragma unroll
    for (int e2 = 1; e2 < 8; ++e2) if (bal[e2] > b0) { b0 = bal[e2]; t0 = e2; }
    int t1 = -1; float b1 = -3.4e38f;
    #pragma unroll
    for (int e2 = 0; e2 < 8; ++e2) if (e2 != t0 && bal[e2] > b1) { b1 = bal[e2]; t1 = e2; }
    tk[b*2] = t0; tk[b*2 + 1] = t1;
  }
}

// ========== expALL: scan + conv1 + conv2(MFMA) + conv3(MFMA) + FC ==========
// grid 256 = one block/sample, 512 thr (8 waves = 2/SIMD). LDS as R9:
//   IMG @0 (324x40); P2T @0 overlays; feat/sff/sgg f32 @3600..3920
//   W2 @12960 (dbuf 2x2560); xf32/w1/bn1 f32 @9040..13436 (us 18080..)
//   WT @18080 overlays xf32 after conv1; FC scratch f32 @9040 after conv3
#define XA_IMG  0
#define XA_W2   12960
#define XA_WT   18080
#define XA_FEAT 3600
#define XA_SFF  3728
#define XA_SGG  3856
#define XA_XF   9040
#define XA_W1F  12508
#define XA_BN1F 13372
#define XA_SC   9040      // FC partial-sum scratch (512 f32), after conv3
__global__ __launch_bounds__(512) void expALL_kernel(
    const float* __restrict__ x, const int* __restrict__ tk,
    const float* __restrict__ ew1, const float* __restrict__ eg1,
    const float* __restrict__ eb1, const ushort* __restrict__ ew2b,
    const float* __restrict__ eg2, const float* __restrict__ eb2,
    const ushort* __restrict__ ew3b, const float* __restrict__ eg3,
    const float* __restrict__ eb3, const float* __restrict__ efw,
    const float* __restrict__ efb, const float* __restrict__ cw1,
    const float* __restrict__ cb1, const float* __restrict__ cw2,
    const float* __restrict__ cb2, float* __restrict__ outF,
    float* __restrict__ outD)
{
  __shared__ __align__(16) ushort smu[27296];
  __shared__ int stk[512];
  __shared__ int sch;
  float* smf = (float*)smu;
  const int t = threadIdx.x, b = blockIdx.x;

  // ---- 1) capacity scan replay ----
  stk[t] = tk[t];
  __syncthreads();
  if (t == 0) {
    float L0=0,L1=0,L2=0,L3=0,L4=0,L5=0,L6=0,L7=0;
    int chv = 0;
    for (int i = 0; i <= b; ++i) {
      const int a = stk[2*i], c = stk[2*i+1];
      const float la = (a==0)?L0:(a==1)?L1:(a==2)?L2:(a==3)?L3:(a==4)?L4:(a==5)?L5:(a==6)?L6:L7;
      const float lc = (c==0)?L0:(c==1)?L1:(c==2)?L2:(c==3)?L3:(c==4)?L4:(c==5)?L5:(c==6)?L6:L7;
      chv = (la < 48.f) ? a : ((lc < 48.f) ? c : ((la <= lc) ? a : c));
      L0 += (chv==0)?1.f:0.f; L1 += (chv==1)?1.f:0.f; L2 += (chv==2)?1.f:0.f; L3 += (chv==3)?1.f:0.f;
      L4 += (chv==4)?1.f:0.f; L5 += (chv==5)?1.f:0.f; L6 += (chv==6)?1.f:0.f; L7 += (chv==7)?1.f:0.f;
    }
    sch = chv;
  }
  __syncthreads();
  const int e = sch;
  if (t < 8) outD[b*8 + t] = (t == e) ? 1.f : 0.f;

  // ---- 2) zero IMG; stage x [3][34][34], w1t, bn1 ----
  {
    uint4 z; z.x = 0; z.y = 0; z.z = 0; z.w = 0;
    for (int j = t; j < 1620; j += 512) ((uint4*)smu)[j] = z;
  }
  for (int j = t; j < 3468; j += 512) {
    int ic = j / 1156, rem = j % 1156, p = rem / 34, cpd = rem % 34;
    int gy = p - 1, gx = cpd - 1;
    float v = 0.f;
    if (gy >= 0 && gy < 32 && gx >= 0 && gx < 32) v = x[b*3072 + ic*1024 + gy*32 + gx];
    smf[XA_XF + j] = v;
  }
  for (int j = t; j < 864; j += 512) {
    int oc = j / 27, r = j % 27, ic = r / 9, k = r % 9;
    smf[XA_W1F + ic*288 + k*32 + oc] = ew1[e*864 + j];
  }
  if (t < 32) { smf[XA_BN1F + t] = eg1[e*32 + t]*BN_RS; smf[XA_BN1F + 32 + t] = eb1[e*32 + t]; }
  __syncthreads();

  // ---- 3) conv1 fp32 (expA math; 2 slabs per thread-group) -> bf16 IMG ----
  {
    const int hi = t >> 8, g = (t >> 5) & 7, c = t & 31;
    for (int rsl = 0; rsl < 2; ++rsl) {
      const int rs = 2*hi + rsl;
      const int r0 = rs * 8;
      float acc[4][8];
      #pragma unroll
      for (int o = 0; o < 4; ++o)
        #pragma unroll
        for (int r = 0; r < 8; ++r) acc[o][r] = 0.f;
      for (int ic = 0; ic < 3; ++ic) {
        float w[4][9];
        #pragma unroll
        for (int k = 0; k < 9; ++k) {
          float4 wv = *(const float4*)&smf[XA_W1F + ic*288 + k*32 + 4*g];
          w[0][k] = wv.x; w[1][k] = wv.y; w[2][k] = wv.z; w[3][k] = wv.w;
        }
        const float* src = &smf[XA_XF + ic*1156 + r0*34 + c];
        #pragma unroll
        for (int rr = 0; rr < 10; ++rr) {
          const float i0 = src[rr*34], i1 = src[rr*34 + 1], i2 = src[rr*34 + 2];
          #pragma unroll
          for (int dr = 0; dr < 3; ++dr) {
            const int r = rr - dr;
            if (r < 0 || r > 7) continue;
            #pragma unroll
            for (int o = 0; o < 4; ++o) {
              acc[o][r] = fmaf(w[o][dr*3+0], i0, acc[o][r]);
              acc[o][r] = fmaf(w[o][dr*3+1], i1, acc[o][r]);
              acc[o][r] = fmaf(w[o][dr*3+2], i2, acc[o][r]);
            }
          }
        }
      }
      #pragma unroll
      for (int o = 0; o < 4; ++o) {
        const int oc = 4*g + o;
        const float s = smf[XA_BN1F + oc], bo = smf[XA_BN1F + 32 + oc];
        float m[4];
        #pragma unroll
        for (int pr = 0; pr < 4; ++pr) {
          float v0 = fmaxf(fmaf(acc[o][2*pr],   s, bo), 0.f);
          float v1 = fmaxf(fmaf(acc[o][2*pr+1], s, bo), 0.f);
          m[pr] = fmaxf(v0, v1);
        }
        #pragma unroll
        for (int pr = 0; pr < 4; ++pr) {
          float nb = __shfl_xor(m[pr], 1);
          m[pr] = fmaxf(m[pr], nb);
        }
        if (!(c & 1)) {
          const int pc = c >> 1;
          #pragma unroll
          for (int pr = 0; pr < 4; ++pr)
            smu[XA_IMG + ((rs*4 + pr + 1)*18 + (pc + 1))*40 + oc] = f2bf(m[pr]);
        }
      }
    }
  }
  if (t < 256) {  // stage W2 tap 0
    int oc = t >> 2, ofs = (t & 3) * 8;
    *(uint4*)&smu[XA_W2 + oc*40 + ofs] = *(const uint4*)&ew2b[(e*9 + 0)*2048 + t*8];
  }
  __syncthreads();

  // ---- 4) conv2 MFMA: wave = (mhalf = w>>2, ntile = w&3), 8 m-tiles each ----
  const int w8 = t >> 6, l = t & 63;
  const int col = l & 15, quad = l >> 4;
  {
    const int ntile = w8 & 3, mhalf = w8 >> 2;
    floatx4 acc[8];
    #pragma unroll
    for (int mt = 0; mt < 8; ++mt)
      #pragma unroll
      for (int i = 0; i < 4; ++i) acc[mt][i] = 0.f;

    for (int tap = 0; tap < 9; ++tap) {
      if (tap < 8 && t < 256) {
        int oc = t >> 2, ofs = (t & 3) * 8;
        *(uint4*)&smu[XA_W2 + ((tap+1)&1)*2560 + oc*40 + ofs] =
            *(const uint4*)&ew2b[(e*9 + tap + 1)*2048 + t*8];
      }
      const ushort* wb = &smu[XA_W2 + (tap&1)*2560];
      short8 bfr = *(const short8*)&wb[(ntile*16 + col)*40 + quad*8];
      const int dy = tap / 3, dx = tap % 3;
      #pragma unroll
      for (int mtl = 0; mtl < 8; ++mtl) {
        const int mt = mhalf*8 + mtl;
        short8 afr = *(const short8*)
            &smu[XA_IMG + ((mt + dy)*18 + col + dx)*40 + quad*8];
        acc[mtl] = __builtin_amdgcn_mfma_f32_16x16x32_bf16(afr, bfr, acc[mtl], 0, 0, 0);
      }
      __syncthreads();
    }

    // P2T borders + pooled interior (overlays dead IMG)
    {
      uint4 z; z.x = 0; z.y = 0; z.z = 0; z.w = 0;
      for (int j = t; j < 288; j += 512) {
        int slot = j >> 3, ofs = (j & 7) * 8, row, cl;
        if (slot < 10)      { row = 0; cl = slot; }
        else if (slot < 20) { row = 9; cl = slot - 10; }
        else if (slot < 28) { row = 1 + (slot - 20); cl = 0; }
        else                { row = 1 + (slot - 28); cl = 9; }
        *(uint4*)&smu[(row*10 + cl)*72 + ofs] = z;
      }
    }
    const int oc2 = ntile*16 + col;
    const float s2 = eg2[e*64 + oc2]*BN_RS, bo2 = eb2[e*64 + oc2];
    #pragma unroll
    for (int mtpl = 0; mtpl < 4; ++mtpl) {
      const int mtp = mhalf*4 + mtpl;
      float a00 = fmaxf(fmaf(acc[2*mtpl][0],   s2, bo2), 0.f);
      float a01 = fmaxf(fmaf(acc[2*mtpl][1],   s2, bo2), 0.f);
      float a02 = fmaxf(fmaf(acc[2*mtpl][2],   s2, bo2), 0.f);
      float a03 = fmaxf(fmaf(acc[2*mtpl][3],   s2, bo2), 0.f);
      float a10 = fmaxf(fmaf(acc[2*mtpl+1][0], s2, bo2), 0.f);
      float a11 = fmaxf(fmaf(acc[2*mtpl+1][1], s2, bo2), 0.f);
      float a12 = fmaxf(fmaf(acc[2*mtpl+1][2], s2, bo2), 0.f);
      float a13 = fmaxf(fmaf(acc[2*mtpl+1][3], s2, bo2), 0.f);
      float p0 = fmaxf(fmaxf(a00, a01), fmaxf(a10, a11));
      float p1 = fmaxf(fmaxf(a02, a03), fmaxf(a12, a13));
      smu[((mtp + 1)*10 + (quad*2 + 1))*72 + oc2] = f2bf(p0);
      smu[((mtp + 1)*10 + (quad*2 + 2))*72 + oc2] = f2bf(p1);
    }
  }
  __syncthreads();

  // ---- 6) conv3 MFMA: wave w8 owns oc-tile w8 (oc = w8*16 + col) ----
  {
    const int oc3 = w8*16 + col;
    floatx4 acc[4];
    #pragma unroll
    for (int mt = 0; mt < 4; ++mt)
      #pragma unroll
      for (int i = 0; i < 4; ++i) acc[mt][i] = 0.f;

    for (int tap = 0; tap < 9; ++tap) {
      __syncthreads();
      for (int j = t; j < 1024; j += 512) {
        int oc = j >> 3, ico = (j & 7) * 8;
        *(uint4*)&smu[XA_WT + oc*72 + ico] =
            *(const uint4*)&ew3b[(e*9 + tap)*8192 + j*8];
      }
      __syncthreads();
      const int dy = tap / 3, dx = tap % 3;
      #pragma unroll
      for (int ks = 0; ks < 2; ++ks) {
        short8 bfr = *(const short8*)&smu[XA_WT + oc3*72 + ks*32 + quad*8];
        #pragma unroll
        for (int mt = 0; mt < 4; ++mt) {
          const int m = mt*16 + col;
          const int y = m >> 3, xx = m & 7;
          short8 afr = *(const short8*)
              &smu[((y + dy)*10 + (xx + dx))*72 + ks*32 + quad*8];
          acc[mt] = __builtin_amdgcn_mfma_f32_16x16x32_bf16(afr, bfr, acc[mt], 0, 0, 0);
        }
      }
    }

    // epilogue: bn + relu + GAP -> feat in LDS
    {
      const float s = eg3[e*128 + oc3]*BN_RS, bo = eb3[e*128 + oc3];
      float gsum = 0.f;
      #pragma unroll
      for (int mt = 0; mt < 4; ++mt)
        #pragma unroll
        for (int i = 0; i < 4; ++i)
          gsum += fmaxf(fmaf(acc[mt][i], s, bo), 0.f);
      gsum += __shfl_xor(gsum, 16);
      gsum += __shfl_xor(gsum, 32);
      if (quad == 0) smf[XA_FEAT + oc3] = gsum * (1.f/64.f);
    }
  }
  __syncthreads();

  // ---- 7) FC chain, 4-way dot split via LDS scratch (XA_WT region dead) ----
  {
    const int out = t & 127, part = t >> 7;     // part 0..3
    float a = (part == 0) ? efb[e*128 + out] : 0.f;
    const float4* wp = (const float4*)&efw[e*16384 + out*128 + part*32];
    #pragma unroll
    for (int i4 = 0; i4 < 8; ++i4) {
      float4 wv = wp[i4];
      const int base = XA_FEAT + part*32 + 4*i4;
      a = fmaf(wv.x, smf[base], a);     a = fmaf(wv.y, smf[base + 1], a);
      a = fmaf(wv.z, smf[base + 2], a); a = fmaf(wv.w, smf[base + 3], a);
    }
    smf[XA_SC + part*128 + out] = a;
  }
  __syncthreads();
  if (t < 128)
    smf[XA_SFF + t] = fmaxf(smf[XA_SC + t] + smf[XA_SC + 128 + t] +
                            smf[XA_SC + 256 + t] + smf[XA_SC + 384 + t], 0.f);
  __syncthreads();
  if (t < 256) {
    const int out = t & 63, part = t >> 6;      // part 0..3
    float a = (part == 0) ? cb1[e*64 + out] : 0.f;
    const float4* wp = (const float4*)&cw1[e*8192 + out*128 + part*32];
    #pragma unroll
    for (int i4 = 0; i4 < 8; ++i4) {
      float4 wv = wp[i4];
      const int base = XA_SFF + part*32 + 4*i4;
      a = fmaf(wv.x, smf[base], a);     a = fmaf(wv.y, smf[base + 1], a);
      a = fmaf(wv.z, smf[base + 2], a); a = fmaf(wv.w, smf[base + 3], a);
    }
    smf[XA_SC + part*64 + out] = a;
  }
  __syncthreads();
  if (t < 64)
    smf[XA_SGG + t] = fmaxf(smf[XA_SC + t] + smf[XA_SC + 64 + t] +
                            smf[XA_SC + 128 + t] + smf[XA_SC + 192 + t], 0.f);
  __syncthreads();
  if (t < 10) {
    float a = cb2[e*10 + t];
    const float4* wp = (const float4*)&cw2[e*640 + t*64];
    #pragma unroll
    for (int i4 = 0; i4 < 16; ++i4) {
      float4 wv = wp[i4];
      a = fmaf(wv.x, smf[XA_SGG + 4*i4],     a);
      a = fmaf(wv.y, smf[XA_SGG + 4*i4 + 1], a);
      a = fmaf(wv.z, smf[XA_SGG + 4*i4 + 2], a);
      a = fmaf(wv.w, smf[XA_SGG + 4*i4 + 3], a);
    }
    outF[b*10 + t] = a;   // routing weight is exactly 1.0 for the chosen expert
  }
}

// ================================ host =====================================
extern "C" void kernel_launch(void* const* d_in, const int* in_sizes, int n_in,
                              void* d_out, int out_size, void* d_ws, size_t ws_size,
                              hipStream_t stream)
{
  const float* x   = (const float*)d_in[0];
  const float* tw1 = (const float*)d_in[1];
  const float* tg1 = (const float*)d_in[2];
  const float* tb1 = (const float*)d_in[3];
  const float* tw2 = (const float*)d_in[4];
  const float* tg2 = (const float*)d_in[5];
  const float* tb2 = (const float*)d_in[6];
  const float* tfw = (const float*)d_in[7];
  const float* tfb = (const float*)d_in[8];
  const float* gw1 = (const float*)d_in[9];
  const float* gb1 = (const float*)d_in[10];
  const float* gw2 = (const float*)d_in[11];
  const float* gb2 = (const float*)d_in[12];
  const float* ew1 = (const float*)d_in[13];
  const float* eg1 = (const float*)d_in[14];
  const float* eb1 = (const float*)d_in[15];
  const float* ew2 = (const float*)d_in[16];
  const float* eg2 = (const float*)d_in[17];
  const float* eb2 = (const float*)d_in[18];
  const float* ew3 = (const float*)d_in[19];
  const float* eg3 = (const float*)d_in[20];
  const float* eb3 = (const float*)d_in[21];
  const float* efw = (const float*)d_in[22];
  const float* efb = (const float*)d_in[23];
  const float* cw1 = (const float*)d_in[24];
  const float* cb1 = (const float*)d_in[25];
  const float* cw2 = (const float*)d_in[26];
  const float* cb2 = (const float*)d_in[27];

  float*  out  = (float*)d_out;
  char*   ws   = (char*)d_ws;
  float*  tfp  = (float*)(ws + WS_TFP);
  int*    tk   = (int*)(ws + WS_TK);
  float*  tw2t = (float*)(ws + WS_TW2T);
  ushort* ew2b = (ushort*)(ws + WS_EW2B);
  ushort* ew3b = (ushort*)(ws + WS_EW3B);

  prep_kernel<<<2916, 256, 0, stream>>>(tw2, ew2, ew3, tw2t, ew2b, ew3b);
  trunk_kernel<<<2048, 256, 0, stream>>>(x, tw1, tg1, tb1, tw2t, tg2, tb2, tfp);
  gate_kernel<<<256, 64, 0, stream>>>(tfp, tfw, tfb, gw1, gb1, gw2, gb2,
                                      out + 2560, tk);
  expALL_kernel<<<256, 512, 0, stream>>>(x, tk, ew1, eg1, eb1, ew2b, eg2, eb2,
                                         ew3b, eg3, eb3, efw, efb, cw1, cb1,
                                         cw2, cb2, out, out + 4608);
}

// Round 11
// 302.977 us; speedup vs baseline: 1.4584x; 1.0746x over previous
//
#include <hip/hip_runtime.h>
#include <hip/hip_bf16.h>
#include <math.h>

// ---------------------------------------------------------------------------
// DistributedMoE forward, MI355X — R11: expALL spill fix. R10 counters showed
// WRITE_SIZE 34MB / FETCH 19MB on expALL (legit output 18KB) with VGPR=128
// and VALUBusy 7.7% -> compiler clamped to 128 VGPR and spilled to scratch;
// kernel was scratch-latency bound. Fix: __launch_bounds__(512,2) (VGPR cap
// 256) + conv1 restructured to 2-oc groups (peak pressure halved). Summation
// order per output unchanged -> absmax stays 0.0078125.
//
// out (fp32): final[256,10] @0, balanced[256,8] @2560, D[256,8] @4608
// ---------------------------------------------------------------------------

#define BN_RS (1.0f / sqrtf(1.00001f))

typedef __attribute__((ext_vector_type(8))) short short8;
typedef __attribute__((ext_vector_type(4))) float floatx4;

static __device__ __forceinline__ ushort f2bf(float f) {
  unsigned u = __float_as_uint(f);
  unsigned r = (u + 0x7fffu + ((u >> 16) & 1u)) >> 16;   // RNE
  return (ushort)r;
}

// ws byte offsets
#define WS_TFP    0           // f32[256][8][32]
#define WS_TK     262144      // i32[512]
#define WS_TW2T   265216      // f32[32ic][9][32oc]           (36864 B)
#define WS_EW2B   302080      // bf16[8][9tap][64oc][32ic]    (294912 B)
#define WS_EW3B   596992      // bf16[8][9tap][128oc][64ic]   (1179648 B)

// =================== prep: weight transposes (R8-proven) ===================
__global__ __launch_bounds__(256) void prep_kernel(
    const float* __restrict__ tw2, const float* __restrict__ ew2,
    const float* __restrict__ ew3, float* __restrict__ tw2t,
    ushort* __restrict__ ew2b, ushort* __restrict__ ew3b)
{
  const int j = blockIdx.x * 256 + threadIdx.x;
  if (j < 9216) {
    int ic = j / 288, rem = j % 288, k = rem / 32, oc = rem % 32;
    tw2t[j] = tw2[oc*288 + ic*9 + k];
  } else if (j < 156672) {
    int jj = j - 9216;                       // [e][tap][oc64][ic32]
    int e = jj / 18432, r2 = jj % 18432;
    int tap = r2 / 2048, r3 = r2 % 2048;
    int oc = r3 / 32, ic = r3 % 32;
    ew2b[jj] = f2bf(ew2[e*18432 + oc*288 + ic*9 + tap]);
  } else if (j < 746496) {
    int jj = j - 156672;                     // [e][tap][oc128][ic64]
    int e = jj / 73728, r2 = jj % 73728;
    int tap = r2 / 8192, r3 = r2 % 8192;
    int oc = r3 / 64, ic = r3 % 64;
    ew3b[jj] = f2bf(ew3[e*73728 + oc*576 + ic*9 + tap]);
  }
}

// ====== fused trunk: conv1 (in-LDS) + conv2 + pool + partial sums ==========
// R6 structure (109us measured), linear tw2t staging.
#define TF_SA1 0
#define TF_WD  6464
#define TF_X   6464
#define TF_W1  7184
#define TF_BN  8832
__global__ __launch_bounds__(256, 4) void trunk_kernel(
    const float* __restrict__ x, const float* __restrict__ tw1,
    const float* __restrict__ tg1, const float* __restrict__ tb1,
    const float* __restrict__ tw2t, const float* __restrict__ tg2,
    const float* __restrict__ tb2, float* __restrict__ tfp)
{
  __shared__ __align__(16) float sm[8960];
  const int t = threadIdx.x;
  const int b = blockIdx.x >> 3, blk = blockIdx.x & 7;
  const int rs = blk >> 1, ch = blk & 1;
  const int r0 = rs*8, c0 = ch*16;

  for (int j = t; j < 720; j += 256) {
    int ic = j / 240, rem = j % 240, rr = rem / 20, cx = rem % 20;
    int gy = r0 - 2 + rr, gx = c0 - 2 + cx;
    float v = 0.f;
    if (gy >= 0 && gy < 32 && gx >= 0 && gx < 32) v = x[b*3072 + ic*1024 + gy*32 + gx];
    sm[TF_X + j] = v;
  }
  for (int j = t; j < 864; j += 256) sm[TF_W1 + j] = tw1[j];
  if (t < 32) {
    sm[TF_BN + t] = tg1[t]*BN_RS;      sm[TF_BN + 32 + t] = tb1[t];
    sm[TF_BN + 64 + t] = tg2[t]*BN_RS; sm[TF_BN + 96 + t] = tb2[t];
  }
  __syncthreads();

  // conv1 (summation order identical to R6..R10)
  {
    float acc1[18];
    for (int it = 0; it < 2; ++it) {
      const int item = it*256 + t;
      if (item < 320) {
        const int oc = item & 31, rr = item >> 5;
        const int gy = r0 - 1 + rr;
        #pragma unroll
        for (int c2 = 0; c2 < 18; ++c2) acc1[c2] = 0.f;
        if (gy >= 0 && gy < 32) {
          for (int ic = 0; ic < 3; ++ic) {
            float w[9];
            #pragma unroll
            for (int k = 0; k < 9; ++k) w[k] = sm[TF_W1 + oc*27 + ic*9 + k];
            #pragma unroll
            for (int wr = 0; wr < 3; ++wr) {
              float rv[20];
              const float4* rp = (const float4*)&sm[TF_X + ic*240 + (rr + wr)*20];
              #pragma unroll
              for (int j4 = 0; j4 < 5; ++j4) {
                float4 v4 = rp[j4];
                rv[4*j4] = v4.x; rv[4*j4+1] = v4.y; rv[4*j4+2] = v4.z; rv[4*j4+3] = v4.w;
              }
              #pragma unroll
              for (int c2 = 0; c2 < 18; ++c2)
                #pragma unroll
                for (int kx = 0; kx < 3; ++kx)
                  acc1[c2] = fmaf(w[wr*3 + kx], rv[c2 + kx], acc1[c2]);
            }
          }
        }
        const float s = sm[TF_BN + oc], bo = sm[TF_BN + 32 + oc];
        #pragma unroll
        for (int c2 = 0; c2 < 18; ++c2) {
          const int gx = c0 - 1 + c2;
          float v = 0.f;
          if (gy >= 0 && gy < 32 && gx >= 0 && gx < 32)
            v = fmaxf(fmaf(acc1[c2], s, bo), 0.f);
          sm[TF_SA1 + oc*202 + rr*20 + c2] = v;
        }
      }
    }
  }
  __syncthreads();

  for (int j = t; j < 1152; j += 256) {
    int qq = j / 288, r = j % 288;
    sm[TF_WD + qq*296 + r] = tw2t[(qq*8)*288 + r];
  }
  __syncthreads();

  const int g = t >> 5, q = (t >> 3) & 3, cp = t & 7;
  float acc[4][8][2];
  #pragma unroll
  for (int o = 0; o < 4; ++o)
    #pragma unroll
    for (int r = 0; r < 8; ++r) { acc[o][r][0] = 0.f; acc[o][r][1] = 0.f; }

  for (int cc = 0; cc < 8; ++cc) {
    if (cc < 7) {
      for (int j = t; j < 1152; j += 256) {
        int qq = j / 288, r = j % 288;
        sm[TF_WD + ((cc+1)&1)*1184 + qq*296 + r] = tw2t[(qq*8 + cc+1)*288 + r];
      }
    }
    const float* wb = &sm[TF_WD + (cc&1)*1184 + q*296];
    float w[4][9];
    #pragma unroll
    for (int k = 0; k < 9; ++k) {
      float4 wv = *(const float4*)&wb[k*32 + 4*g];
      w[0][k] = wv.x; w[1][k] = wv.y; w[2][k] = wv.z; w[3][k] = wv.w;
    }
    const float* src = &sm[TF_SA1 + (q*8+cc)*202 + 2*cp];
    #pragma unroll
    for (int rr = 0; rr < 10; ++rr) {
      float2 va = *(const float2*)&src[rr*20];
      float2 vb = *(const float2*)&src[rr*20 + 2];
      const float i0 = va.x, i1 = va.y, i2 = vb.x, i3 = vb.y;
      #pragma unroll
      for (int dr = 0; dr < 3; ++dr) {
        const int r = rr - dr;
        if (r < 0 || r > 7) continue;
        #pragma unroll
        for (int o = 0; o < 4; ++o) {
          acc[o][r][0] = fmaf(w[o][dr*3+0], i0, acc[o][r][0]);
          acc[o][r][1] = fmaf(w[o][dr*3+0], i1, acc[o][r][1]);
          acc[o][r][0] = fmaf(w[o][dr*3+1], i1, acc[o][r][0]);
          acc[o][r][1] = fmaf(w[o][dr*3+1], i2, acc[o][r][1]);
          acc[o][r][0] = fmaf(w[o][dr*3+2], i2, acc[o][r][0]);
          acc[o][r][1] = fmaf(w[o][dr*3+2], i3, acc[o][r][1]);
        }
      }
    }
    __syncthreads();
  }

  const int slot = g*8 + cp;
  if (q >= 2) {
    float* dst = &sm[(q-2)*4168 + slot*65];
    #pragma unroll
    for (int o = 0; o < 4; ++o)
      #pragma unroll
      for (int r = 0; r < 8; ++r) {
        dst[o*16 + r*2 + 0] = acc[o][r][0];
        dst[o*16 + r*2 + 1] = acc[o][r][1];
      }
  }
  __syncthreads();
  if (q < 2) {
    const float* s0 = &sm[q*4168 + slot*65];
    #pragma unroll
    for (int o = 0; o < 4; ++o)
      #pragma unroll
      for (int r = 0; r < 8; ++r) {
        acc[o][r][0] += s0[o*16 + r*2 + 0];
        acc[o][r][1] += s0[o*16 + r*2 + 1];
      }
  }
  __syncthreads();
  if (q == 1) {
    float* dst = &sm[slot*65];
    #pragma unroll
    for (int o = 0; o < 4; ++o)
      #pragma unroll
      for (int r = 0; r < 8; ++r) {
        dst[o*16 + r*2 + 0] = acc[o][r][0];
        dst[o*16 + r*2 + 1] = acc[o][r][1];
      }
  }
  __syncthreads();
  if (q == 0) {
    const float* s0 = &sm[slot*65];
    #pragma unroll
    for (int o = 0; o < 4; ++o) {
      const int oc = 4*g + o;
      const float s = sm[TF_BN + 64 + oc], bo = sm[TF_BN + 96 + oc];
      float ps = 0.f;
      #pragma unroll
      for (int pr = 0; pr < 4; ++pr) {
        float c00 = acc[o][2*pr][0]   + s0[o*16 + (2*pr)*2 + 0];
        float c01 = acc[o][2*pr][1]   + s0[o*16 + (2*pr)*2 + 1];
        float c10 = acc[o][2*pr+1][0] + s0[o*16 + (2*pr+1)*2 + 0];
        float c11 = acc[o][2*pr+1][1] + s0[o*16 + (2*pr+1)*2 + 1];
        float v0 = fmaxf(fmaf(c00, s, bo), 0.f);
        float v1 = fmaxf(fmaf(c01, s, bo), 0.f);
        float v2 = fmaxf(fmaf(c10, s, bo), 0.f);
        float v3 = fmaxf(fmaf(c11, s, bo), 0.f);
        ps += fmaxf(fmaxf(v0, v1), fmaxf(v2, v3));
      }
      ps += __shfl_xor(ps, 1);
      ps += __shfl_xor(ps, 2);
      ps += __shfl_xor(ps, 4);
      if ((t & 31) == 0) tfp[b*256 + (rs*2 + ch)*32 + oc] = ps;
    }
  }
}

// ============================== gate + top2 ================================
__global__ __launch_bounds__(64) void gate_kernel(
    const float* __restrict__ tfp, const float* __restrict__ tfw, const float* __restrict__ tfb,
    const float* __restrict__ gw1, const float* __restrict__ gb1,
    const float* __restrict__ gw2, const float* __restrict__ gb2,
    float* __restrict__ outBal, int* __restrict__ tk)
{
  __shared__ float feat[128], rf[64], g1[32], bal[8];
  const int b = blockIdx.x, t = threadIdx.x;
  #pragma unroll
  for (int h = 0; h < 2; ++h) {
    const int f = t + 64*h;
    const int oc = f >> 2, qy = (f >> 1) & 1, qx = f & 1;
    feat[f] = (tfp[b*256 + (4*qy + qx)*32 + oc] +
               tfp[b*256 + (4*qy + 2 + qx)*32 + oc]) * (1.f/64.f);
  }
  __syncthreads();
  {
    float a = tfb[t];
    const float4* wp = (const float4*)&tfw[t*128];
    #pragma unroll 8
    for (int i4 = 0; i4 < 32; ++i4) {
      float4 wv = wp[i4];
      a = fmaf(wv.x, feat[4*i4], a);   a = fmaf(wv.y, feat[4*i4+1], a);
      a = fmaf(wv.z, feat[4*i4+2], a); a = fmaf(wv.w, feat[4*i4+3], a);
    }
    rf[t] = fmaxf(a, 0.f);
  }
  __syncthreads();
  if (t < 32) {
    float a = gb1[t];
    const float4* wp = (const float4*)&gw1[t*64];
    #pragma unroll
    for (int i4 = 0; i4 < 16; ++i4) {
      float4 wv = wp[i4];
      a = fmaf(wv.x, rf[4*i4], a);   a = fmaf(wv.y, rf[4*i4+1], a);
      a = fmaf(wv.z, rf[4*i4+2], a); a = fmaf(wv.w, rf[4*i4+3], a);
    }
    g1[t] = fmaxf(a, 0.f);
  }
  __syncthreads();
  if (t < 8) {
    float a = gb2[t];
    const float4* wp = (const float4*)&gw2[t*32];
    #pragma unroll
    for (int i4 = 0; i4 < 8; ++i4) {
      float4 wv = wp[i4];
      a = fmaf(wv.x, g1[4*i4], a);   a = fmaf(wv.y, g1[4*i4+1], a);
      a = fmaf(wv.z, g1[4*i4+2], a); a = fmaf(wv.w, g1[4*i4+3], a);
    }
    const float v = a - 0.25f;   // boost=0, -LOAD_PEN*usage = -0.25
    bal[t] = v;
    outBal[b*8 + t] = v;
  }
  __syncthreads();
  if (t == 0) {
    int t0 = 0; float b0 = bal[0];
    #pragma unroll
    for (int e2 = 1; e2 < 8; ++e2) if (bal[e2] > b0) { b0 = bal[e2]; t0 = e2; }
    int t1 = -1; float b1 = -3.4e38f;
    #pragma unroll
    for (int e2 = 0; e2 < 8; ++e2) if (e2 != t0 && bal[e2] > b1) { b1 = bal[e2]; t1 = e2; }
    tk[b*2] = t0; tk[b*2 + 1] = t1;
  }
}

// ========== expALL: scan + conv1 + conv2(MFMA) + conv3(MFMA) + FC ==========
// grid 256 = one block/sample, 512 thr. __launch_bounds__(512,2): VGPR cap
// 256 — R10's 128-cap forced ~34MB of scratch spill traffic (the 123us).
// conv1 uses 2-oc groups (peak live regs halved vs R10).
#define XA_IMG  0
#define XA_W2   12960
#define XA_WT   18080
#define XA_FEAT 3600
#define XA_SFF  3728
#define XA_SGG  3856
#define XA_XF   9040
#define XA_W1F  12508
#define XA_BN1F 13372
#define XA_SC   9040      // FC partial-sum scratch (512 f32), after conv3
__global__ __launch_bounds__(512, 2) void expALL_kernel(
    const float* __restrict__ x, const int* __restrict__ tk,
    const float* __restrict__ ew1, const float* __restrict__ eg1,
    const float* __restrict__ eb1, const ushort* __restrict__ ew2b,
    const float* __restrict__ eg2, const float* __restrict__ eb2,
    const ushort* __restrict__ ew3b, const float* __restrict__ eg3,
    const float* __restrict__ eb3, const float* __restrict__ efw,
    const float* __restrict__ efb, const float* __restrict__ cw1,
    const float* __restrict__ cb1, const float* __restrict__ cw2,
    const float* __restrict__ cb2, float* __restrict__ outF,
    float* __restrict__ outD)
{
  __shared__ __align__(16) ushort smu[27296];
  __shared__ int stk[512];
  __shared__ int sch;
  float* smf = (float*)smu;
  const int t = threadIdx.x, b = blockIdx.x;

  // ---- 1) capacity scan replay ----
  stk[t] = tk[t];
  __syncthreads();
  if (t == 0) {
    float L0=0,L1=0,L2=0,L3=0,L4=0,L5=0,L6=0,L7=0;
    int chv = 0;
    for (int i = 0; i <= b; ++i) {
      const int a = stk[2*i], c = stk[2*i+1];
      const float la = (a==0)?L0:(a==1)?L1:(a==2)?L2:(a==3)?L3:(a==4)?L4:(a==5)?L5:(a==6)?L6:L7;
      const float lc = (c==0)?L0:(c==1)?L1:(c==2)?L2:(c==3)?L3:(c==4)?L4:(c==5)?L5:(c==6)?L6:L7;
      chv = (la < 48.f) ? a : ((lc < 48.f) ? c : ((la <= lc) ? a : c));
      L0 += (chv==0)?1.f:0.f; L1 += (chv==1)?1.f:0.f; L2 += (chv==2)?1.f:0.f; L3 += (chv==3)?1.f:0.f;
      L4 += (chv==4)?1.f:0.f; L5 += (chv==5)?1.f:0.f; L6 += (chv==6)?1.f:0.f; L7 += (chv==7)?1.f:0.f;
    }
    sch = chv;
  }
  __syncthreads();
  const int e = sch;
  if (t < 8) outD[b*8 + t] = (t == e) ? 1.f : 0.f;

  // ---- 2) zero IMG; stage x [3][34][34], w1t, bn1 ----
  {
    uint4 z; z.x = 0; z.y = 0; z.z = 0; z.w = 0;
    for (int j = t; j < 1620; j += 512) ((uint4*)smu)[j] = z;
  }
  for (int j = t; j < 3468; j += 512) {
    int ic = j / 1156, rem = j % 1156, p = rem / 34, cpd = rem % 34;
    int gy = p - 1, gx = cpd - 1;
    float v = 0.f;
    if (gy >= 0 && gy < 32 && gx >= 0 && gx < 32) v = x[b*3072 + ic*1024 + gy*32 + gx];
    smf[XA_XF + j] = v;
  }
  for (int j = t; j < 864; j += 512) {
    int oc = j / 27, r = j % 27, ic = r / 9, k = r % 9;
    smf[XA_W1F + ic*288 + k*32 + oc] = ew1[e*864 + j];
  }
  if (t < 32) { smf[XA_BN1F + t] = eg1[e*32 + t]*BN_RS; smf[XA_BN1F + 32 + t] = eb1[e*32 + t]; }
  __syncthreads();

  // ---- 3) conv1 fp32: 16 groups x 2 oc x 32 cols; 4 slab loop -> bf16 IMG --
  {
    const int g = t >> 5, c = t & 31;        // g in 0..15 (2 oc each)
    for (int rs = 0; rs < 4; ++rs) {
      const int r0 = rs * 8;
      float acc[2][8];
      #pragma unroll
      for (int o = 0; o < 2; ++o)
        #pragma unroll
        for (int r = 0; r < 8; ++r) acc[o][r] = 0.f;
      for (int ic = 0; ic < 3; ++ic) {
        float w[2][9];
        #pragma unroll
        for (int k = 0; k < 9; ++k) {
          float2 wv = *(const float2*)&smf[XA_W1F + ic*288 + k*32 + 2*g];
          w[0][k] = wv.x; w[1][k] = wv.y;
        }
        const float* src = &smf[XA_XF + ic*1156 + r0*34 + c];
        #pragma unroll
        for (int rr = 0; rr < 10; ++rr) {
          const float i0 = src[rr*34], i1 = src[rr*34 + 1], i2 = src[rr*34 + 2];
          #pragma unroll
          for (int dr = 0; dr < 3; ++dr) {
            const int r = rr - dr;
            if (r < 0 || r > 7) continue;
            #pragma unroll
            for (int o = 0; o < 2; ++o) {
              acc[o][r] = fmaf(w[o][dr*3+0], i0, acc[o][r]);
              acc[o][r] = fmaf(w[o][dr*3+1], i1, acc[o][r]);
              acc[o][r] = fmaf(w[o][dr*3+2], i2, acc[o][r]);
            }
          }
        }
      }
      #pragma unroll
      for (int o = 0; o < 2; ++o) {
        const int oc = 2*g + o;
        const float s = smf[XA_BN1F + oc], bo = smf[XA_BN1F + 32 + oc];
        float m[4];
        #pragma unroll
        for (int pr = 0; pr < 4; ++pr) {
          float v0 = fmaxf(fmaf(acc[o][2*pr],   s, bo), 0.f);
          float v1 = fmaxf(fmaf(acc[o][2*pr+1], s, bo), 0.f);
          m[pr] = fmaxf(v0, v1);
        }
        #pragma unroll
        for (int pr = 0; pr < 4; ++pr) {
          float nb = __shfl_xor(m[pr], 1);
          m[pr] = fmaxf(m[pr], nb);
        }
        if (!(c & 1)) {
          const int pc = c >> 1;
          #pragma unroll
          for (int pr = 0; pr < 4; ++pr)
            smu[XA_IMG + ((rs*4 + pr + 1)*18 + (pc + 1))*40 + oc] = f2bf(m[pr]);
        }
      }
    }
  }
  if (t < 256) {  // stage W2 tap 0
    int oc = t >> 2, ofs = (t & 3) * 8;
    *(uint4*)&smu[XA_W2 + oc*40 + ofs] = *(const uint4*)&ew2b[(e*9 + 0)*2048 + t*8];
  }
  __syncthreads();

  // ---- 4) conv2 MFMA: wave = (mhalf, ntile), 8 m-tiles each ----
  const int w8 = t >> 6, l = t & 63;
  const int col = l & 15, quad = l >> 4;
  {
    const int ntile = w8 & 3, mhalf = w8 >> 2;
    floatx4 acc[8];
    #pragma unroll
    for (int mt = 0; mt < 8; ++mt)
      #pragma unroll
      for (int i = 0; i < 4; ++i) acc[mt][i] = 0.f;

    for (int tap = 0; tap < 9; ++tap) {
      if (tap < 8 && t < 256) {
        int oc = t >> 2, ofs = (t & 3) * 8;
        *(uint4*)&smu[XA_W2 + ((tap+1)&1)*2560 + oc*40 + ofs] =
            *(const uint4*)&ew2b[(e*9 + tap + 1)*2048 + t*8];
      }
      const ushort* wb = &smu[XA_W2 + (tap&1)*2560];
      short8 bfr = *(const short8*)&wb[(ntile*16 + col)*40 + quad*8];
      const int dy = tap / 3, dx = tap % 3;
      #pragma unroll
      for (int mtl = 0; mtl < 8; ++mtl) {
        const int mt = mhalf*8 + mtl;
        short8 afr = *(const short8*)
            &smu[XA_IMG + ((mt + dy)*18 + col + dx)*40 + quad*8];
        acc[mtl] = __builtin_amdgcn_mfma_f32_16x16x32_bf16(afr, bfr, acc[mtl], 0, 0, 0);
      }
      __syncthreads();
    }

    // P2T borders + pooled interior (overlays dead IMG)
    {
      uint4 z; z.x = 0; z.y = 0; z.z = 0; z.w = 0;
      for (int j = t; j < 288; j += 512) {
        int slot = j >> 3, ofs = (j & 7) * 8, row, cl;
        if (slot < 10)      { row = 0; cl = slot; }
        else if (slot < 20) { row = 9; cl = slot - 10; }
        else if (slot < 28) { row = 1 + (slot - 20); cl = 0; }
        else                { row = 1 + (slot - 28); cl = 9; }
        *(uint4*)&smu[(row*10 + cl)*72 + ofs] = z;
      }
    }
    const int oc2 = ntile*16 + col;
    const float s2 = eg2[e*64 + oc2]*BN_RS, bo2 = eb2[e*64 + oc2];
    #pragma unroll
    for (int mtpl = 0; mtpl < 4; ++mtpl) {
      const int mtp = mhalf*4 + mtpl;
      float a00 = fmaxf(fmaf(acc[2*mtpl][0],   s2, bo2), 0.f);
      float a01 = fmaxf(fmaf(acc[2*mtpl][1],   s2, bo2), 0.f);
      float a02 = fmaxf(fmaf(acc[2*mtpl][2],   s2, bo2), 0.f);
      float a03 = fmaxf(fmaf(acc[2*mtpl][3],   s2, bo2), 0.f);
      float a10 = fmaxf(fmaf(acc[2*mtpl+1][0], s2, bo2), 0.f);
      float a11 = fmaxf(fmaf(acc[2*mtpl+1][1], s2, bo2), 0.f);
      float a12 = fmaxf(fmaf(acc[2*mtpl+1][2], s2, bo2), 0.f);
      float a13 = fmaxf(fmaf(acc[2*mtpl+1][3], s2, bo2), 0.f);
      float p0 = fmaxf(fmaxf(a00, a01), fmaxf(a10, a11));
      float p1 = fmaxf(fmaxf(a02, a03), fmaxf(a12, a13));
      smu[((mtp + 1)*10 + (quad*2 + 1))*72 + oc2] = f2bf(p0);
      smu[((mtp + 1)*10 + (quad*2 + 2))*72 + oc2] = f2bf(p1);
    }
  }
  __syncthreads();

  // ---- 6) conv3 MFMA: wave w8 owns oc-tile w8 (oc = w8*16 + col) ----
  {
    const int oc3 = w8*16 + col;
    floatx4 acc[4];
    #pragma unroll
    for (int mt = 0; mt < 4; ++mt)
      #pragma unroll
      for (int i = 0; i < 4; ++i) acc[mt][i] = 0.f;

    for (int tap = 0; tap < 9; ++tap) {
      __syncthreads();
      for (int j = t; j < 1024; j += 512) {
        int oc = j >> 3, ico = (j & 7) * 8;
        *(uint4*)&smu[XA_WT + oc*72 + ico] =
            *(const uint4*)&ew3b[(e*9 + tap)*8192 + j*8];
      }
      __syncthreads();
      const int dy = tap / 3, dx = tap % 3;
      #pragma unroll
      for (int ks = 0; ks < 2; ++ks) {
        short8 bfr = *(const short8*)&smu[XA_WT + oc3*72 + ks*32 + quad*8];
        #pragma unroll
        for (int mt = 0; mt < 4; ++mt) {
          const int m = mt*16 + col;
          const int y = m >> 3, xx = m & 7;
          short8 afr = *(const short8*)
              &smu[((y + dy)*10 + (xx + dx))*72 + ks*32 + quad*8];
          acc[mt] = __builtin_amdgcn_mfma_f32_16x16x32_bf16(afr, bfr, acc[mt], 0, 0, 0);
        }
      }
    }

    // epilogue: bn + relu + GAP -> feat in LDS
    {
      const float s = eg3[e*128 + oc3]*BN_RS, bo = eb3[e*128 + oc3];
      float gsum = 0.f;
      #pragma unroll
      for (int mt = 0; mt < 4; ++mt)
        #pragma unroll
        for (int i = 0; i < 4; ++i)
          gsum += fmaxf(fmaf(acc[mt][i], s, bo), 0.f);
      gsum += __shfl_xor(gsum, 16);
      gsum += __shfl_xor(gsum, 32);
      if (quad == 0) smf[XA_FEAT + oc3] = gsum * (1.f/64.f);
    }
  }
  __syncthreads();

  // ---- 7) FC chain, 4-way dot split via LDS scratch ----
  {
    const int out = t & 127, part = t >> 7;     // part 0..3
    float a = (part == 0) ? efb[e*128 + out] : 0.f;
    const float4* wp = (const float4*)&efw[e*16384 + out*128 + part*32];
    #pragma unroll
    for (int i4 = 0; i4 < 8; ++i4) {
      float4 wv = wp[i4];
      const int base = XA_FEAT + part*32 + 4*i4;
      a = fmaf(wv.x, smf[base], a);     a = fmaf(wv.y, smf[base + 1], a);
      a = fmaf(wv.z, smf[base + 2], a); a = fmaf(wv.w, smf[base + 3], a);
    }
    smf[XA_SC + part*128 + out] = a;
  }
  __syncthreads();
  if (t < 128)
    smf[XA_SFF + t] = fmaxf(smf[XA_SC + t] + smf[XA_SC + 128 + t] +
                            smf[XA_SC + 256 + t] + smf[XA_SC + 384 + t], 0.f);
  __syncthreads();
  if (t < 256) {
    const int out = t & 63, part = t >> 6;      // part 0..3
    float a = (part == 0) ? cb1[e*64 + out] : 0.f;
    const float4* wp = (const float4*)&cw1[e*8192 + out*128 + part*32];
    #pragma unroll
    for (int i4 = 0; i4 < 8; ++i4) {
      float4 wv = wp[i4];
      const int base = XA_SFF + part*32 + 4*i4;
      a = fmaf(wv.x, smf[base], a);     a = fmaf(wv.y, smf[base + 1], a);
      a = fmaf(wv.z, smf[base + 2], a); a = fmaf(wv.w, smf[base + 3], a);
    }
    smf[XA_SC + part*64 + out] = a;
  }
  __syncthreads();
  if (t < 64)
    smf[XA_SGG + t] = fmaxf(smf[XA_SC + t] + smf[XA_SC + 64 + t] +
                            smf[XA_SC + 128 + t] + smf[XA_SC + 192 + t], 0.f);
  __syncthreads();
  if (t < 10) {
    float a = cb2[e*10 + t];
    const float4* wp = (const float4*)&cw2[e*640 + t*64];
    #pragma unroll
    for (int i4 = 0; i4 < 16; ++i4) {
      float4 wv = wp[i4];
      a = fmaf(wv.x, smf[XA_SGG + 4*i4],     a);
      a = fmaf(wv.y, smf[XA_SGG + 4*i4 + 1], a);
      a = fmaf(wv.z, smf[XA_SGG + 4*i4 + 2], a);
      a = fmaf(wv.w, smf[XA_SGG + 4*i4 + 3], a);
    }
    outF[b*10 + t] = a;   // routing weight is exactly 1.0 for the chosen expert
  }
}

// ================================ host =====================================
extern "C" void kernel_launch(void* const* d_in, const int* in_sizes, int n_in,
                              void* d_out, int out_size, void* d_ws, size_t ws_size,
                              hipStream_t stream)
{
  const float* x   = (const float*)d_in[0];
  const float* tw1 = (const float*)d_in[1];
  const float* tg1 = (const float*)d_in[2];
  const float* tb1 = (const float*)d_in[3];
  const float* tw2 = (const float*)d_in[4];
  const float* tg2 = (const float*)d_in[5];
  const float* tb2 = (const float*)d_in[6];
  const float* tfw = (const float*)d_in[7];
  const float* tfb = (const float*)d_in[8];
  const float* gw1 = (const float*)d_in[9];
  const float* gb1 = (const float*)d_in[10];
  const float* gw2 = (const float*)d_in[11];
  const float* gb2 = (const float*)d_in[12];
  const float* ew1 = (const float*)d_in[13];
  const float* eg1 = (const float*)d_in[14];
  const float* eb1 = (const float*)d_in[15];
  const float* ew2 = (const float*)d_in[16];
  const float* eg2 = (const float*)d_in[17];
  const float* eb2 = (const float*)d_in[18];
  const float* ew3 = (const float*)d_in[19];
  const float* eg3 = (const float*)d_in[20];
  const float* eb3 = (const float*)d_in[21];
  const float* efw = (const float*)d_in[22];
  const float* efb = (const float*)d_in[23];
  const float* cw1 = (const float*)d_in[24];
  const float* cb1 = (const float*)d_in[25];
  const float* cw2 = (const float*)d_in[26];
  const float* cb2 = (const float*)d_in[27];

  float*  out  = (float*)d_out;
  char*   ws   = (char*)d_ws;
  float*  tfp  = (float*)(ws + WS_TFP);
  int*    tk   = (int*)(ws + WS_TK);
  float*  tw2t = (float*)(ws + WS_TW2T);
  ushort* ew2b = (ushort*)(ws + WS_EW2B);
  ushort* ew3b = (ushort*)(ws + WS_EW3B);

  prep_kernel<<<2916, 256, 0, stream>>>(tw2, ew2, ew3, tw2t, ew2b, ew3b);
  trunk_kernel<<<2048, 256, 0, stream>>>(x, tw1, tg1, tb1, tw2t, tg2, tb2, tfp);
  gate_kernel<<<256, 64, 0, stream>>>(tfp, tfw, tfb, gw1, gb1, gw2, gb2,
                                      out + 2560, tk);
  expALL_kernel<<<256, 512, 0, stream>>>(x, tk, ew1, eg1, eb1, ew2b, eg2, eb2,
                                         ew3b, eg3, eb3, efw, efb, cw1, cb1,
                                         cw2, cb2, out, out + 4608);
}